// Round 1
// baseline (936.573 us; speedup 1.0000x reference)
//
#include <hip/hip_runtime.h>
#include <hip/hip_bf16.h>
#include <math.h>

#define T_ 2048
#define H_ 2048
#define HQ_ 32
#define HKV_ 2
#define D_ 64
#define G_ 16
#define M_ 32
#define TOPK_ 16
#define WINDOW_ 512
#define HQD_ 2048   // HQ*D
#define KVD_ 128    // HKV*D
#define GATE_LD 96  // HQ*3

typedef __attribute__((ext_vector_type(8))) __bf16 bf16x8;
typedef __attribute__((ext_vector_type(4))) float f32x4;

#define MFMA16(a, b, c) __builtin_amdgcn_mfma_f32_16x16x32_bf16((a), (b), (c), 0, 0, 0)

// ---------------------------------------------------------------------------
// Generic GEMM: C[M][N] = A[M][K] @ B[K][N].  BM=BN=128, BK=32, 256 threads.
// AMODE: 0 = A fp32 (convert to bf16 while staging), 1 = A bf16.
// OMODE: 0 = bf16 out, 2 = fp32 out.
// A-frag: lane holds A[row=l&15][k=(l>>4)*8+j]; B staged transposed so
// B-frag lane reads B^T[col=l&15][k] contiguously. C/D: row=(l>>4)*4+reg, col=l&15.
// ---------------------------------------------------------------------------
template<int AMODE, int OMODE>
__global__ __launch_bounds__(256) void gemm_kernel(
    const void* __restrict__ Av, const float* __restrict__ B,
    void* __restrict__ Cv, int Mdim, int Ndim, int Kdim)
{
  __shared__ __bf16 As[128][40];
  __shared__ __bf16 Bs[128][40];
  const int tid = threadIdx.x;
  const int lane = tid & 63;
  const int w = tid >> 6;
  const int r15 = lane & 15;
  const int kq = (lane >> 4) * 8;
  const int m0 = blockIdx.y * 128;
  const int n0 = blockIdx.x * 128;

  const f32x4 fzero = {0.f, 0.f, 0.f, 0.f};
  f32x4 acc[2][8];
#pragma unroll
  for (int a = 0; a < 2; ++a)
#pragma unroll
    for (int b = 0; b < 8; ++b) acc[a][b] = fzero;

  const int ar = tid >> 1, akc = (tid & 1) * 16;
  const int bkr = tid >> 3, bnc = (tid & 7) * 16;

  for (int k0 = 0; k0 < Kdim; k0 += 32) {
    __syncthreads();
    if constexpr (AMODE == 0) {
      const float* a = (const float*)Av + (size_t)(m0 + ar) * Kdim + k0 + akc;
      float4 f0 = *(const float4*)(a);
      float4 f1 = *(const float4*)(a + 4);
      float4 f2 = *(const float4*)(a + 8);
      float4 f3 = *(const float4*)(a + 12);
      bf16x8 w0 = {(__bf16)f0.x, (__bf16)f0.y, (__bf16)f0.z, (__bf16)f0.w,
                   (__bf16)f1.x, (__bf16)f1.y, (__bf16)f1.z, (__bf16)f1.w};
      bf16x8 w1 = {(__bf16)f2.x, (__bf16)f2.y, (__bf16)f2.z, (__bf16)f2.w,
                   (__bf16)f3.x, (__bf16)f3.y, (__bf16)f3.z, (__bf16)f3.w};
      *(bf16x8*)&As[ar][akc] = w0;
      *(bf16x8*)&As[ar][akc + 8] = w1;
    } else {
      const __bf16* a = (const __bf16*)Av + (size_t)(m0 + ar) * Kdim + k0 + akc;
      *(int4*)&As[ar][akc] = *(const int4*)a;
      *(int4*)&As[ar][akc + 8] = *(const int4*)(a + 8);
    }
    {
      const float* b = B + (size_t)(k0 + bkr) * Ndim + n0 + bnc;
#pragma unroll
      for (int e = 0; e < 16; ++e) {
        float val = (n0 + bnc + e < Ndim) ? b[e] : 0.f;
        Bs[bnc + e][bkr] = (__bf16)val;
      }
    }
    __syncthreads();
    bf16x8 af0 = *(bf16x8*)&As[w * 32 + r15][kq];
    bf16x8 af1 = *(bf16x8*)&As[w * 32 + 16 + r15][kq];
#pragma unroll
    for (int ni = 0; ni < 8; ++ni) {
      bf16x8 bfrag = *(bf16x8*)&Bs[ni * 16 + r15][kq];
      acc[0][ni] = MFMA16(af0, bfrag, acc[0][ni]);
      acc[1][ni] = MFMA16(af1, bfrag, acc[1][ni]);
    }
  }

#pragma unroll
  for (int mi = 0; mi < 2; ++mi)
#pragma unroll
    for (int ni = 0; ni < 8; ++ni)
#pragma unroll
      for (int reg = 0; reg < 4; ++reg) {
        int row = m0 + w * 32 + mi * 16 + (lane >> 4) * 4 + reg;
        int col = n0 + ni * 16 + r15;
        if (col >= Ndim) continue;
        float v = acc[mi][ni][reg];
        if constexpr (OMODE == 0) {
          ((__bf16*)Cv)[(size_t)row * Ndim + col] = (__bf16)v;
        } else {
          ((float*)Cv)[(size_t)row * Ndim + col] = v;
        }
      }
}

// ---------------------------------------------------------------------------
// Fused K/V/Gate projection: blockIdx.x selects {0:K, 1:V(+V^T), 2:gate(sigmoid)}.
// ---------------------------------------------------------------------------
__global__ __launch_bounds__(256) void gemm_kvg_kernel(
    const float* __restrict__ x, const float* __restrict__ Wk,
    const float* __restrict__ Wv, const float* __restrict__ Wg,
    __bf16* __restrict__ kout, __bf16* __restrict__ vout,
    __bf16* __restrict__ vTout, float* __restrict__ gout)
{
  __shared__ __bf16 As[128][40];
  __shared__ __bf16 Bs[128][40];
  const int sel = blockIdx.x;  // 0=k,1=v,2=g
  const float* B = (sel == 0) ? Wk : (sel == 1) ? Wv : Wg;
  const int Ndim = (sel == 2) ? GATE_LD : KVD_;
  const int tid = threadIdx.x;
  const int lane = tid & 63;
  const int w = tid >> 6;
  const int r15 = lane & 15;
  const int kq = (lane >> 4) * 8;
  const int m0 = blockIdx.y * 128;

  const f32x4 fzero = {0.f, 0.f, 0.f, 0.f};
  f32x4 acc[2][8];
#pragma unroll
  for (int a = 0; a < 2; ++a)
#pragma unroll
    for (int b = 0; b < 8; ++b) acc[a][b] = fzero;

  const int ar = tid >> 1, akc = (tid & 1) * 16;
  const int bkr = tid >> 3, bnc = (tid & 7) * 16;

  for (int k0 = 0; k0 < H_; k0 += 32) {
    __syncthreads();
    {
      const float* a = x + (size_t)(m0 + ar) * H_ + k0 + akc;
      float4 f0 = *(const float4*)(a);
      float4 f1 = *(const float4*)(a + 4);
      float4 f2 = *(const float4*)(a + 8);
      float4 f3 = *(const float4*)(a + 12);
      bf16x8 w0 = {(__bf16)f0.x, (__bf16)f0.y, (__bf16)f0.z, (__bf16)f0.w,
                   (__bf16)f1.x, (__bf16)f1.y, (__bf16)f1.z, (__bf16)f1.w};
      bf16x8 w1 = {(__bf16)f2.x, (__bf16)f2.y, (__bf16)f2.z, (__bf16)f2.w,
                   (__bf16)f3.x, (__bf16)f3.y, (__bf16)f3.z, (__bf16)f3.w};
      *(bf16x8*)&As[ar][akc] = w0;
      *(bf16x8*)&As[ar][akc + 8] = w1;
    }
    {
      const float* b = B + (size_t)(k0 + bkr) * Ndim + bnc;
#pragma unroll
      for (int e = 0; e < 16; ++e) {
        float val = (bnc + e < Ndim) ? b[e] : 0.f;
        Bs[bnc + e][bkr] = (__bf16)val;
      }
    }
    __syncthreads();
    bf16x8 af0 = *(bf16x8*)&As[w * 32 + r15][kq];
    bf16x8 af1 = *(bf16x8*)&As[w * 32 + 16 + r15][kq];
#pragma unroll
    for (int ni = 0; ni < 8; ++ni) {
      bf16x8 bfrag = *(bf16x8*)&Bs[ni * 16 + r15][kq];
      acc[0][ni] = MFMA16(af0, bfrag, acc[0][ni]);
      acc[1][ni] = MFMA16(af1, bfrag, acc[1][ni]);
    }
  }

#pragma unroll
  for (int mi = 0; mi < 2; ++mi)
#pragma unroll
    for (int ni = 0; ni < 8; ++ni)
#pragma unroll
      for (int reg = 0; reg < 4; ++reg) {
        int row = m0 + w * 32 + mi * 16 + (lane >> 4) * 4 + reg;
        int col = ni * 16 + r15;
        if (col >= Ndim) continue;
        float v = acc[mi][ni][reg];
        if (sel == 0) {
          kout[(size_t)row * KVD_ + col] = (__bf16)v;
        } else if (sel == 1) {
          vout[(size_t)row * KVD_ + col] = (__bf16)v;
          vTout[(size_t)col * T_ + row] = (__bf16)v;
        } else {
          gout[(size_t)row * GATE_LD + col] = 1.f / (1.f + expf(-v));
        }
      }
}

// ---------------------------------------------------------------------------
// ck/cv: ck[h][m][d] = sum_t (k[m*64+t][h][d] + pe[h][t][d]) * w_ck[h][t]
// ---------------------------------------------------------------------------
__global__ void ckcv_kernel(const __bf16* __restrict__ kbf, const __bf16* __restrict__ vbf,
                            const float* __restrict__ pe, const float* __restrict__ wck,
                            const float* __restrict__ wcv, float* __restrict__ ckf,
                            float* __restrict__ cvf)
{
  const int m = blockIdx.x, h = blockIdx.y, d = threadIdx.x;
  float cka = 0.f, cva = 0.f;
  for (int t = 0; t < 64; ++t) {
    float kk = (float)kbf[(size_t)(m * 64 + t) * KVD_ + h * 64 + d];
    float vv = (float)vbf[(size_t)(m * 64 + t) * KVD_ + h * 64 + d];
    float pev = pe[((size_t)h * 64 + t) * 64 + d];
    cka += (kk + pev) * wck[h * 64 + t];
    cva += vv * wcv[h * 64 + t];
  }
  ckf[((size_t)h * M_ + m) * D_ + d] = cka;
  cvf[((size_t)h * M_ + m) * D_ + d] = cva;
}

// ---------------------------------------------------------------------------
// Compressed attention: wave per (i, h_kv), loops g. Produces comp_out (bf16)
// and block scores s[h][i][m] (fp32, written once -> no atomics, no memset).
// ---------------------------------------------------------------------------
__global__ __launch_bounds__(256) void comp_kernel(
    const __bf16* __restrict__ q, const float* __restrict__ ckf,
    const float* __restrict__ cvf, __bf16* __restrict__ comp,
    float* __restrict__ sout)
{
  __shared__ float cks[M_][65];
  __shared__ float cvs[M_][65];
  __shared__ float qv[4][64];
  __shared__ float pv_sh[4][32];
  const int h = blockIdx.y;
  const int tid = threadIdx.x, w = tid >> 6, lane = tid & 63;
  {
    int mm = tid >> 3, dc = (tid & 7) * 8;
#pragma unroll
    for (int e = 0; e < 8; ++e) {
      cks[mm][dc + e] = ckf[((size_t)h * M_ + mm) * D_ + dc + e];
      cvs[mm][dc + e] = cvf[((size_t)h * M_ + mm) * D_ + dc + e];
    }
  }
  __syncthreads();
  const int i = blockIdx.x * 4 + w;
  const int nvis = (i >= 63) ? ((i - 63) >> 6) + 1 : 0;
  float s_acc = 0.f;
  for (int g = 0; g < G_; ++g) {
    const int head = h * G_ + g;
    qv[w][lane] = (float)q[(size_t)i * HQD_ + head * 64 + lane];
    float lg = -__builtin_inff();
    if (lane < nvis) {
      float a = 0.f;
      for (int d2 = 0; d2 < 64; ++d2) a += qv[w][d2] * cks[lane][d2];
      lg = a * 0.125f;
    }
    float mx = lg;
    for (int off = 1; off < 32; off <<= 1) mx = fmaxf(mx, __shfl_xor(mx, off));
    float p = (lane < nvis) ? expf(lg - mx) : 0.f;
    float sum = p;
    for (int off = 1; off < 32; off <<= 1) sum += __shfl_xor(sum, off);
    float pn = (sum > 0.f) ? p / sum : 0.f;
    s_acc += pn;
    if (lane < 32) pv_sh[w][lane] = pn;
    float o = 0.f;
    for (int m2 = 0; m2 < nvis; ++m2) o += pv_sh[w][m2] * cvs[m2][lane];
    comp[(size_t)i * HQD_ + head * 64 + lane] = (__bf16)o;
  }
  if (lane < 32) sout[((size_t)h * T_ + i) * M_ + lane] = s_acc;
}

// ---------------------------------------------------------------------------
// Top-k selection (stable, replicates jax.lax.top_k tie-breaking) -> bitmask.
// ---------------------------------------------------------------------------
__global__ void topk_kernel(const float* __restrict__ sin, unsigned* __restrict__ sel)
{
  int idx = blockIdx.x * blockDim.x + threadIdx.x;
  if (idx >= HKV_ * T_) return;
  int h = idx >> 11, i = idx & (T_ - 1);
  int qblk = i >> 6;
  float sc[M_];
#pragma unroll
  for (int m = 0; m < M_; ++m) {
    if (m > qblk) sc[m] = -__builtin_inff();
    else if (m == 0 || m > qblk - 2) sc[m] = __builtin_inff();
    else sc[m] = sin[((size_t)h * T_ + i) * M_ + m];
  }
  unsigned picked = 0;
  for (int r = 0; r < TOPK_; ++r) {
    float best = -__builtin_inff();
    int bi = -1;
#pragma unroll
    for (int m = 0; m < M_; ++m) {
      if (!((picked >> m) & 1u) && sc[m] > best) { best = sc[m]; bi = m; }
    }
    if (bi < 0) break;
    picked |= 1u << bi;
  }
  sel[(size_t)h * T_ + i] = picked;
}

// ---------------------------------------------------------------------------
// Flash kernel: block per (qb, h*16+g); 4 waves; 64 queries x 64 d per block.
// Two online-softmax branches (sparse sel-mask, sliding window) share S tile.
// PV computed as O^T = V^T * P^T so all MFMA operands are contiguous-K.
// Epilogue fuses gating with comp_out and writes `fused` (bf16).
// ---------------------------------------------------------------------------
__global__ __launch_bounds__(256) void flash_kernel(
    const __bf16* __restrict__ q, const __bf16* __restrict__ kg,
    const __bf16* __restrict__ vT, const unsigned* __restrict__ selg,
    const __bf16* __restrict__ comp, const float* __restrict__ gate,
    __bf16* __restrict__ fused)
{
  __shared__ alignas(16) char smem[38400];
  __bf16 (*Qs)[72] = (__bf16(*)[72])(smem);            // 9216 B
  __bf16 (*Ks)[72] = (__bf16(*)[72])(smem + 9216);     // 9216 B
  __bf16 (*Vt)[72] = (__bf16(*)[72])(smem + 18432);    // 9216 B
  __bf16 (*Ps)[72] = (__bf16(*)[72])(smem + 27648);    // 9216 B, wave w rows 16w..
  float* alpha_sh = (float*)(smem + 36864);            // [2][4][16]
  float* lsum_sh = (float*)(smem + 37376);             // [2][4][16]
  unsigned* sel_sh = (unsigned*)(smem + 37888);        // [64]
  unsigned* union_p = (unsigned*)(smem + 38144);

  const int qb = blockIdx.x;
  const int hg = blockIdx.y;  // head index; h = hg>>4
  const int h = hg >> 4;
  const int tid = threadIdx.x;
  const int lane = tid & 63;
  const int w = tid >> 6;
  const int r15 = lane & 15;
  const int kq = (lane >> 4) * 8;
  const int rbase = (lane >> 4) * 4;

  {
    int r = tid >> 2, dc = (tid & 3) * 16;
    const __bf16* src = q + (size_t)(qb * 64 + r) * HQD_ + hg * 64 + dc;
    *(int4*)&Qs[r][dc] = *(const int4*)src;
    *(int4*)&Qs[r][dc + 8] = *(const int4*)(src + 8);
  }
  if (tid < 64) sel_sh[tid] = selg[h * T_ + qb * 64 + tid];
  __syncthreads();
  if (tid == 0) {
    unsigned u = 0;
    for (int rr = 0; rr < 64; ++rr) u |= sel_sh[rr];
    *union_p = u;
  }
  __syncthreads();
  const unsigned ubits = *union_p;

  // Q fragments and per-row sel bits are loop-invariant: hoist.
  bf16x8 aq0 = *(bf16x8*)&Qs[w * 16 + r15][kq];
  bf16x8 aq1 = *(bf16x8*)&Qs[w * 16 + r15][32 + kq];
  unsigned selr[4];
#pragma unroll
  for (int reg = 0; reg < 4; ++reg) selr[reg] = sel_sh[w * 16 + rbase + reg];

  const f32x4 fzero = {0.f, 0.f, 0.f, 0.f};
  f32x4 accO[2][4];
  float mrun[2][4], lrun[2][4];
#pragma unroll
  for (int br = 0; br < 2; ++br)
#pragma unroll
    for (int a = 0; a < 4; ++a) {
      accO[br][a] = fzero;
      mrun[br][a] = -__builtin_inff();
      lrun[br][a] = 0.f;
    }

  for (int kb = 0; kb <= qb; ++kb) {
    const bool sp_act = (ubits >> kb) & 1u;
    const bool wn_act = (kb + 8) >= qb;
    if (!sp_act && !wn_act) continue;
    __syncthreads();
    {
      int t = tid >> 2, dc = (tid & 3) * 16;
      const __bf16* ksrc = kg + (size_t)(kb * 64 + t) * KVD_ + h * 64 + dc;
      *(int4*)&Ks[t][dc] = *(const int4*)ksrc;
      *(int4*)&Ks[t][dc + 8] = *(const int4*)(ksrc + 8);
      const __bf16* vsrc = vT + (size_t)(h * 64 + t) * T_ + kb * 64 + dc;
      *(int4*)&Vt[t][dc] = *(const int4*)vsrc;
      *(int4*)&Vt[t][dc + 8] = *(const int4*)(vsrc + 8);
    }
    __syncthreads();

    f32x4 accS[4];
#pragma unroll
    for (int f = 0; f < 4; ++f) {
      bf16x8 b0 = *(bf16x8*)&Ks[f * 16 + r15][kq];
      bf16x8 b1 = *(bf16x8*)&Ks[f * 16 + r15][32 + kq];
      f32x4 s = fzero;
      s = MFMA16(aq0, b0, s);
      s = MFMA16(aq1, b1, s);
      accS[f] = s;
    }

    float sv[4][4];
#pragma unroll
    for (int f = 0; f < 4; ++f)
#pragma unroll
      for (int reg = 0; reg < 4; ++reg) sv[f][reg] = accS[f][reg] * 0.125f;

    bf16x8 av[4][2];
#pragma unroll
    for (int df = 0; df < 4; ++df) {
      av[df][0] = *(bf16x8*)&Vt[df * 16 + r15][kq];
      av[df][1] = *(bf16x8*)&Vt[df * 16 + r15][32 + kq];
    }

#pragma unroll
    for (int br = 0; br < 2; ++br) {
      if (br == 0 ? !sp_act : !wn_act) continue;
      float al[4], mt[4];
#pragma unroll
      for (int reg = 0; reg < 4; ++reg) {
        const int r = w * 16 + rbase + reg;
        float m = -__builtin_inff();
#pragma unroll
        for (int f = 0; f < 4; ++f) {
          const int t = f * 16 + r15;
          bool causal = (kb < qb) || (t <= r);
          bool v = (br == 0) ? (causal && ((selr[reg] >> kb) & 1u))
                             : (causal && ((qb - kb) * 64 + r - t) <= WINDOW_);
          if (v) m = fmaxf(m, sv[f][reg]);
        }
#pragma unroll
        for (int off = 1; off < 16; off <<= 1) m = fmaxf(m, __shfl_xor(m, off));
        float mnew = fmaxf(mrun[br][reg], m);
        al[reg] = (mnew == -__builtin_inff()) ? 1.f : expf(mrun[br][reg] - mnew);
        mrun[br][reg] = mnew;
        mt[reg] = mnew;
      }
      float rs[4] = {0.f, 0.f, 0.f, 0.f};
      float pr[4][4];
#pragma unroll
      for (int f = 0; f < 4; ++f) {
#pragma unroll
        for (int reg = 0; reg < 4; ++reg) {
          const int r = w * 16 + rbase + reg;
          const int t = f * 16 + r15;
          bool causal = (kb < qb) || (t <= r);
          bool v = (br == 0) ? (causal && ((selr[reg] >> kb) & 1u))
                             : (causal && ((qb - kb) * 64 + r - t) <= WINDOW_);
          float p = v ? expf(sv[f][reg] - mt[reg]) : 0.f;
          pr[f][reg] = p;
          rs[reg] += p;
        }
      }
#pragma unroll
      for (int reg = 0; reg < 4; ++reg) {
        float rsum = rs[reg];
#pragma unroll
        for (int off = 1; off < 16; off <<= 1) rsum += __shfl_xor(rsum, off);
        lrun[br][reg] = lrun[br][reg] * al[reg] + rsum;
      }
      if (r15 == 0) {
#pragma unroll
        for (int reg = 0; reg < 4; ++reg)
          alpha_sh[(br * 4 + w) * 16 + rbase + reg] = al[reg];
      }
#pragma unroll
      for (int f = 0; f < 4; ++f)
#pragma unroll
        for (int reg = 0; reg < 4; ++reg)
          Ps[w * 16 + rbase + reg][f * 16 + r15] = (__bf16)pr[f][reg];

      float alr = alpha_sh[(br * 4 + w) * 16 + r15];
      bf16x8 bp0 = *(bf16x8*)&Ps[w * 16 + r15][kq];
      bf16x8 bp1 = *(bf16x8*)&Ps[w * 16 + r15][32 + kq];
#pragma unroll
      for (int df = 0; df < 4; ++df) {
        f32x4 o = accO[br][df] * alr;
        o = MFMA16(av[df][0], bp0, o);
        o = MFMA16(av[df][1], bp1, o);
        accO[br][df] = o;
      }
    }
  }

  __syncthreads();  // done with Ks/Vt before aliasing as Ot
  if (r15 == 0) {
#pragma unroll
    for (int br = 0; br < 2; ++br)
#pragma unroll
      for (int reg = 0; reg < 4; ++reg)
        lsum_sh[(br * 4 + w) * 16 + rbase + reg] = lrun[br][reg];
  }
  float* Otw = (float*)(smem + 9216) + w * (16 * 68);
  const int r2 = lane >> 2;
  const int dq = (lane & 3) * 16;
  const int i_out = qb * 64 + w * 16 + r2;
  const float* gp = gate + (size_t)i_out * GATE_LD + hg * 3;
  const float g0 = gp[0], g1 = gp[1], g2 = gp[2];
  float fv[16];
  {
    const bf16x8* cp = (const bf16x8*)(comp + (size_t)i_out * HQD_ + hg * 64 + dq);
    bf16x8 c0 = cp[0], c1 = cp[1];
#pragma unroll
    for (int e = 0; e < 8; ++e) {
      fv[e] = g0 * (float)c0[e];
      fv[8 + e] = g0 * (float)c1[e];
    }
  }
#pragma unroll
  for (int br = 0; br < 2; ++br) {
    const float linv = 1.f / lsum_sh[(br * 4 + w) * 16 + r15];
#pragma unroll
    for (int df = 0; df < 4; ++df)
#pragma unroll
      for (int reg = 0; reg < 4; ++reg)
        Otw[r15 * 68 + df * 16 + rbase + reg] = accO[br][df][reg] * linv;
    const float gg = (br == 0) ? g1 : g2;
#pragma unroll
    for (int e = 0; e < 16; ++e) fv[e] += gg * Otw[r2 * 68 + dq + e];
  }
  bf16x8 o0, o1;
#pragma unroll
  for (int e = 0; e < 8; ++e) {
    o0[e] = (__bf16)fv[e];
    o1[e] = (__bf16)fv[8 + e];
  }
  bf16x8* op = (bf16x8*)(fused + (size_t)i_out * HQD_ + hg * 64 + dq);
  op[0] = o0;
  op[1] = o1;
}

// ---------------------------------------------------------------------------
extern "C" void kernel_launch(void* const* d_in, const int* in_sizes, int n_in,
                              void* d_out, int out_size, void* d_ws, size_t ws_size,
                              hipStream_t stream)
{
  (void)in_sizes; (void)n_in; (void)out_size; (void)ws_size;
  const float* x = (const float*)d_in[0];
  const float* Wq = (const float*)d_in[2];
  const float* Wk = (const float*)d_in[3];
  const float* Wv = (const float*)d_in[4];
  const float* Wo = (const float*)d_in[5];
  const float* Wg = (const float*)d_in[6];
  const float* wck = (const float*)d_in[7];
  const float* wcv = (const float*)d_in[8];
  const float* pe = (const float*)d_in[9];

  char* ws = (char*)d_ws;
  size_t off = 0;
  auto alloc = [&](size_t b) {
    void* p = ws + off;
    off += (b + 255) & ~(size_t)255;
    return p;
  };
  __bf16* qbf = (__bf16*)alloc((size_t)T_ * HQD_ * 2);
  __bf16* kbf = (__bf16*)alloc((size_t)T_ * KVD_ * 2);
  __bf16* vbf = (__bf16*)alloc((size_t)T_ * KVD_ * 2);
  __bf16* vTbf = (__bf16*)alloc((size_t)T_ * KVD_ * 2);
  float* gatef = (float*)alloc((size_t)T_ * GATE_LD * 4);
  float* ckf = (float*)alloc((size_t)HKV_ * M_ * D_ * 4);
  float* cvf = (float*)alloc((size_t)HKV_ * M_ * D_ * 4);
  float* sf = (float*)alloc((size_t)HKV_ * T_ * M_ * 4);
  unsigned* selw = (unsigned*)alloc((size_t)HKV_ * T_ * 4);
  __bf16* compb = (__bf16*)alloc((size_t)T_ * HQD_ * 2);
  __bf16* fusedb = (__bf16*)alloc((size_t)T_ * HQD_ * 2);

  gemm_kernel<0, 0><<<dim3(16, 16), 256, 0, stream>>>(x, Wq, qbf, T_, HQD_, H_);
  gemm_kvg_kernel<<<dim3(3, 16), 256, 0, stream>>>(x, Wk, Wv, Wg, kbf, vbf, vTbf, gatef);
  ckcv_kernel<<<dim3(M_, HKV_), 64, 0, stream>>>(kbf, vbf, pe, wck, wcv, ckf, cvf);
  comp_kernel<<<dim3(T_ / 4, HKV_), 256, 0, stream>>>(qbf, ckf, cvf, compb, sf);
  topk_kernel<<<dim3(16), 256, 0, stream>>>(sf, selw);
  flash_kernel<<<dim3(32, 32), 256, 0, stream>>>(qbf, kbf, vTbf, selw, compb, gatef, fusedb);
  gemm_kernel<1, 2><<<dim3(16, 16), 256, 0, stream>>>(fusedb, Wo, d_out, T_, H_, HQD_);
}

// Round 2
// 778.141 us; speedup vs baseline: 1.2036x; 1.2036x over previous
//
#include <hip/hip_runtime.h>
#include <hip/hip_bf16.h>
#include <math.h>

#define T_ 2048
#define H_ 2048
#define HQ_ 32
#define HKV_ 2
#define D_ 64
#define G_ 16
#define M_ 32
#define TOPK_ 16
#define WINDOW_ 512
#define HQD_ 2048   // HQ*D
#define KVD_ 128    // HKV*D
#define GATE_LD 96  // HQ*3

typedef __attribute__((ext_vector_type(8))) __bf16 bf16x8;
typedef __attribute__((ext_vector_type(4))) float f32x4;

#define MFMA16(a, b, c) __builtin_amdgcn_mfma_f32_16x16x32_bf16((a), (b), (c), 0, 0, 0)

// ---------------------------------------------------------------------------
// fp32 -> bf16 elementwise convert (8 elems/thread)
// ---------------------------------------------------------------------------
__global__ __launch_bounds__(256) void cvt_bf16_kernel(const float* __restrict__ in,
                                                       __bf16* __restrict__ out, int n8)
{
  int i = blockIdx.x * blockDim.x + threadIdx.x;
  if (i >= n8) return;
  const float4* p = (const float4*)(in + (size_t)i * 8);
  float4 f0 = p[0], f1 = p[1];
  bf16x8 w = {(__bf16)f0.x, (__bf16)f0.y, (__bf16)f0.z, (__bf16)f0.w,
              (__bf16)f1.x, (__bf16)f1.y, (__bf16)f1.z, (__bf16)f1.w};
  *(bf16x8*)(out + (size_t)i * 8) = w;
}

// ---------------------------------------------------------------------------
// GEMM: C[M][N] = A[M][K](bf16) @ B[K][N](fp32, converted while staging).
// BM=BN=128, BK=32, 256 threads. OMODE: 0 = bf16 out, 2 = fp32 out.
// ---------------------------------------------------------------------------
template<int OMODE>
__global__ __launch_bounds__(256) void gemm_kernel(
    const __bf16* __restrict__ A, const float* __restrict__ B,
    void* __restrict__ Cv, int Ndim, int Kdim)
{
  __shared__ __bf16 As[128][40];
  __shared__ __bf16 Bs[128][40];
  const int tid = threadIdx.x;
  const int lane = tid & 63;
  const int w = tid >> 6;
  const int r15 = lane & 15;
  const int kq = (lane >> 4) * 8;
  const int m0 = blockIdx.y * 128;
  const int n0 = blockIdx.x * 128;

  const f32x4 fzero = {0.f, 0.f, 0.f, 0.f};
  f32x4 acc[2][8];
#pragma unroll
  for (int a = 0; a < 2; ++a)
#pragma unroll
    for (int b = 0; b < 8; ++b) acc[a][b] = fzero;

  const int ar = tid >> 1, akc = (tid & 1) * 16;
  const int bkr = tid >> 3, bnc = (tid & 7) * 16;

  for (int k0 = 0; k0 < Kdim; k0 += 32) {
    __syncthreads();
    {
      const __bf16* a = A + (size_t)(m0 + ar) * Kdim + k0 + akc;
      *(int4*)&As[ar][akc] = ((const int4*)a)[0];
      *(int4*)&As[ar][akc + 8] = ((const int4*)a)[1];
    }
    {
      const float* b = B + (size_t)(k0 + bkr) * Ndim + n0 + bnc;
      float4 f0 = ((const float4*)b)[0];
      float4 f1 = ((const float4*)b)[1];
      float4 f2 = ((const float4*)b)[2];
      float4 f3 = ((const float4*)b)[3];
      Bs[bnc + 0][bkr] = (__bf16)f0.x;  Bs[bnc + 1][bkr] = (__bf16)f0.y;
      Bs[bnc + 2][bkr] = (__bf16)f0.z;  Bs[bnc + 3][bkr] = (__bf16)f0.w;
      Bs[bnc + 4][bkr] = (__bf16)f1.x;  Bs[bnc + 5][bkr] = (__bf16)f1.y;
      Bs[bnc + 6][bkr] = (__bf16)f1.z;  Bs[bnc + 7][bkr] = (__bf16)f1.w;
      Bs[bnc + 8][bkr] = (__bf16)f2.x;  Bs[bnc + 9][bkr] = (__bf16)f2.y;
      Bs[bnc + 10][bkr] = (__bf16)f2.z; Bs[bnc + 11][bkr] = (__bf16)f2.w;
      Bs[bnc + 12][bkr] = (__bf16)f3.x; Bs[bnc + 13][bkr] = (__bf16)f3.y;
      Bs[bnc + 14][bkr] = (__bf16)f3.z; Bs[bnc + 15][bkr] = (__bf16)f3.w;
    }
    __syncthreads();
    bf16x8 af0 = *(bf16x8*)&As[w * 32 + r15][kq];
    bf16x8 af1 = *(bf16x8*)&As[w * 32 + 16 + r15][kq];
#pragma unroll
    for (int ni = 0; ni < 8; ++ni) {
      bf16x8 bfrag = *(bf16x8*)&Bs[ni * 16 + r15][kq];
      acc[0][ni] = MFMA16(af0, bfrag, acc[0][ni]);
      acc[1][ni] = MFMA16(af1, bfrag, acc[1][ni]);
    }
  }

#pragma unroll
  for (int mi = 0; mi < 2; ++mi)
#pragma unroll
    for (int ni = 0; ni < 8; ++ni)
#pragma unroll
      for (int reg = 0; reg < 4; ++reg) {
        int row = m0 + w * 32 + mi * 16 + (lane >> 4) * 4 + reg;
        int col = n0 + ni * 16 + r15;
        float v = acc[mi][ni][reg];
        if constexpr (OMODE == 0) {
          ((__bf16*)Cv)[(size_t)row * Ndim + col] = (__bf16)v;
        } else {
          ((float*)Cv)[(size_t)row * Ndim + col] = v;
        }
      }
}

// ---------------------------------------------------------------------------
// Fused K/V/Gate projection: blockIdx.x selects {0:K, 1:V(+V^T), 2:gate}.
// ---------------------------------------------------------------------------
__global__ __launch_bounds__(256) void gemm_kvg_kernel(
    const __bf16* __restrict__ xbf, const float* __restrict__ Wk,
    const float* __restrict__ Wv, const float* __restrict__ Wg,
    __bf16* __restrict__ kout, __bf16* __restrict__ vout,
    __bf16* __restrict__ vTout, float* __restrict__ gout)
{
  __shared__ __bf16 As[128][40];
  __shared__ __bf16 Bs[128][40];
  const int sel = blockIdx.x;  // 0=k,1=v,2=g
  const float* B = (sel == 0) ? Wk : (sel == 1) ? Wv : Wg;
  const int Ndim = (sel == 2) ? GATE_LD : KVD_;
  const int tid = threadIdx.x;
  const int lane = tid & 63;
  const int w = tid >> 6;
  const int r15 = lane & 15;
  const int kq = (lane >> 4) * 8;
  const int m0 = blockIdx.y * 128;

  const f32x4 fzero = {0.f, 0.f, 0.f, 0.f};
  f32x4 acc[2][8];
#pragma unroll
  for (int a = 0; a < 2; ++a)
#pragma unroll
    for (int b = 0; b < 8; ++b) acc[a][b] = fzero;

  const int ar = tid >> 1, akc = (tid & 1) * 16;
  const int bkr = tid >> 3, bnc = (tid & 7) * 16;

  for (int k0 = 0; k0 < H_; k0 += 32) {
    __syncthreads();
    {
      const __bf16* a = xbf + (size_t)(m0 + ar) * H_ + k0 + akc;
      *(int4*)&As[ar][akc] = ((const int4*)a)[0];
      *(int4*)&As[ar][akc + 8] = ((const int4*)a)[1];
    }
    if (sel < 2) {
      const float* b = B + (size_t)(k0 + bkr) * Ndim + bnc;
      float4 f0 = ((const float4*)b)[0];
      float4 f1 = ((const float4*)b)[1];
      float4 f2 = ((const float4*)b)[2];
      float4 f3 = ((const float4*)b)[3];
      Bs[bnc + 0][bkr] = (__bf16)f0.x;  Bs[bnc + 1][bkr] = (__bf16)f0.y;
      Bs[bnc + 2][bkr] = (__bf16)f0.z;  Bs[bnc + 3][bkr] = (__bf16)f0.w;
      Bs[bnc + 4][bkr] = (__bf16)f1.x;  Bs[bnc + 5][bkr] = (__bf16)f1.y;
      Bs[bnc + 6][bkr] = (__bf16)f1.z;  Bs[bnc + 7][bkr] = (__bf16)f1.w;
      Bs[bnc + 8][bkr] = (__bf16)f2.x;  Bs[bnc + 9][bkr] = (__bf16)f2.y;
      Bs[bnc + 10][bkr] = (__bf16)f2.z; Bs[bnc + 11][bkr] = (__bf16)f2.w;
      Bs[bnc + 12][bkr] = (__bf16)f3.x; Bs[bnc + 13][bkr] = (__bf16)f3.y;
      Bs[bnc + 14][bkr] = (__bf16)f3.z; Bs[bnc + 15][bkr] = (__bf16)f3.w;
    } else {
      const float* b = B + (size_t)(k0 + bkr) * Ndim + bnc;
#pragma unroll
      for (int e = 0; e < 16; ++e) {
        float val = (bnc + e < Ndim) ? b[e] : 0.f;
        Bs[bnc + e][bkr] = (__bf16)val;
      }
    }
    __syncthreads();
    bf16x8 af0 = *(bf16x8*)&As[w * 32 + r15][kq];
    bf16x8 af1 = *(bf16x8*)&As[w * 32 + 16 + r15][kq];
#pragma unroll
    for (int ni = 0; ni < 8; ++ni) {
      bf16x8 bfrag = *(bf16x8*)&Bs[ni * 16 + r15][kq];
      acc[0][ni] = MFMA16(af0, bfrag, acc[0][ni]);
      acc[1][ni] = MFMA16(af1, bfrag, acc[1][ni]);
    }
  }

#pragma unroll
  for (int mi = 0; mi < 2; ++mi)
#pragma unroll
    for (int ni = 0; ni < 8; ++ni)
#pragma unroll
      for (int reg = 0; reg < 4; ++reg) {
        int row = m0 + w * 32 + mi * 16 + (lane >> 4) * 4 + reg;
        int col = ni * 16 + r15;
        if (col >= Ndim) continue;
        float v = acc[mi][ni][reg];
        if (sel == 0) {
          kout[(size_t)row * KVD_ + col] = (__bf16)v;
        } else if (sel == 1) {
          vout[(size_t)row * KVD_ + col] = (__bf16)v;
          vTout[(size_t)col * T_ + row] = (__bf16)v;
        } else {
          gout[(size_t)row * GATE_LD + col] = 1.f / (1.f + __expf(-v));
        }
      }
}

// ---------------------------------------------------------------------------
// ck/cv pooling
// ---------------------------------------------------------------------------
__global__ void ckcv_kernel(const __bf16* __restrict__ kbf, const __bf16* __restrict__ vbf,
                            const float* __restrict__ pe, const float* __restrict__ wck,
                            const float* __restrict__ wcv, float* __restrict__ ckf,
                            float* __restrict__ cvf)
{
  const int m = blockIdx.x, h = blockIdx.y, d = threadIdx.x;
  float cka = 0.f, cva = 0.f;
  for (int t = 0; t < 64; ++t) {
    float kk = (float)kbf[(size_t)(m * 64 + t) * KVD_ + h * 64 + d];
    float vv = (float)vbf[(size_t)(m * 64 + t) * KVD_ + h * 64 + d];
    float pev = pe[((size_t)h * 64 + t) * 64 + d];
    cka += (kk + pev) * wck[h * 64 + t];
    cva += vv * wcv[h * 64 + t];
  }
  ckf[((size_t)h * M_ + m) * D_ + d] = cka;
  cvf[((size_t)h * M_ + m) * D_ + d] = cva;
}

// ---------------------------------------------------------------------------
// Compressed attention: wave per (i, h_kv); balanced i-swizzle.
// ---------------------------------------------------------------------------
__global__ __launch_bounds__(256) void comp_kernel(
    const __bf16* __restrict__ q, const float* __restrict__ ckf,
    const float* __restrict__ cvf, __bf16* __restrict__ comp,
    float* __restrict__ sout)
{
  __shared__ float cks[M_][65];
  __shared__ float cvs[M_][65];
  __shared__ float qv[4][64];
  __shared__ float pv_sh[4][32];
  const int h = blockIdx.y;
  const int tid = threadIdx.x, w = tid >> 6, lane = tid & 63;
  {
    int mm = tid >> 3, dc = (tid & 7) * 8;
#pragma unroll
    for (int e = 0; e < 8; ++e) {
      cks[mm][dc + e] = ckf[((size_t)h * M_ + mm) * D_ + dc + e];
      cvs[mm][dc + e] = cvf[((size_t)h * M_ + mm) * D_ + dc + e];
    }
  }
  __syncthreads();
  const int bid = blockIdx.x;
  const int ib = (bid & 1) ? (511 - (bid >> 1)) : (bid >> 1);  // balance
  const int i = ib * 4 + w;
  const int nvis = (i >= 63) ? ((i - 63) >> 6) + 1 : 0;
  float s_acc = 0.f;
  for (int g = 0; g < G_; ++g) {
    const int head = h * G_ + g;
    qv[w][lane] = (float)q[(size_t)i * HQD_ + head * 64 + lane];
    float lg = -1e30f;
    if (lane < nvis) {
      float a0 = 0.f, a1 = 0.f, a2 = 0.f, a3 = 0.f;
#pragma unroll
      for (int d2 = 0; d2 < 64; d2 += 4) {
        a0 += qv[w][d2] * cks[lane][d2];
        a1 += qv[w][d2 + 1] * cks[lane][d2 + 1];
        a2 += qv[w][d2 + 2] * cks[lane][d2 + 2];
        a3 += qv[w][d2 + 3] * cks[lane][d2 + 3];
      }
      lg = (a0 + a1 + a2 + a3) * 0.125f;
    }
    float mx = lg;
    for (int off = 1; off < 32; off <<= 1) mx = fmaxf(mx, __shfl_xor(mx, off));
    float p = (lane < nvis) ? __expf(lg - mx) : 0.f;
    float sum = p;
    for (int off = 1; off < 32; off <<= 1) sum += __shfl_xor(sum, off);
    float pn = (sum > 0.f) ? p / sum : 0.f;
    s_acc += pn;
    if (lane < 32) pv_sh[w][lane] = pn;
    float o = 0.f, o2 = 0.f;
    int m2 = 0;
    for (; m2 + 1 < nvis; m2 += 2) {
      o += pv_sh[w][m2] * cvs[m2][lane];
      o2 += pv_sh[w][m2 + 1] * cvs[m2 + 1][lane];
    }
    if (m2 < nvis) o += pv_sh[w][m2] * cvs[m2][lane];
    o += o2;
    comp[(size_t)i * HQD_ + head * 64 + lane] = (__bf16)o;
  }
  if (lane < 32) sout[((size_t)h * T_ + i) * M_ + lane] = s_acc;
}

// ---------------------------------------------------------------------------
// Top-k selection (stable) -> bitmask.
// ---------------------------------------------------------------------------
__global__ void topk_kernel(const float* __restrict__ sin, unsigned* __restrict__ sel)
{
  int idx = blockIdx.x * blockDim.x + threadIdx.x;
  if (idx >= HKV_ * T_) return;
  int h = idx >> 11, i = idx & (T_ - 1);
  int qblk = i >> 6;
  float sc[M_];
#pragma unroll
  for (int m = 0; m < M_; ++m) {
    if (m > qblk) sc[m] = -__builtin_inff();
    else if (m == 0 || m > qblk - 2) sc[m] = __builtin_inff();
    else sc[m] = sin[((size_t)h * T_ + i) * M_ + m];
  }
  unsigned picked = 0;
  for (int r = 0; r < TOPK_; ++r) {
    float best = -__builtin_inff();
    int bi = -1;
#pragma unroll
    for (int m = 0; m < M_; ++m) {
      if (!((picked >> m) & 1u) && sc[m] > best) { best = sc[m]; bi = m; }
    }
    if (bi < 0) break;
    picked |= 1u << bi;
  }
  sel[(size_t)h * T_ + i] = picked;
}

// ---------------------------------------------------------------------------
// Flash kernel, shared-exp version. 1D grid of 1024 with balance swizzle.
// For each active kb (except kb==qb-8): ONE shared p=exp(sv-rowmax) tile and
// ONE PV (into accP); branch states folded in with per-row scalar factors.
// ---------------------------------------------------------------------------
__global__ __launch_bounds__(256, 4) void flash_kernel(
    const __bf16* __restrict__ q, const __bf16* __restrict__ kg,
    const __bf16* __restrict__ vT, const unsigned* __restrict__ selg,
    const __bf16* __restrict__ comp, const float* __restrict__ gate,
    __bf16* __restrict__ fused)
{
  __shared__ alignas(16) char smem[38912];
  __bf16 (*Qs)[72] = (__bf16(*)[72])(smem);            // 9216
  __bf16 (*Ks)[72] = (__bf16(*)[72])(smem + 9216);     // 9216
  __bf16 (*Vt)[72] = (__bf16(*)[72])(smem + 18432);    // 9216
  __bf16 (*Ps)[72] = (__bf16(*)[72])(smem + 27648);    // 9216
  float* fA = (float*)(smem + 36864);                  // [2][64] alpha
  float* fF = (float*)(smem + 37376);                  // [2][64] fact
  float* lsum_sh = (float*)(smem + 37888);             // [2][64]
  unsigned* sel_sh = (unsigned*)(smem + 38400);        // [64]
  unsigned* union_p = (unsigned*)(smem + 38656);

  // balance swizzle: co-resident v-groups get qb sets {b, 31-b, b+16, 15-b}
  const int lin = blockIdx.x;
  const int slot = lin & 255;
  const int v = lin >> 8;
  const int base = slot & 31, hseg = slot >> 5;
  const int hg = hseg * 4 + v;
  const int b2 = (base + ((v >> 1) << 4)) & 31;
  const int qb = (v & 1) ? (31 - b2) : b2;
  const int h = hg >> 4;

  const int tid = threadIdx.x;
  const int lane = tid & 63;
  const int w = tid >> 6;
  const int r15 = lane & 15;
  const int kq = (lane >> 4) * 8;
  const int rbase = (lane >> 4) * 4;

  {
    int r = tid >> 2, dc = (tid & 3) * 16;
    const __bf16* src = q + (size_t)(qb * 64 + r) * HQD_ + hg * 64 + dc;
    *(int4*)&Qs[r][dc] = *(const int4*)src;
    *(int4*)&Qs[r][dc + 8] = *(const int4*)(src + 8);
  }
  if (tid < 64) sel_sh[tid] = selg[h * T_ + qb * 64 + tid];
  __syncthreads();
  if (tid == 0) {
    unsigned u = 0;
    for (int rr = 0; rr < 64; ++rr) u |= sel_sh[rr];
    *union_p = u;
  }
  __syncthreads();
  const unsigned ubits = *union_p;

  bf16x8 aq0 = *(bf16x8*)&Qs[w * 16 + r15][kq];
  bf16x8 aq1 = *(bf16x8*)&Qs[w * 16 + r15][32 + kq];
  unsigned selr[4];
#pragma unroll
  for (int reg = 0; reg < 4; ++reg) selr[reg] = sel_sh[w * 16 + rbase + reg];

  const f32x4 fzero = {0.f, 0.f, 0.f, 0.f};
  f32x4 accO[2][4];
  float mrun[2][4], lrun[2][4];
#pragma unroll
  for (int br = 0; br < 2; ++br)
#pragma unroll
    for (int a = 0; a < 4; ++a) {
      accO[br][a] = fzero;
      mrun[br][a] = -__builtin_inff();
      lrun[br][a] = 0.f;
    }

  for (int kb = 0; kb <= qb; ++kb) {
    const bool sp_act = (ubits >> kb) & 1u;
    const bool wn_act = (kb + 8) >= qb;
    const bool boundary = (kb + 8) == qb;
    if (!sp_act && !wn_act) continue;
    __syncthreads();
    {
      int t = tid >> 2, dc = (tid & 3) * 16;
      const __bf16* ksrc = kg + (size_t)(kb * 64 + t) * KVD_ + h * 64 + dc;
      *(int4*)&Ks[t][dc] = *(const int4*)ksrc;
      *(int4*)&Ks[t][dc + 8] = *(const int4*)(ksrc + 8);
      const __bf16* vsrc = vT + (size_t)(h * 64 + t) * T_ + kb * 64 + dc;
      *(int4*)&Vt[t][dc] = *(const int4*)vsrc;
      *(int4*)&Vt[t][dc + 8] = *(const int4*)(vsrc + 8);
    }
    __syncthreads();

    // QK^T -> s4 (in-place through the pipeline: sv -> p)
    f32x4 s4[4];
#pragma unroll
    for (int f = 0; f < 4; ++f) {
      bf16x8 b0 = *(bf16x8*)&Ks[f * 16 + r15][kq];
      bf16x8 b1 = *(bf16x8*)&Ks[f * 16 + r15][32 + kq];
      f32x4 s = fzero;
      s = MFMA16(aq0, b0, s);
      s = MFMA16(aq1, b1, s);
#pragma unroll
      for (int reg = 0; reg < 4; ++reg) s[reg] = s[reg] * 0.125f;
      s4[f] = s;
    }
    if (kb == qb) {  // shared causal mask on the diagonal
#pragma unroll
      for (int f = 0; f < 4; ++f) {
        const int t = f * 16 + r15;
#pragma unroll
        for (int reg = 0; reg < 4; ++reg) {
          const int r = w * 16 + rbase + reg;
          if (t > r) s4[f][reg] = -1e30f;
        }
      }
    }
    // row max (full row, shared by both branches)
    float rm[4];
#pragma unroll
    for (int reg = 0; reg < 4; ++reg)
      rm[reg] = fmaxf(fmaxf(s4[0][reg], s4[1][reg]), fmaxf(s4[2][reg], s4[3][reg]));
#pragma unroll
    for (int reg = 0; reg < 4; ++reg)
#pragma unroll
      for (int off = 1; off < 16; off <<= 1) rm[reg] = fmaxf(rm[reg], __shfl_xor(rm[reg], off));

    if (!boundary) {
      // ---------------- shared single-pass path ----------------
      float rs[4] = {0.f, 0.f, 0.f, 0.f};
#pragma unroll
      for (int f = 0; f < 4; ++f)
#pragma unroll
        for (int reg = 0; reg < 4; ++reg) {
          float p = __expf(s4[f][reg] - rm[reg]);
          s4[f][reg] = p;
          rs[reg] += p;
        }
#pragma unroll
      for (int reg = 0; reg < 4; ++reg)
#pragma unroll
        for (int off = 1; off < 16; off <<= 1) rs[reg] += __shfl_xor(rs[reg], off);

      // branch bookkeeping (uniform within 16-lane group)
      if (sp_act) {
        float aS[4], fS[4];
#pragma unroll
        for (int reg = 0; reg < 4; ++reg) {
          if ((selr[reg] >> kb) & 1u) {
            float mnew = fmaxf(mrun[0][reg], rm[reg]);
            aS[reg] = __expf(mrun[0][reg] - mnew);
            fS[reg] = __expf(rm[reg] - mnew);
            mrun[0][reg] = mnew;
            lrun[0][reg] = lrun[0][reg] * aS[reg] + rs[reg] * fS[reg];
          } else { aS[reg] = 1.f; fS[reg] = 0.f; }
        }
        if (r15 == 0)
#pragma unroll
          for (int reg = 0; reg < 4; ++reg) {
            fA[w * 16 + rbase + reg] = aS[reg];
            fF[w * 16 + rbase + reg] = fS[reg];
          }
      }
      if (wn_act) {
        float aW[4], fW[4];
#pragma unroll
        for (int reg = 0; reg < 4; ++reg) {
          float mnew = fmaxf(mrun[1][reg], rm[reg]);
          aW[reg] = __expf(mrun[1][reg] - mnew);
          fW[reg] = __expf(rm[reg] - mnew);
          mrun[1][reg] = mnew;
          lrun[1][reg] = lrun[1][reg] * aW[reg] + rs[reg] * fW[reg];
        }
        if (r15 == 0)
#pragma unroll
          for (int reg = 0; reg < 4; ++reg) {
            fA[64 + w * 16 + rbase + reg] = aW[reg];
            fF[64 + w * 16 + rbase + reg] = fW[reg];
          }
      }
      // shared P tile + single PV
#pragma unroll
      for (int f = 0; f < 4; ++f)
#pragma unroll
        for (int reg = 0; reg < 4; ++reg)
          Ps[w * 16 + rbase + reg][f * 16 + r15] = (__bf16)s4[f][reg];
      bf16x8 bp0 = *(bf16x8*)&Ps[w * 16 + r15][kq];
      bf16x8 bp1 = *(bf16x8*)&Ps[w * 16 + r15][32 + kq];
      f32x4 accP[4];
#pragma unroll
      for (int df = 0; df < 4; ++df) {
        bf16x8 av0 = *(bf16x8*)&Vt[df * 16 + r15][kq];
        bf16x8 av1 = *(bf16x8*)&Vt[df * 16 + r15][32 + kq];
        f32x4 t = MFMA16(av0, bp0, fzero);
        accP[df] = MFMA16(av1, bp1, t);
      }
      if (sp_act) {
        float aS = fA[w * 16 + r15], fS = fF[w * 16 + r15];
#pragma unroll
        for (int df = 0; df < 4; ++df)
#pragma unroll
          for (int reg = 0; reg < 4; ++reg)
            accO[0][df][reg] = accO[0][df][reg] * aS + accP[df][reg] * fS;
      }
      if (wn_act) {
        float aW = fA[64 + w * 16 + r15], fW = fF[64 + w * 16 + r15];
#pragma unroll
        for (int df = 0; df < 4; ++df)
#pragma unroll
          for (int reg = 0; reg < 4; ++reg)
            accO[1][df][reg] = accO[1][df][reg] * aW + accP[df][reg] * fW;
      }
    } else {
      // ---------------- boundary kb == qb-8: two-pass ----------------
      if (sp_act) {
        float pr[4][4];
        float rs[4] = {0.f, 0.f, 0.f, 0.f};
#pragma unroll
        for (int f = 0; f < 4; ++f)
#pragma unroll
          for (int reg = 0; reg < 4; ++reg) {
            float p = __expf(s4[f][reg] - rm[reg]);
            pr[f][reg] = p;
            rs[reg] += p;
          }
#pragma unroll
        for (int reg = 0; reg < 4; ++reg)
#pragma unroll
          for (int off = 1; off < 16; off <<= 1) rs[reg] += __shfl_xor(rs[reg], off);
        float aS[4], fS[4];
#pragma unroll
        for (int reg = 0; reg < 4; ++reg) {
          if ((selr[reg] >> kb) & 1u) {
            float mnew = fmaxf(mrun[0][reg], rm[reg]);
            aS[reg] = __expf(mrun[0][reg] - mnew);
            fS[reg] = __expf(rm[reg] - mnew);
            mrun[0][reg] = mnew;
            lrun[0][reg] = lrun[0][reg] * aS[reg] + rs[reg] * fS[reg];
          } else { aS[reg] = 1.f; fS[reg] = 0.f; }
        }
        if (r15 == 0)
#pragma unroll
          for (int reg = 0; reg < 4; ++reg) {
            fA[w * 16 + rbase + reg] = aS[reg];
            fF[w * 16 + rbase + reg] = fS[reg];
          }
#pragma unroll
        for (int f = 0; f < 4; ++f)
#pragma unroll
          for (int reg = 0; reg < 4; ++reg)
            Ps[w * 16 + rbase + reg][f * 16 + r15] = (__bf16)pr[f][reg];
        bf16x8 bp0 = *(bf16x8*)&Ps[w * 16 + r15][kq];
        bf16x8 bp1 = *(bf16x8*)&Ps[w * 16 + r15][32 + kq];
        float aSr = fA[w * 16 + r15], fSr = fF[w * 16 + r15];
#pragma unroll
        for (int df = 0; df < 4; ++df) {
          bf16x8 av0 = *(bf16x8*)&Vt[df * 16 + r15][kq];
          bf16x8 av1 = *(bf16x8*)&Vt[df * 16 + r15][kq + 32];
          f32x4 t = MFMA16(av0, bp0, fzero);
          f32x4 pv = MFMA16(av1, bp1, t);
#pragma unroll
          for (int reg = 0; reg < 4; ++reg)
            accO[0][df][reg] = accO[0][df][reg] * aSr + pv[reg] * fSr;
        }
      }
      // window pass: mask t >= r
#pragma unroll
      for (int f = 0; f < 4; ++f) {
        const int t = f * 16 + r15;
#pragma unroll
        for (int reg = 0; reg < 4; ++reg) {
          const int r = w * 16 + rbase + reg;
          if (t < r) s4[f][reg] = -1e30f;
        }
      }
      float rmw[4];
#pragma unroll
      for (int reg = 0; reg < 4; ++reg)
        rmw[reg] = fmaxf(fmaxf(s4[0][reg], s4[1][reg]), fmaxf(s4[2][reg], s4[3][reg]));
#pragma unroll
      for (int reg = 0; reg < 4; ++reg)
#pragma unroll
        for (int off = 1; off < 16; off <<= 1) rmw[reg] = fmaxf(rmw[reg], __shfl_xor(rmw[reg], off));
      float rs[4] = {0.f, 0.f, 0.f, 0.f};
#pragma unroll
      for (int f = 0; f < 4; ++f)
#pragma unroll
        for (int reg = 0; reg < 4; ++reg) {
          float p = __expf(s4[f][reg] - rmw[reg]);
          s4[f][reg] = p;
          rs[reg] += p;
        }
#pragma unroll
      for (int reg = 0; reg < 4; ++reg)
#pragma unroll
        for (int off = 1; off < 16; off <<= 1) rs[reg] += __shfl_xor(rs[reg], off);
      float aW[4], fW[4];
#pragma unroll
      for (int reg = 0; reg < 4; ++reg) {
        float mnew = fmaxf(mrun[1][reg], rmw[reg]);
        aW[reg] = __expf(mrun[1][reg] - mnew);
        fW[reg] = __expf(rmw[reg] - mnew);
        mrun[1][reg] = mnew;
        lrun[1][reg] = lrun[1][reg] * aW[reg] + rs[reg] * fW[reg];
      }
      if (r15 == 0)
#pragma unroll
        for (int reg = 0; reg < 4; ++reg) {
          fA[64 + w * 16 + rbase + reg] = aW[reg];
          fF[64 + w * 16 + rbase + reg] = fW[reg];
        }
#pragma unroll
      for (int f = 0; f < 4; ++f)
#pragma unroll
        for (int reg = 0; reg < 4; ++reg)
          Ps[w * 16 + rbase + reg][f * 16 + r15] = (__bf16)s4[f][reg];
      bf16x8 bp0 = *(bf16x8*)&Ps[w * 16 + r15][kq];
      bf16x8 bp1 = *(bf16x8*)&Ps[w * 16 + r15][32 + kq];
      float aWr = fA[64 + w * 16 + r15], fWr = fF[64 + w * 16 + r15];
#pragma unroll
      for (int df = 0; df < 4; ++df) {
        bf16x8 av0 = *(bf16x8*)&Vt[df * 16 + r15][kq];
        bf16x8 av1 = *(bf16x8*)&Vt[df * 16 + r15][kq + 32];
        f32x4 t = MFMA16(av0, bp0, fzero);
        f32x4 pv = MFMA16(av1, bp1, t);
#pragma unroll
        for (int reg = 0; reg < 4; ++reg)
          accO[1][df][reg] = accO[1][df][reg] * aWr + pv[reg] * fWr;
      }
    }
  }

  __syncthreads();  // done with Ks/Vt before aliasing as Ot
  if (r15 == 0) {
#pragma unroll
    for (int br = 0; br < 2; ++br)
#pragma unroll
      for (int reg = 0; reg < 4; ++reg)
        lsum_sh[br * 64 + w * 16 + rbase + reg] = lrun[br][reg];
  }
  float* Otw = (float*)(smem + 9216) + w * (16 * 68);
  const int r2 = lane >> 2;
  const int dq = (lane & 3) * 16;
  const int i_out = qb * 64 + w * 16 + r2;
  const float* gp = gate + (size_t)i_out * GATE_LD + hg * 3;
  const float g0 = gp[0], g1 = gp[1], g2 = gp[2];
  float fv[16];
  {
    const bf16x8* cp = (const bf16x8*)(comp + (size_t)i_out * HQD_ + hg * 64 + dq);
    bf16x8 c0 = cp[0], c1 = cp[1];
#pragma unroll
    for (int e = 0; e < 8; ++e) {
      fv[e] = g0 * (float)c0[e];
      fv[8 + e] = g0 * (float)c1[e];
    }
  }
#pragma unroll
  for (int br = 0; br < 2; ++br) {
    const float linv = 1.f / lsum_sh[br * 64 + w * 16 + r15];
#pragma unroll
    for (int df = 0; df < 4; ++df)
#pragma unroll
      for (int reg = 0; reg < 4; ++reg)
        Otw[r15 * 68 + df * 16 + rbase + reg] = accO[br][df][reg] * linv;
    const float gg = (br == 0) ? g1 : g2;
#pragma unroll
    for (int e = 0; e < 16; ++e) fv[e] += gg * Otw[r2 * 68 + dq + e];
  }
  bf16x8 o0, o1;
#pragma unroll
  for (int e = 0; e < 8; ++e) {
    o0[e] = (__bf16)fv[e];
    o1[e] = (__bf16)fv[8 + e];
  }
  bf16x8* op = (bf16x8*)(fused + (size_t)i_out * HQD_ + hg * 64 + dq);
  op[0] = o0;
  op[1] = o1;
}

// ---------------------------------------------------------------------------
extern "C" void kernel_launch(void* const* d_in, const int* in_sizes, int n_in,
                              void* d_out, int out_size, void* d_ws, size_t ws_size,
                              hipStream_t stream)
{
  (void)in_sizes; (void)n_in; (void)out_size; (void)ws_size;
  const float* x = (const float*)d_in[0];
  const float* Wq = (const float*)d_in[2];
  const float* Wk = (const float*)d_in[3];
  const float* Wv = (const float*)d_in[4];
  const float* Wo = (const float*)d_in[5];
  const float* Wg = (const float*)d_in[6];
  const float* wck = (const float*)d_in[7];
  const float* wcv = (const float*)d_in[8];
  const float* pe = (const float*)d_in[9];

  char* ws = (char*)d_ws;
  size_t off = 0;
  auto alloc = [&](size_t b) {
    void* p = ws + off;
    off += (b + 255) & ~(size_t)255;
    return p;
  };
  __bf16* xbf = (__bf16*)alloc((size_t)T_ * H_ * 2);
  __bf16* qbf = (__bf16*)alloc((size_t)T_ * HQD_ * 2);
  __bf16* kbf = (__bf16*)alloc((size_t)T_ * KVD_ * 2);
  __bf16* vbf = (__bf16*)alloc((size_t)T_ * KVD_ * 2);
  __bf16* vTbf = (__bf16*)alloc((size_t)T_ * KVD_ * 2);
  float* gatef = (float*)alloc((size_t)T_ * GATE_LD * 4);
  float* ckf = (float*)alloc((size_t)HKV_ * M_ * D_ * 4);
  float* cvf = (float*)alloc((size_t)HKV_ * M_ * D_ * 4);
  float* sf = (float*)alloc((size_t)HKV_ * T_ * M_ * 4);
  unsigned* selw = (unsigned*)alloc((size_t)HKV_ * T_ * 4);
  __bf16* compb = (__bf16*)alloc((size_t)T_ * HQD_ * 2);
  __bf16* fusedb = (__bf16*)alloc((size_t)T_ * HQD_ * 2);

  cvt_bf16_kernel<<<dim3((T_ * H_ / 8 + 255) / 256), 256, 0, stream>>>(x, xbf, T_ * H_ / 8);
  gemm_kernel<0><<<dim3(16, 16), 256, 0, stream>>>(xbf, Wq, qbf, HQD_, H_);
  gemm_kvg_kernel<<<dim3(3, 16), 256, 0, stream>>>(xbf, Wk, Wv, Wg, kbf, vbf, vTbf, gatef);
  ckcv_kernel<<<dim3(M_, HKV_), 64, 0, stream>>>(kbf, vbf, pe, wck, wcv, ckf, cvf);
  comp_kernel<<<dim3(T_ / 4, HKV_), 256, 0, stream>>>(qbf, ckf, cvf, compb, sf);
  topk_kernel<<<dim3(16), 256, 0, stream>>>(sf, selw);
  flash_kernel<<<dim3(1024), 256, 0, stream>>>(qbf, kbf, vTbf, selw, compb, gatef, fusedb);
  gemm_kernel<2><<<dim3(16, 16), 256, 0, stream>>>(fusedb, Wo, d_out, H_, HQD_);
}

// Round 3
// 589.060 us; speedup vs baseline: 1.5899x; 1.3210x over previous
//
#include <hip/hip_runtime.h>
#include <hip/hip_bf16.h>
#include <math.h>

#define T_ 2048
#define H_ 2048
#define HQ_ 32
#define HKV_ 2
#define D_ 64
#define G_ 16
#define M_ 32
#define TOPK_ 16
#define WINDOW_ 512
#define HQD_ 2048   // HQ*D
#define KVD_ 128    // HKV*D
#define GATE_LD 96  // HQ*3

typedef __attribute__((ext_vector_type(8))) __bf16 bf16x8;
typedef __attribute__((ext_vector_type(2))) __bf16 bf16x2;
typedef __attribute__((ext_vector_type(4))) float f32x4;

#define MFMA16(a, b, c) __builtin_amdgcn_mfma_f32_16x16x32_bf16((a), (b), (c), 0, 0, 0)

// ---------------------------------------------------------------------------
// fp32 -> bf16 elementwise convert (8 elems/thread)
// ---------------------------------------------------------------------------
__global__ __launch_bounds__(256) void cvt_bf16_kernel(const float* __restrict__ in,
                                                       __bf16* __restrict__ out, int n8)
{
  int i = blockIdx.x * blockDim.x + threadIdx.x;
  if (i >= n8) return;
  const float4* p = (const float4*)(in + (size_t)i * 8);
  float4 f0 = p[0], f1 = p[1];
  bf16x8 w = {(__bf16)f0.x, (__bf16)f0.y, (__bf16)f0.z, (__bf16)f0.w,
              (__bf16)f1.x, (__bf16)f1.y, (__bf16)f1.z, (__bf16)f1.w};
  *(bf16x8*)(out + (size_t)i * 8) = w;
}

// ---------------------------------------------------------------------------
// GEMM: C[M][N] = A[M][K](bf16) @ B[K][N](fp32, converted while staging).
// BM=BN=128, BK=32, 256 threads.
// OMODE: 0 = bf16 out, 2 = fp32 out, 3 = bf16 out scaled by 0.125 (Q proj).
// ---------------------------------------------------------------------------
template<int OMODE>
__global__ __launch_bounds__(256) void gemm_kernel(
    const __bf16* __restrict__ A, const float* __restrict__ B,
    void* __restrict__ Cv, int Ndim, int Kdim)
{
  __shared__ __bf16 As[128][40];
  __shared__ __bf16 Bs[128][40];
  const int tid = threadIdx.x;
  const int lane = tid & 63;
  const int w = tid >> 6;
  const int r15 = lane & 15;
  const int kq = (lane >> 4) * 8;
  const int m0 = blockIdx.y * 128;
  const int n0 = blockIdx.x * 128;

  const f32x4 fzero = {0.f, 0.f, 0.f, 0.f};
  f32x4 acc[2][8];
#pragma unroll
  for (int a = 0; a < 2; ++a)
#pragma unroll
    for (int b = 0; b < 8; ++b) acc[a][b] = fzero;

  const int ar = tid >> 1, akc = (tid & 1) * 16;
  const int bkr = tid >> 3, bnc = (tid & 7) * 16;

  for (int k0 = 0; k0 < Kdim; k0 += 32) {
    __syncthreads();
    {
      const __bf16* a = A + (size_t)(m0 + ar) * Kdim + k0 + akc;
      *(int4*)&As[ar][akc] = ((const int4*)a)[0];
      *(int4*)&As[ar][akc + 8] = ((const int4*)a)[1];
    }
    {
      const float* b = B + (size_t)(k0 + bkr) * Ndim + n0 + bnc;
      float4 f0 = ((const float4*)b)[0];
      float4 f1 = ((const float4*)b)[1];
      float4 f2 = ((const float4*)b)[2];
      float4 f3 = ((const float4*)b)[3];
      Bs[bnc + 0][bkr] = (__bf16)f0.x;  Bs[bnc + 1][bkr] = (__bf16)f0.y;
      Bs[bnc + 2][bkr] = (__bf16)f0.z;  Bs[bnc + 3][bkr] = (__bf16)f0.w;
      Bs[bnc + 4][bkr] = (__bf16)f1.x;  Bs[bnc + 5][bkr] = (__bf16)f1.y;
      Bs[bnc + 6][bkr] = (__bf16)f1.z;  Bs[bnc + 7][bkr] = (__bf16)f1.w;
      Bs[bnc + 8][bkr] = (__bf16)f2.x;  Bs[bnc + 9][bkr] = (__bf16)f2.y;
      Bs[bnc + 10][bkr] = (__bf16)f2.z; Bs[bnc + 11][bkr] = (__bf16)f2.w;
      Bs[bnc + 12][bkr] = (__bf16)f3.x; Bs[bnc + 13][bkr] = (__bf16)f3.y;
      Bs[bnc + 14][bkr] = (__bf16)f3.z; Bs[bnc + 15][bkr] = (__bf16)f3.w;
    }
    __syncthreads();
    bf16x8 af0 = *(bf16x8*)&As[w * 32 + r15][kq];
    bf16x8 af1 = *(bf16x8*)&As[w * 32 + 16 + r15][kq];
#pragma unroll
    for (int ni = 0; ni < 8; ++ni) {
      bf16x8 bfrag = *(bf16x8*)&Bs[ni * 16 + r15][kq];
      acc[0][ni] = MFMA16(af0, bfrag, acc[0][ni]);
      acc[1][ni] = MFMA16(af1, bfrag, acc[1][ni]);
    }
  }

#pragma unroll
  for (int mi = 0; mi < 2; ++mi)
#pragma unroll
    for (int ni = 0; ni < 8; ++ni)
#pragma unroll
      for (int reg = 0; reg < 4; ++reg) {
        int row = m0 + w * 32 + mi * 16 + (lane >> 4) * 4 + reg;
        int col = n0 + ni * 16 + r15;
        float v = acc[mi][ni][reg];
        if constexpr (OMODE == 0) {
          ((__bf16*)Cv)[(size_t)row * Ndim + col] = (__bf16)v;
        } else if constexpr (OMODE == 3) {
          ((__bf16*)Cv)[(size_t)row * Ndim + col] = (__bf16)(v * 0.125f);
        } else {
          ((float*)Cv)[(size_t)row * Ndim + col] = v;
        }
      }
}

// ---------------------------------------------------------------------------
// Fused K/V/Gate projection: blockIdx.x selects {0:K, 1:V(+V^T), 2:gate}.
// ---------------------------------------------------------------------------
__global__ __launch_bounds__(256) void gemm_kvg_kernel(
    const __bf16* __restrict__ xbf, const float* __restrict__ Wk,
    const float* __restrict__ Wv, const float* __restrict__ Wg,
    __bf16* __restrict__ kout, __bf16* __restrict__ vout,
    __bf16* __restrict__ vTout, float* __restrict__ gout)
{
  __shared__ __bf16 As[128][40];
  __shared__ __bf16 Bs[128][40];
  const int sel = blockIdx.x;  // 0=k,1=v,2=g
  const float* B = (sel == 0) ? Wk : (sel == 1) ? Wv : Wg;
  const int Ndim = (sel == 2) ? GATE_LD : KVD_;
  const int tid = threadIdx.x;
  const int lane = tid & 63;
  const int w = tid >> 6;
  const int r15 = lane & 15;
  const int kq = (lane >> 4) * 8;
  const int m0 = blockIdx.y * 128;

  const f32x4 fzero = {0.f, 0.f, 0.f, 0.f};
  f32x4 acc[2][8];
#pragma unroll
  for (int a = 0; a < 2; ++a)
#pragma unroll
    for (int b = 0; b < 8; ++b) acc[a][b] = fzero;

  const int ar = tid >> 1, akc = (tid & 1) * 16;
  const int bkr = tid >> 3, bnc = (tid & 7) * 16;

  for (int k0 = 0; k0 < H_; k0 += 32) {
    __syncthreads();
    {
      const __bf16* a = xbf + (size_t)(m0 + ar) * H_ + k0 + akc;
      *(int4*)&As[ar][akc] = ((const int4*)a)[0];
      *(int4*)&As[ar][akc + 8] = ((const int4*)a)[1];
    }
    if (sel < 2) {
      const float* b = B + (size_t)(k0 + bkr) * Ndim + bnc;
      float4 f0 = ((const float4*)b)[0];
      float4 f1 = ((const float4*)b)[1];
      float4 f2 = ((const float4*)b)[2];
      float4 f3 = ((const float4*)b)[3];
      Bs[bnc + 0][bkr] = (__bf16)f0.x;  Bs[bnc + 1][bkr] = (__bf16)f0.y;
      Bs[bnc + 2][bkr] = (__bf16)f0.z;  Bs[bnc + 3][bkr] = (__bf16)f0.w;
      Bs[bnc + 4][bkr] = (__bf16)f1.x;  Bs[bnc + 5][bkr] = (__bf16)f1.y;
      Bs[bnc + 6][bkr] = (__bf16)f1.z;  Bs[bnc + 7][bkr] = (__bf16)f1.w;
      Bs[bnc + 8][bkr] = (__bf16)f2.x;  Bs[bnc + 9][bkr] = (__bf16)f2.y;
      Bs[bnc + 10][bkr] = (__bf16)f2.z; Bs[bnc + 11][bkr] = (__bf16)f2.w;
      Bs[bnc + 12][bkr] = (__bf16)f3.x; Bs[bnc + 13][bkr] = (__bf16)f3.y;
      Bs[bnc + 14][bkr] = (__bf16)f3.z; Bs[bnc + 15][bkr] = (__bf16)f3.w;
    } else {
      const float* b = B + (size_t)(k0 + bkr) * Ndim + bnc;
#pragma unroll
      for (int e = 0; e < 16; ++e) {
        float val = (bnc + e < Ndim) ? b[e] : 0.f;
        Bs[bnc + e][bkr] = (__bf16)val;
      }
    }
    __syncthreads();
    bf16x8 af0 = *(bf16x8*)&As[w * 32 + r15][kq];
    bf16x8 af1 = *(bf16x8*)&As[w * 32 + 16 + r15][kq];
#pragma unroll
    for (int ni = 0; ni < 8; ++ni) {
      bf16x8 bfrag = *(bf16x8*)&Bs[ni * 16 + r15][kq];
      acc[0][ni] = MFMA16(af0, bfrag, acc[0][ni]);
      acc[1][ni] = MFMA16(af1, bfrag, acc[1][ni]);
    }
  }

#pragma unroll
  for (int mi = 0; mi < 2; ++mi)
#pragma unroll
    for (int ni = 0; ni < 8; ++ni)
#pragma unroll
      for (int reg = 0; reg < 4; ++reg) {
        int row = m0 + w * 32 + mi * 16 + (lane >> 4) * 4 + reg;
        int col = ni * 16 + r15;
        if (col >= Ndim) continue;
        float v = acc[mi][ni][reg];
        if (sel == 0) {
          kout[(size_t)row * KVD_ + col] = (__bf16)v;
        } else if (sel == 1) {
          vout[(size_t)row * KVD_ + col] = (__bf16)v;
          vTout[(size_t)col * T_ + row] = (__bf16)v;
        } else {
          gout[(size_t)row * GATE_LD + col] = 1.f / (1.f + __expf(-v));
        }
      }
}

// ---------------------------------------------------------------------------
// ck/cv pooling
// ---------------------------------------------------------------------------
__global__ void ckcv_kernel(const __bf16* __restrict__ kbf, const __bf16* __restrict__ vbf,
                            const float* __restrict__ pe, const float* __restrict__ wck,
                            const float* __restrict__ wcv, float* __restrict__ ckf,
                            float* __restrict__ cvf)
{
  const int m = blockIdx.x, h = blockIdx.y, d = threadIdx.x;
  float cka = 0.f, cva = 0.f;
  for (int t = 0; t < 64; ++t) {
    float kk = (float)kbf[(size_t)(m * 64 + t) * KVD_ + h * 64 + d];
    float vv = (float)vbf[(size_t)(m * 64 + t) * KVD_ + h * 64 + d];
    float pev = pe[((size_t)h * 64 + t) * 64 + d];
    cka += (kk + pev) * wck[h * 64 + t];
    cva += vv * wcv[h * 64 + t];
  }
  ckf[((size_t)h * M_ + m) * D_ + d] = cka;
  cvf[((size_t)h * M_ + m) * D_ + d] = cva;
}

// ---------------------------------------------------------------------------
// Compressed attention: wave per (i, h_kv); balanced i-swizzle.
// q is pre-scaled by 0.125 so logits need no extra scale.
// ---------------------------------------------------------------------------
__global__ __launch_bounds__(256) void comp_kernel(
    const __bf16* __restrict__ q, const float* __restrict__ ckf,
    const float* __restrict__ cvf, __bf16* __restrict__ comp,
    float* __restrict__ sout)
{
  __shared__ float cks[M_][65];
  __shared__ float cvs[M_][65];
  __shared__ float qv[4][64];
  __shared__ float pv_sh[4][32];
  const int h = blockIdx.y;
  const int tid = threadIdx.x, w = tid >> 6, lane = tid & 63;
  {
    int mm = tid >> 3, dc = (tid & 7) * 8;
#pragma unroll
    for (int e = 0; e < 8; ++e) {
      cks[mm][dc + e] = ckf[((size_t)h * M_ + mm) * D_ + dc + e];
      cvs[mm][dc + e] = cvf[((size_t)h * M_ + mm) * D_ + dc + e];
    }
  }
  __syncthreads();
  const int bid = blockIdx.x;
  const int ib = (bid & 1) ? (511 - (bid >> 1)) : (bid >> 1);  // balance
  const int i = ib * 4 + w;
  const int nvis = (i >= 63) ? ((i - 63) >> 6) + 1 : 0;
  float s_acc = 0.f;
  for (int g = 0; g < G_; ++g) {
    const int head = h * G_ + g;
    qv[w][lane] = (float)q[(size_t)i * HQD_ + head * 64 + lane];
    float lg = -1e30f;
    if (lane < nvis) {
      float a0 = 0.f, a1 = 0.f, a2 = 0.f, a3 = 0.f;
#pragma unroll
      for (int d2 = 0; d2 < 64; d2 += 4) {
        a0 += qv[w][d2] * cks[lane][d2];
        a1 += qv[w][d2 + 1] * cks[lane][d2 + 1];
        a2 += qv[w][d2 + 2] * cks[lane][d2 + 2];
        a3 += qv[w][d2 + 3] * cks[lane][d2 + 3];
      }
      lg = a0 + a1 + a2 + a3;
    }
    float mx = lg;
    for (int off = 1; off < 32; off <<= 1) mx = fmaxf(mx, __shfl_xor(mx, off));
    float p = (lane < nvis) ? __expf(lg - mx) : 0.f;
    float sum = p;
    for (int off = 1; off < 32; off <<= 1) sum += __shfl_xor(sum, off);
    float pn = (sum > 0.f) ? p / sum : 0.f;
    s_acc += pn;
    if (lane < 32) pv_sh[w][lane] = pn;
    float o = 0.f, o2 = 0.f;
    int m2 = 0;
    for (; m2 + 1 < nvis; m2 += 2) {
      o += pv_sh[w][m2] * cvs[m2][lane];
      o2 += pv_sh[w][m2 + 1] * cvs[m2 + 1][lane];
    }
    if (m2 < nvis) o += pv_sh[w][m2] * cvs[m2][lane];
    o += o2;
    comp[(size_t)i * HQD_ + head * 64 + lane] = (__bf16)o;
  }
  if (lane < 32) sout[((size_t)h * T_ + i) * M_ + lane] = s_acc;
}

// ---------------------------------------------------------------------------
// Top-k selection (stable) -> bitmask.
// ---------------------------------------------------------------------------
__global__ void topk_kernel(const float* __restrict__ sin, unsigned* __restrict__ sel)
{
  int idx = blockIdx.x * blockDim.x + threadIdx.x;
  if (idx >= HKV_ * T_) return;
  int h = idx >> 11, i = idx & (T_ - 1);
  int qblk = i >> 6;
  float sc[M_];
#pragma unroll
  for (int m = 0; m < M_; ++m) {
    if (m > qblk) sc[m] = -__builtin_inff();
    else if (m == 0 || m > qblk - 2) sc[m] = __builtin_inff();
    else sc[m] = sin[((size_t)h * T_ + i) * M_ + m];
  }
  unsigned picked = 0;
  for (int r = 0; r < TOPK_; ++r) {
    float best = -__builtin_inff();
    int bi = -1;
#pragma unroll
    for (int m = 0; m < M_; ++m) {
      if (!((picked >> m) & 1u) && sc[m] > best) { best = sc[m]; bi = m; }
    }
    if (bi < 0) break;
    picked |= 1u << bi;
  }
  sel[(size_t)h * T_ + i] = picked;
}

// ---------------------------------------------------------------------------
// Flash kernel, swapped-QK^T (S^T = K·Q^T) so each lane owns ONE query row
// (col = lane&15). Per-lane m/l/alpha bookkeeping, 2-shuffle row reductions,
// packed bf16x2 P-tile writes. Shared exp+PV across both branches except at
// the single window-boundary block. q pre-scaled by 0.125.
// ---------------------------------------------------------------------------
__global__ __launch_bounds__(256) void flash_kernel(
    const __bf16* __restrict__ q, const __bf16* __restrict__ kg,
    const __bf16* __restrict__ vT, const unsigned* __restrict__ selg,
    const __bf16* __restrict__ comp, const float* __restrict__ gate,
    __bf16* __restrict__ fused)
{
  __shared__ alignas(16) char smem[37120];
  __bf16 (*Qs)[72] = (__bf16(*)[72])(smem);            // 9216
  __bf16 (*Ks)[72] = (__bf16(*)[72])(smem + 9216);     // 9216 (t rows)
  __bf16 (*Vt)[72] = (__bf16(*)[72])(smem + 18432);    // 9216 (d rows)
  __bf16 (*Ps)[72] = (__bf16(*)[72])(smem + 27648);    // 9216 (q rows x t)
  unsigned* sel_sh = (unsigned*)(smem + 36864);        // [64]

  // balance swizzle: co-resident v-groups get qb sets {b, 31-b, b+16, 15-b}
  const int lin = blockIdx.x;
  const int slot = lin & 255;
  const int v = lin >> 8;
  const int base = slot & 31, hseg = slot >> 5;
  const int hg = hseg * 4 + v;
  const int b2 = (base + ((v >> 1) << 4)) & 31;
  const int qb = (v & 1) ? (31 - b2) : b2;
  const int h = hg >> 4;

  const int tid = threadIdx.x;
  const int lane = tid & 63;
  const int w = tid >> 6;
  const int r15 = lane & 15;
  const int kq = (lane >> 4) * 8;
  const int rbase = (lane >> 4) * 4;
  const int myrow = w * 16 + r15;   // this lane's query row (within 64-block)

  {
    int r = tid >> 2, dc = (tid & 3) * 16;
    const __bf16* src = q + (size_t)(qb * 64 + r) * HQD_ + hg * 64 + dc;
    *(int4*)&Qs[r][dc] = *(const int4*)src;
    *(int4*)&Qs[r][dc + 8] = *(const int4*)(src + 8);
  }
  if (tid < 64) sel_sh[tid] = selg[h * T_ + qb * 64 + tid];
  __syncthreads();
  unsigned ubits = sel_sh[lane];
#pragma unroll
  for (int off = 1; off < 64; off <<= 1) ubits |= __shfl_xor(ubits, off);

  bf16x8 aq0 = *(bf16x8*)&Qs[myrow][kq];
  bf16x8 aq1 = *(bf16x8*)&Qs[myrow][32 + kq];
  const unsigned selrow = sel_sh[myrow];   // per-lane row's selected blocks

  const f32x4 fzero = {0.f, 0.f, 0.f, 0.f};
  f32x4 accO[2][4];
#pragma unroll
  for (int br = 0; br < 2; ++br)
#pragma unroll
    for (int a = 0; a < 4; ++a) accO[br][a] = fzero;
  float mrun0 = -__builtin_inff(), mrun1 = -__builtin_inff();
  float lrun0 = 0.f, lrun1 = 0.f;

  for (int kb = 0; kb <= qb; ++kb) {
    const bool sp_act = (ubits >> kb) & 1u;
    const bool wn_act = (kb + 8) >= qb;
    const bool boundary = (kb + 8) == qb;
    if (!sp_act && !wn_act) continue;
    __syncthreads();
    {
      int t = tid >> 2, dc = (tid & 3) * 16;
      const __bf16* ksrc = kg + (size_t)(kb * 64 + t) * KVD_ + h * 64 + dc;
      *(int4*)&Ks[t][dc] = *(const int4*)ksrc;
      *(int4*)&Ks[t][dc + 8] = *(const int4*)(ksrc + 8);
      const __bf16* vsrc = vT + (size_t)(h * 64 + t) * T_ + kb * 64 + dc;
      *(int4*)&Vt[t][dc] = *(const int4*)vsrc;
      *(int4*)&Vt[t][dc + 8] = *(const int4*)(vsrc + 8);
    }
    __syncthreads();

    // S^T: A = K-frag (rows t), B = Q-frag (cols = q rows). Lane: col=r15,
    // rows t = f*16 + rbase + reg.
    float st[4][4];
#pragma unroll
    for (int f = 0; f < 4; ++f) {
      bf16x8 kf0 = *(bf16x8*)&Ks[f * 16 + r15][kq];
      bf16x8 kf1 = *(bf16x8*)&Ks[f * 16 + r15][32 + kq];
      f32x4 s = MFMA16(kf0, aq0, fzero);
      s = MFMA16(kf1, aq1, s);
#pragma unroll
      for (int reg = 0; reg < 4; ++reg) st[f][reg] = s[reg];
    }
    if (kb == qb) {  // causal diagonal mask: t > myrow -> -inf
#pragma unroll
      for (int f = 0; f < 4; ++f)
#pragma unroll
        for (int reg = 0; reg < 4; ++reg)
          if (f * 16 + rbase + reg > myrow) st[f][reg] = -1e30f;
    }

    if (!boundary) {
      // ---- shared single-pass: one exp tile + one PV for both branches ----
      float rm = -1e30f;
#pragma unroll
      for (int f = 0; f < 4; ++f)
#pragma unroll
        for (int reg = 0; reg < 4; ++reg) rm = fmaxf(rm, st[f][reg]);
      rm = fmaxf(rm, __shfl_xor(rm, 16));
      rm = fmaxf(rm, __shfl_xor(rm, 32));
      float rsum = 0.f;
#pragma unroll
      for (int f = 0; f < 4; ++f)
#pragma unroll
        for (int reg = 0; reg < 4; ++reg) {
          float p = __expf(st[f][reg] - rm);
          st[f][reg] = p;
          rsum += p;
        }
      rsum += __shfl_xor(rsum, 16);
      rsum += __shfl_xor(rsum, 32);

      float aS = 1.f, fS = 0.f, aW = 1.f, fW = 0.f;
      if (sp_act && ((selrow >> kb) & 1u)) {
        float mnew = fmaxf(mrun0, rm);
        aS = __expf(mrun0 - mnew);
        fS = __expf(rm - mnew);
        mrun0 = mnew;
        lrun0 = lrun0 * aS + rsum * fS;
      }
      if (wn_act) {
        float mnew = fmaxf(mrun1, rm);
        aW = __expf(mrun1 - mnew);
        fW = __expf(rm - mnew);
        mrun1 = mnew;
        lrun1 = lrun1 * aW + rsum * fW;
      }
      // packed P write: Ps[qrow][t]
#pragma unroll
      for (int f = 0; f < 4; ++f)
#pragma unroll
        for (int c = 0; c < 2; ++c) {
          bf16x2 pk = {(__bf16)st[f][2 * c], (__bf16)st[f][2 * c + 1]};
          *(bf16x2*)&Ps[myrow][f * 16 + rbase + 2 * c] = pk;
        }
      bf16x8 bp0 = *(bf16x8*)&Ps[myrow][kq];
      bf16x8 bp1 = *(bf16x8*)&Ps[myrow][32 + kq];
      f32x4 accP[4];
#pragma unroll
      for (int df = 0; df < 4; ++df) {
        bf16x8 av0 = *(bf16x8*)&Vt[df * 16 + r15][kq];
        bf16x8 av1 = *(bf16x8*)&Vt[df * 16 + r15][32 + kq];
        f32x4 t = MFMA16(av0, bp0, fzero);
        accP[df] = MFMA16(av1, bp1, t);
      }
      if (sp_act) {
#pragma unroll
        for (int df = 0; df < 4; ++df)
#pragma unroll
          for (int reg = 0; reg < 4; ++reg)
            accO[0][df][reg] = accO[0][df][reg] * aS + accP[df][reg] * fS;
      }
      if (wn_act) {
#pragma unroll
        for (int df = 0; df < 4; ++df)
#pragma unroll
          for (int reg = 0; reg < 4; ++reg)
            accO[1][df][reg] = accO[1][df][reg] * aW + accP[df][reg] * fW;
      }
    } else {
      // ---- boundary kb == qb-8: two passes (different masks) ----
      if (sp_act) {
        float rm = -1e30f;
#pragma unroll
        for (int f = 0; f < 4; ++f)
#pragma unroll
          for (int reg = 0; reg < 4; ++reg) rm = fmaxf(rm, st[f][reg]);
        rm = fmaxf(rm, __shfl_xor(rm, 16));
        rm = fmaxf(rm, __shfl_xor(rm, 32));
        float rsum = 0.f;
        float pw[4][4];
#pragma unroll
        for (int f = 0; f < 4; ++f)
#pragma unroll
          for (int reg = 0; reg < 4; ++reg) {
            float p = __expf(st[f][reg] - rm);
            pw[f][reg] = p;
            rsum += p;
          }
        rsum += __shfl_xor(rsum, 16);
        rsum += __shfl_xor(rsum, 32);
        float aS = 1.f, fS = 0.f;
        if ((selrow >> kb) & 1u) {
          float mnew = fmaxf(mrun0, rm);
          aS = __expf(mrun0 - mnew);
          fS = __expf(rm - mnew);
          mrun0 = mnew;
          lrun0 = lrun0 * aS + rsum * fS;
        }
#pragma unroll
        for (int f = 0; f < 4; ++f)
#pragma unroll
          for (int c = 0; c < 2; ++c) {
            bf16x2 pk = {(__bf16)pw[f][2 * c], (__bf16)pw[f][2 * c + 1]};
            *(bf16x2*)&Ps[myrow][f * 16 + rbase + 2 * c] = pk;
          }
        bf16x8 bp0 = *(bf16x8*)&Ps[myrow][kq];
        bf16x8 bp1 = *(bf16x8*)&Ps[myrow][32 + kq];
#pragma unroll
        for (int df = 0; df < 4; ++df) {
          bf16x8 av0 = *(bf16x8*)&Vt[df * 16 + r15][kq];
          bf16x8 av1 = *(bf16x8*)&Vt[df * 16 + r15][32 + kq];
          f32x4 t = MFMA16(av0, bp0, fzero);
          f32x4 pv = MFMA16(av1, bp1, t);
#pragma unroll
          for (int reg = 0; reg < 4; ++reg)
            accO[0][df][reg] = accO[0][df][reg] * aS + pv[reg] * fS;
        }
      }
      // window pass: keep t >= myrow
#pragma unroll
      for (int f = 0; f < 4; ++f)
#pragma unroll
        for (int reg = 0; reg < 4; ++reg)
          if (f * 16 + rbase + reg < myrow) st[f][reg] = -1e30f;
      float rm = -1e30f;
#pragma unroll
      for (int f = 0; f < 4; ++f)
#pragma unroll
        for (int reg = 0; reg < 4; ++reg) rm = fmaxf(rm, st[f][reg]);
      rm = fmaxf(rm, __shfl_xor(rm, 16));
      rm = fmaxf(rm, __shfl_xor(rm, 32));
      float rsum = 0.f;
#pragma unroll
      for (int f = 0; f < 4; ++f)
#pragma unroll
        for (int reg = 0; reg < 4; ++reg) {
          float p = __expf(st[f][reg] - rm);
          st[f][reg] = p;
          rsum += p;
        }
      rsum += __shfl_xor(rsum, 16);
      rsum += __shfl_xor(rsum, 32);
      float mnew = fmaxf(mrun1, rm);
      float aW = __expf(mrun1 - mnew);
      float fW = __expf(rm - mnew);
      mrun1 = mnew;
      lrun1 = lrun1 * aW + rsum * fW;
#pragma unroll
      for (int f = 0; f < 4; ++f)
#pragma unroll
        for (int c = 0; c < 2; ++c) {
          bf16x2 pk = {(__bf16)st[f][2 * c], (__bf16)st[f][2 * c + 1]};
          *(bf16x2*)&Ps[myrow][f * 16 + rbase + 2 * c] = pk;
        }
      bf16x8 bp0 = *(bf16x8*)&Ps[myrow][kq];
      bf16x8 bp1 = *(bf16x8*)&Ps[myrow][32 + kq];
#pragma unroll
      for (int df = 0; df < 4; ++df) {
        bf16x8 av0 = *(bf16x8*)&Vt[df * 16 + r15][kq];
        bf16x8 av1 = *(bf16x8*)&Vt[df * 16 + r15][32 + kq];
        f32x4 t = MFMA16(av0, bp0, fzero);
        f32x4 pv = MFMA16(av1, bp1, t);
#pragma unroll
        for (int reg = 0; reg < 4; ++reg)
          accO[1][df][reg] = accO[1][df][reg] * aW + pv[reg] * fW;
      }
    }
  }

  __syncthreads();  // all waves done with Ks/Vt before aliasing as Otw
  float* Otw = (float*)(smem + 9216) + w * (16 * 68);
  const int r2 = lane >> 2;
  const int dq = (lane & 3) * 16;
  const int i_out = qb * 64 + w * 16 + r2;
  const float* gp = gate + (size_t)i_out * GATE_LD + hg * 3;
  const float g0 = gp[0], g1 = gp[1], g2 = gp[2];
  float fv[16];
  {
    const bf16x8* cp = (const bf16x8*)(comp + (size_t)i_out * HQD_ + hg * 64 + dq);
    bf16x8 c0 = cp[0], c1 = cp[1];
#pragma unroll
    for (int e = 0; e < 8; ++e) {
      fv[e] = g0 * (float)c0[e];
      fv[8 + e] = g0 * (float)c1[e];
    }
  }
  const float linv0 = 1.f / lrun0;
  const float linv1 = 1.f / lrun1;
#pragma unroll
  for (int br = 0; br < 2; ++br) {
    const float linv = (br == 0) ? linv0 : linv1;
#pragma unroll
    for (int df = 0; df < 4; ++df)
#pragma unroll
      for (int reg = 0; reg < 4; ++reg)
        Otw[r15 * 68 + df * 16 + rbase + reg] = accO[br][df][reg] * linv;
    const float gg = (br == 0) ? g1 : g2;
#pragma unroll
    for (int e = 0; e < 16; ++e) fv[e] += gg * Otw[r2 * 68 + dq + e];
  }
  bf16x8 o0, o1;
#pragma unroll
  for (int e = 0; e < 8; ++e) {
    o0[e] = (__bf16)fv[e];
    o1[e] = (__bf16)fv[8 + e];
  }
  bf16x8* op = (bf16x8*)(fused + (size_t)i_out * HQD_ + hg * 64 + dq);
  op[0] = o0;
  op[1] = o1;
}

// ---------------------------------------------------------------------------
extern "C" void kernel_launch(void* const* d_in, const int* in_sizes, int n_in,
                              void* d_out, int out_size, void* d_ws, size_t ws_size,
                              hipStream_t stream)
{
  (void)in_sizes; (void)n_in; (void)out_size; (void)ws_size;
  const float* x = (const float*)d_in[0];
  const float* Wq = (const float*)d_in[2];
  const float* Wk = (const float*)d_in[3];
  const float* Wv = (const float*)d_in[4];
  const float* Wo = (const float*)d_in[5];
  const float* Wg = (const float*)d_in[6];
  const float* wck = (const float*)d_in[7];
  const float* wcv = (const float*)d_in[8];
  const float* pe = (const float*)d_in[9];

  char* ws = (char*)d_ws;
  size_t off = 0;
  auto alloc = [&](size_t b) {
    void* p = ws + off;
    off += (b + 255) & ~(size_t)255;
    return p;
  };
  __bf16* xbf = (__bf16*)alloc((size_t)T_ * H_ * 2);
  __bf16* qbf = (__bf16*)alloc((size_t)T_ * HQD_ * 2);
  __bf16* kbf = (__bf16*)alloc((size_t)T_ * KVD_ * 2);
  __bf16* vbf = (__bf16*)alloc((size_t)T_ * KVD_ * 2);
  __bf16* vTbf = (__bf16*)alloc((size_t)T_ * KVD_ * 2);
  float* gatef = (float*)alloc((size_t)T_ * GATE_LD * 4);
  float* ckf = (float*)alloc((size_t)HKV_ * M_ * D_ * 4);
  float* cvf = (float*)alloc((size_t)HKV_ * M_ * D_ * 4);
  float* sf = (float*)alloc((size_t)HKV_ * T_ * M_ * 4);
  unsigned* selw = (unsigned*)alloc((size_t)HKV_ * T_ * 4);
  __bf16* compb = (__bf16*)alloc((size_t)T_ * HQD_ * 2);
  __bf16* fusedb = (__bf16*)alloc((size_t)T_ * HQD_ * 2);

  cvt_bf16_kernel<<<dim3((T_ * H_ / 8 + 255) / 256), 256, 0, stream>>>(x, xbf, T_ * H_ / 8);
  gemm_kernel<3><<<dim3(16, 16), 256, 0, stream>>>(xbf, Wq, qbf, HQD_, H_);   // Q, pre-scaled
  gemm_kvg_kernel<<<dim3(3, 16), 256, 0, stream>>>(xbf, Wk, Wv, Wg, kbf, vbf, vTbf, gatef);
  ckcv_kernel<<<dim3(M_, HKV_), 64, 0, stream>>>(kbf, vbf, pe, wck, wcv, ckf, cvf);
  comp_kernel<<<dim3(T_ / 4, HKV_), 256, 0, stream>>>(qbf, ckf, cvf, compb, sf);
  topk_kernel<<<dim3(16), 256, 0, stream>>>(sf, selw);
  flash_kernel<<<dim3(1024), 256, 0, stream>>>(qbf, kbf, vTbf, selw, compb, gatef, fusedb);
  gemm_kernel<2><<<dim3(16, 16), 256, 0, stream>>>(fusedb, Wo, d_out, H_, HQD_);
}

// Round 5
// 407.735 us; speedup vs baseline: 2.2970x; 1.4447x over previous
//
#include <hip/hip_runtime.h>
#include <hip/hip_bf16.h>
#include <math.h>

#define T_ 2048
#define H_ 2048
#define HQ_ 32
#define HKV_ 2
#define D_ 64
#define G_ 16
#define M_ 32
#define TOPK_ 16
#define WINDOW_ 512
#define HQD_ 2048   // HQ*D
#define KVD_ 128    // HKV*D
#define GATE_LD 96  // HQ*3

typedef __attribute__((ext_vector_type(8))) __bf16 bf16x8;
typedef __attribute__((ext_vector_type(2))) __bf16 bf16x2;
typedef __attribute__((ext_vector_type(4))) float f32x4;

#define MFMA16(a, b, c) __builtin_amdgcn_mfma_f32_16x16x32_bf16((a), (b), (c), 0, 0, 0)

// ---------------------------------------------------------------------------
// fp32 -> bf16 elementwise convert (8 elems/thread)
// ---------------------------------------------------------------------------
__global__ __launch_bounds__(256) void cvt_bf16_kernel(const float* __restrict__ in,
                                                       __bf16* __restrict__ out, int n8)
{
  int i = blockIdx.x * blockDim.x + threadIdx.x;
  if (i >= n8) return;
  const float4* p = (const float4*)(in + (size_t)i * 8);
  float4 f0 = p[0], f1 = p[1];
  bf16x8 w = {(__bf16)f0.x, (__bf16)f0.y, (__bf16)f0.z, (__bf16)f0.w,
              (__bf16)f1.x, (__bf16)f1.y, (__bf16)f1.z, (__bf16)f1.w};
  *(bf16x8*)(out + (size_t)i * 8) = w;
}

// ---------------------------------------------------------------------------
// Fused projection GEMM: col-blocks 0-15 = Wq (scaled 0.125), 16 = Wk,
// 17 = Wv (+V^T), 18 = Wg (sigmoid). BM=BN=128, BK=32, reg double-buffer,
// XOR-swizzled B staging (k ^ (((n>>4)&3)<<3)) to kill transpose-store
// bank conflicts.
// ---------------------------------------------------------------------------
__global__ __launch_bounds__(256) void proj_kernel(
    const __bf16* __restrict__ xbf,
    const float* __restrict__ Wq, const float* __restrict__ Wk,
    const float* __restrict__ Wv, const float* __restrict__ Wg,
    __bf16* __restrict__ qout, __bf16* __restrict__ kout,
    __bf16* __restrict__ vout, __bf16* __restrict__ vTout,
    float* __restrict__ gout)
{
  __shared__ __bf16 As[128][40];
  __shared__ __bf16 Bs[128][40];
  const int bx = blockIdx.x;                    // 0..18
  const int sel = (bx < 16) ? 0 : (bx - 15);    // 0=Q,1=K,2=V,3=G
  const float* B = (sel == 0) ? Wq : (sel == 1) ? Wk : (sel == 2) ? Wv : Wg;
  const int Ndim = (sel == 0) ? HQD_ : (sel == 3) ? GATE_LD : KVD_;
  const int n0 = (sel == 0) ? bx * 128 : 0;
  const int tid = threadIdx.x;
  const int lane = tid & 63;
  const int w = tid >> 6;
  const int r15 = lane & 15;
  const int kq = (lane >> 4) * 8;
  const int m0 = blockIdx.y * 128;

  const f32x4 fzero = {0.f, 0.f, 0.f, 0.f};
  f32x4 acc[2][8];
#pragma unroll
  for (int a = 0; a < 2; ++a)
#pragma unroll
    for (int b = 0; b < 8; ++b) acc[a][b] = fzero;

  const int ar = tid >> 1, akc = (tid & 1) * 16;
  const int bkr = tid >> 3, bnc = (tid & 7) * 16;
  const int bks = bkr ^ (((bnc >> 4) & 3) << 3);   // swizzled k column
  const bool bok = (bnc < Ndim);                   // G: cols >= 96 skipped

  int4 a0, a1;
  float4 f0, f1, f2, f3;
  {
    const __bf16* a = xbf + (size_t)(m0 + ar) * H_ + akc;
    a0 = ((const int4*)a)[0];
    a1 = ((const int4*)a)[1];
    if (bok) {
      const float* b = B + (size_t)bkr * Ndim + n0 + bnc;
      f0 = ((const float4*)b)[0];
      f1 = ((const float4*)b)[1];
      f2 = ((const float4*)b)[2];
      f3 = ((const float4*)b)[3];
    }
  }

  for (int k0 = 0; k0 < H_; k0 += 32) {
    __syncthreads();
    *(int4*)&As[ar][akc] = a0;
    *(int4*)&As[ar][akc + 8] = a1;
    if (bok) {
      Bs[bnc + 0][bks] = (__bf16)f0.x;  Bs[bnc + 1][bks] = (__bf16)f0.y;
      Bs[bnc + 2][bks] = (__bf16)f0.z;  Bs[bnc + 3][bks] = (__bf16)f0.w;
      Bs[bnc + 4][bks] = (__bf16)f1.x;  Bs[bnc + 5][bks] = (__bf16)f1.y;
      Bs[bnc + 6][bks] = (__bf16)f1.z;  Bs[bnc + 7][bks] = (__bf16)f1.w;
      Bs[bnc + 8][bks] = (__bf16)f2.x;  Bs[bnc + 9][bks] = (__bf16)f2.y;
      Bs[bnc + 10][bks] = (__bf16)f2.z; Bs[bnc + 11][bks] = (__bf16)f2.w;
      Bs[bnc + 12][bks] = (__bf16)f3.x; Bs[bnc + 13][bks] = (__bf16)f3.y;
      Bs[bnc + 14][bks] = (__bf16)f3.z; Bs[bnc + 15][bks] = (__bf16)f3.w;
    }
    __syncthreads();
    if (k0 + 32 < H_) {   // prefetch next tile; overlaps MFMA below
      const __bf16* a = xbf + (size_t)(m0 + ar) * H_ + (k0 + 32) + akc;
      a0 = ((const int4*)a)[0];
      a1 = ((const int4*)a)[1];
      if (bok) {
        const float* b = B + (size_t)(k0 + 32 + bkr) * Ndim + n0 + bnc;
        f0 = ((const float4*)b)[0];
        f1 = ((const float4*)b)[1];
        f2 = ((const float4*)b)[2];
        f3 = ((const float4*)b)[3];
      }
    }
    bf16x8 af0 = *(bf16x8*)&As[w * 32 + r15][kq];
    bf16x8 af1 = *(bf16x8*)&As[w * 32 + 16 + r15][kq];
#pragma unroll
    for (int ni = 0; ni < 8; ++ni) {
      bf16x8 bfrag = *(bf16x8*)&Bs[ni * 16 + r15][kq ^ ((ni & 3) << 3)];
      acc[0][ni] = MFMA16(af0, bfrag, acc[0][ni]);
      acc[1][ni] = MFMA16(af1, bfrag, acc[1][ni]);
    }
  }

#pragma unroll
  for (int mi = 0; mi < 2; ++mi)
#pragma unroll
    for (int ni = 0; ni < 8; ++ni)
#pragma unroll
      for (int reg = 0; reg < 4; ++reg) {
        int row = m0 + w * 32 + mi * 16 + (lane >> 4) * 4 + reg;
        int col = ni * 16 + r15;
        float vv = acc[mi][ni][reg];
        if (sel == 0) {
          qout[(size_t)row * HQD_ + n0 + col] = (__bf16)(vv * 0.125f);
        } else if (sel == 1) {
          kout[(size_t)row * KVD_ + col] = (__bf16)vv;
        } else if (sel == 2) {
          vout[(size_t)row * KVD_ + col] = (__bf16)vv;
          vTout[(size_t)col * T_ + row] = (__bf16)vv;
        } else if (col < GATE_LD) {
          gout[(size_t)row * GATE_LD + col] = 1.f / (1.f + __expf(-vv));
        }
      }
}

// ---------------------------------------------------------------------------
// Output GEMM: d_out = fused[2048x2048]bf16 @ Wo[2048x2048]fp32 -> fp32.
// Same reg double-buffer + swizzled B staging.
// ---------------------------------------------------------------------------
__global__ __launch_bounds__(256) void gemm_wo_kernel(
    const __bf16* __restrict__ A, const float* __restrict__ B,
    float* __restrict__ C)
{
  __shared__ __bf16 As[128][40];
  __shared__ __bf16 Bs[128][40];
  const int tid = threadIdx.x;
  const int lane = tid & 63;
  const int w = tid >> 6;
  const int r15 = lane & 15;
  const int kq = (lane >> 4) * 8;
  const int m0 = blockIdx.y * 128;
  const int n0 = blockIdx.x * 128;

  const f32x4 fzero = {0.f, 0.f, 0.f, 0.f};
  f32x4 acc[2][8];
#pragma unroll
  for (int a = 0; a < 2; ++a)
#pragma unroll
    for (int b = 0; b < 8; ++b) acc[a][b] = fzero;

  const int ar = tid >> 1, akc = (tid & 1) * 16;
  const int bkr = tid >> 3, bnc = (tid & 7) * 16;
  const int bks = bkr ^ (((bnc >> 4) & 3) << 3);

  int4 a0, a1;
  float4 f0, f1, f2, f3;
  {
    const __bf16* a = A + (size_t)(m0 + ar) * H_ + akc;
    a0 = ((const int4*)a)[0];
    a1 = ((const int4*)a)[1];
    const float* b = B + (size_t)bkr * H_ + n0 + bnc;
    f0 = ((const float4*)b)[0];
    f1 = ((const float4*)b)[1];
    f2 = ((const float4*)b)[2];
    f3 = ((const float4*)b)[3];
  }

  for (int k0 = 0; k0 < H_; k0 += 32) {
    __syncthreads();
    *(int4*)&As[ar][akc] = a0;
    *(int4*)&As[ar][akc + 8] = a1;
    Bs[bnc + 0][bks] = (__bf16)f0.x;  Bs[bnc + 1][bks] = (__bf16)f0.y;
    Bs[bnc + 2][bks] = (__bf16)f0.z;  Bs[bnc + 3][bks] = (__bf16)f0.w;
    Bs[bnc + 4][bks] = (__bf16)f1.x;  Bs[bnc + 5][bks] = (__bf16)f1.y;
    Bs[bnc + 6][bks] = (__bf16)f1.z;  Bs[bnc + 7][bks] = (__bf16)f1.w;
    Bs[bnc + 8][bks] = (__bf16)f2.x;  Bs[bnc + 9][bks] = (__bf16)f2.y;
    Bs[bnc + 10][bks] = (__bf16)f2.z; Bs[bnc + 11][bks] = (__bf16)f2.w;
    Bs[bnc + 12][bks] = (__bf16)f3.x; Bs[bnc + 13][bks] = (__bf16)f3.y;
    Bs[bnc + 14][bks] = (__bf16)f3.z; Bs[bnc + 15][bks] = (__bf16)f3.w;
    __syncthreads();
    if (k0 + 32 < H_) {
      const __bf16* a = A + (size_t)(m0 + ar) * H_ + (k0 + 32) + akc;
      a0 = ((const int4*)a)[0];
      a1 = ((const int4*)a)[1];
      const float* b = B + (size_t)(k0 + 32 + bkr) * H_ + n0 + bnc;
      f0 = ((const float4*)b)[0];
      f1 = ((const float4*)b)[1];
      f2 = ((const float4*)b)[2];
      f3 = ((const float4*)b)[3];
    }
    bf16x8 af0 = *(bf16x8*)&As[w * 32 + r15][kq];
    bf16x8 af1 = *(bf16x8*)&As[w * 32 + 16 + r15][kq];
#pragma unroll
    for (int ni = 0; ni < 8; ++ni) {
      bf16x8 bfrag = *(bf16x8*)&Bs[ni * 16 + r15][kq ^ ((ni & 3) << 3)];
      acc[0][ni] = MFMA16(af0, bfrag, acc[0][ni]);
      acc[1][ni] = MFMA16(af1, bfrag, acc[1][ni]);
    }
  }

#pragma unroll
  for (int mi = 0; mi < 2; ++mi)
#pragma unroll
    for (int ni = 0; ni < 8; ++ni)
#pragma unroll
      for (int reg = 0; reg < 4; ++reg) {
        int row = m0 + w * 32 + mi * 16 + (lane >> 4) * 4 + reg;
        int col = n0 + ni * 16 + r15;
        C[(size_t)row * H_ + col] = acc[mi][ni][reg];
      }
}

// ---------------------------------------------------------------------------
// ck/cv pooling
// ---------------------------------------------------------------------------
__global__ void ckcv_kernel(const __bf16* __restrict__ kbf, const __bf16* __restrict__ vbf,
                            const float* __restrict__ pe, const float* __restrict__ wck,
                            const float* __restrict__ wcv, float* __restrict__ ckf,
                            float* __restrict__ cvf)
{
  const int m = blockIdx.x, h = blockIdx.y, d = threadIdx.x;
  float cka = 0.f, cva = 0.f;
  for (int t = 0; t < 64; ++t) {
    float kk = (float)kbf[(size_t)(m * 64 + t) * KVD_ + h * 64 + d];
    float vv = (float)vbf[(size_t)(m * 64 + t) * KVD_ + h * 64 + d];
    float pev = pe[((size_t)h * 64 + t) * 64 + d];
    cka += (kk + pev) * wck[h * 64 + t];
    cva += vv * wcv[h * 64 + t];
  }
  ckf[((size_t)h * M_ + m) * D_ + d] = cka;
  cvf[((size_t)h * M_ + m) * D_ + d] = cva;
}

// ---------------------------------------------------------------------------
// Compressed attention: wave per (i, h_kv); balanced i-swizzle.
// q is pre-scaled by 0.125 so logits need no extra scale.
// ---------------------------------------------------------------------------
__global__ __launch_bounds__(256) void comp_kernel(
    const __bf16* __restrict__ q, const float* __restrict__ ckf,
    const float* __restrict__ cvf, __bf16* __restrict__ comp,
    float* __restrict__ sout)
{
  __shared__ float cks[M_][65];
  __shared__ float cvs[M_][65];
  __shared__ float qv[4][64];
  __shared__ float pv_sh[4][32];
  const int h = blockIdx.y;
  const int tid = threadIdx.x, w = tid >> 6, lane = tid & 63;
  {
    int mm = tid >> 3, dc = (tid & 7) * 8;
#pragma unroll
    for (int e = 0; e < 8; ++e) {
      cks[mm][dc + e] = ckf[((size_t)h * M_ + mm) * D_ + dc + e];
      cvs[mm][dc + e] = cvf[((size_t)h * M_ + mm) * D_ + dc + e];
    }
  }
  __syncthreads();
  const int bid = blockIdx.x;
  const int ib = (bid & 1) ? (511 - (bid >> 1)) : (bid >> 1);  // balance
  const int i = ib * 4 + w;
  const int nvis = (i >= 63) ? ((i - 63) >> 6) + 1 : 0;
  float s_acc = 0.f;
  for (int g = 0; g < G_; ++g) {
    const int head = h * G_ + g;
    qv[w][lane] = (float)q[(size_t)i * HQD_ + head * 64 + lane];
    float lg = -1e30f;
    if (lane < nvis) {
      float a0 = 0.f, a1 = 0.f, a2 = 0.f, a3 = 0.f;
#pragma unroll
      for (int d2 = 0; d2 < 64; d2 += 4) {
        a0 += qv[w][d2] * cks[lane][d2];
        a1 += qv[w][d2 + 1] * cks[lane][d2 + 1];
        a2 += qv[w][d2 + 2] * cks[lane][d2 + 2];
        a3 += qv[w][d2 + 3] * cks[lane][d2 + 3];
      }
      lg = a0 + a1 + a2 + a3;
    }
    float mx = lg;
    for (int off = 1; off < 32; off <<= 1) mx = fmaxf(mx, __shfl_xor(mx, off));
    float p = (lane < nvis) ? __expf(lg - mx) : 0.f;
    float sum = p;
    for (int off = 1; off < 32; off <<= 1) sum += __shfl_xor(sum, off);
    float pn = (sum > 0.f) ? p / sum : 0.f;
    s_acc += pn;
    if (lane < 32) pv_sh[w][lane] = pn;
    float o = 0.f, o2 = 0.f;
    int m2 = 0;
    for (; m2 + 1 < nvis; m2 += 2) {
      o += pv_sh[w][m2] * cvs[m2][lane];
      o2 += pv_sh[w][m2 + 1] * cvs[m2 + 1][lane];
    }
    if (m2 < nvis) o += pv_sh[w][m2] * cvs[m2][lane];
    o += o2;
    comp[(size_t)i * HQD_ + head * 64 + lane] = (__bf16)o;
  }
  if (lane < 32) sout[((size_t)h * T_ + i) * M_ + lane] = s_acc;
}

// ---------------------------------------------------------------------------
// Top-k selection (stable) -> bitmask.
// ---------------------------------------------------------------------------
__global__ void topk_kernel(const float* __restrict__ sin, unsigned* __restrict__ sel)
{
  int idx = blockIdx.x * blockDim.x + threadIdx.x;
  if (idx >= HKV_ * T_) return;
  int h = idx >> 11, i = idx & (T_ - 1);
  int qblk = i >> 6;
  float sc[M_];
#pragma unroll
  for (int m = 0; m < M_; ++m) {
    if (m > qblk) sc[m] = -__builtin_inff();
    else if (m == 0 || m > qblk - 2) sc[m] = __builtin_inff();
    else sc[m] = sin[((size_t)h * T_ + i) * M_ + m];
  }
  unsigned picked = 0;
  for (int r = 0; r < TOPK_; ++r) {
    float best = -__builtin_inff();
    int bi = -1;
#pragma unroll
    for (int m = 0; m < M_; ++m) {
      if (!((picked >> m) & 1u) && sc[m] > best) { best = sc[m]; bi = m; }
    }
    if (bi < 0) break;
    picked |= 1u << bi;
  }
  sel[(size_t)h * T_ + i] = picked;
}

// ---------------------------------------------------------------------------
// Flash kernel, swapped-QK^T (S^T = K·Q^T) so each lane owns ONE query row
// (col = lane&15). Per-lane m/l/alpha bookkeeping, 2-shuffle row reductions,
// packed bf16x2 P-tile writes. Shared exp+PV across both branches except at
// the single window-boundary block. q pre-scaled by 0.125.
// ---------------------------------------------------------------------------
__global__ __launch_bounds__(256) void flash_kernel(
    const __bf16* __restrict__ q, const __bf16* __restrict__ kg,
    const __bf16* __restrict__ vT, const unsigned* __restrict__ selg,
    const __bf16* __restrict__ comp, const float* __restrict__ gate,
    __bf16* __restrict__ fused)
{
  __shared__ alignas(16) char smem[37120];
  __bf16 (*Qs)[72] = (__bf16(*)[72])(smem);            // 9216
  __bf16 (*Ks)[72] = (__bf16(*)[72])(smem + 9216);     // 9216 (t rows)
  __bf16 (*Vt)[72] = (__bf16(*)[72])(smem + 18432);    // 9216 (d rows)
  __bf16 (*Ps)[72] = (__bf16(*)[72])(smem + 27648);    // 9216 (q rows x t)
  unsigned* sel_sh = (unsigned*)(smem + 36864);        // [64]

  // balance swizzle: co-resident v-groups get qb sets {b, 31-b, b+16, 15-b}
  const int lin = blockIdx.x;
  const int slot = lin & 255;
  const int v = lin >> 8;
  const int base = slot & 31, hseg = slot >> 5;
  const int hg = hseg * 4 + v;
  const int b2 = (base + ((v >> 1) << 4)) & 31;
  const int qb = (v & 1) ? (31 - b2) : b2;
  const int h = hg >> 4;

  const int tid = threadIdx.x;
  const int lane = tid & 63;
  const int w = tid >> 6;
  const int r15 = lane & 15;
  const int kq = (lane >> 4) * 8;
  const int rbase = (lane >> 4) * 4;
  const int myrow = w * 16 + r15;   // this lane's query row (within 64-block)

  {
    int r = tid >> 2, dc = (tid & 3) * 16;
    const __bf16* src = q + (size_t)(qb * 64 + r) * HQD_ + hg * 64 + dc;
    *(int4*)&Qs[r][dc] = *(const int4*)src;
    *(int4*)&Qs[r][dc + 8] = *(const int4*)(src + 8);
  }
  if (tid < 64) sel_sh[tid] = selg[h * T_ + qb * 64 + tid];
  __syncthreads();
  unsigned ubits = sel_sh[lane];
#pragma unroll
  for (int off = 1; off < 64; off <<= 1) ubits |= __shfl_xor(ubits, off);

  bf16x8 aq0 = *(bf16x8*)&Qs[myrow][kq];
  bf16x8 aq1 = *(bf16x8*)&Qs[myrow][32 + kq];
  const unsigned selrow = sel_sh[myrow];   // per-lane row's selected blocks

  const f32x4 fzero = {0.f, 0.f, 0.f, 0.f};
  f32x4 accO[2][4];
#pragma unroll
  for (int br = 0; br < 2; ++br)
#pragma unroll
    for (int a = 0; a < 4; ++a) accO[br][a] = fzero;
  float mrun0 = -__builtin_inff(), mrun1 = -__builtin_inff();
  float lrun0 = 0.f, lrun1 = 0.f;

  for (int kb = 0; kb <= qb; ++kb) {
    const bool sp_act = (ubits >> kb) & 1u;
    const bool wn_act = (kb + 8) >= qb;
    const bool boundary = (kb + 8) == qb;
    if (!sp_act && !wn_act) continue;
    __syncthreads();
    {
      int t = tid >> 2, dc = (tid & 3) * 16;
      const __bf16* ksrc = kg + (size_t)(kb * 64 + t) * KVD_ + h * 64 + dc;
      *(int4*)&Ks[t][dc] = *(const int4*)ksrc;
      *(int4*)&Ks[t][dc + 8] = *(const int4*)(ksrc + 8);
      const __bf16* vsrc = vT + (size_t)(h * 64 + t) * T_ + kb * 64 + dc;
      *(int4*)&Vt[t][dc] = *(const int4*)vsrc;
      *(int4*)&Vt[t][dc + 8] = *(const int4*)(vsrc + 8);
    }
    __syncthreads();

    // S^T: A = K-frag (rows t), B = Q-frag (cols = q rows). Lane: col=r15,
    // rows t = f*16 + rbase + reg.
    float st[4][4];
#pragma unroll
    for (int f = 0; f < 4; ++f) {
      bf16x8 kf0 = *(bf16x8*)&Ks[f * 16 + r15][kq];
      bf16x8 kf1 = *(bf16x8*)&Ks[f * 16 + r15][32 + kq];
      f32x4 s = MFMA16(kf0, aq0, fzero);
      s = MFMA16(kf1, aq1, s);
#pragma unroll
      for (int reg = 0; reg < 4; ++reg) st[f][reg] = s[reg];
    }
    if (kb == qb) {  // causal diagonal mask: t > myrow -> -inf
#pragma unroll
      for (int f = 0; f < 4; ++f)
#pragma unroll
        for (int reg = 0; reg < 4; ++reg)
          if (f * 16 + rbase + reg > myrow) st[f][reg] = -1e30f;
    }

    if (!boundary) {
      // ---- shared single-pass: one exp tile + one PV for both branches ----
      float rm = -1e30f;
#pragma unroll
      for (int f = 0; f < 4; ++f)
#pragma unroll
        for (int reg = 0; reg < 4; ++reg) rm = fmaxf(rm, st[f][reg]);
      rm = fmaxf(rm, __shfl_xor(rm, 16));
      rm = fmaxf(rm, __shfl_xor(rm, 32));
      float rsum = 0.f;
#pragma unroll
      for (int f = 0; f < 4; ++f)
#pragma unroll
        for (int reg = 0; reg < 4; ++reg) {
          float p = __expf(st[f][reg] - rm);
          st[f][reg] = p;
          rsum += p;
        }
      rsum += __shfl_xor(rsum, 16);
      rsum += __shfl_xor(rsum, 32);

      float aS = 1.f, fS = 0.f, aW = 1.f, fW = 0.f;
      if (sp_act && ((selrow >> kb) & 1u)) {
        float mnew = fmaxf(mrun0, rm);
        aS = __expf(mrun0 - mnew);
        fS = __expf(rm - mnew);
        mrun0 = mnew;
        lrun0 = lrun0 * aS + rsum * fS;
      }
      if (wn_act) {
        float mnew = fmaxf(mrun1, rm);
        aW = __expf(mrun1 - mnew);
        fW = __expf(rm - mnew);
        mrun1 = mnew;
        lrun1 = lrun1 * aW + rsum * fW;
      }
      // packed P write: Ps[qrow][t]
#pragma unroll
      for (int f = 0; f < 4; ++f)
#pragma unroll
        for (int c = 0; c < 2; ++c) {
          bf16x2 pk = {(__bf16)st[f][2 * c], (__bf16)st[f][2 * c + 1]};
          *(bf16x2*)&Ps[myrow][f * 16 + rbase + 2 * c] = pk;
        }
      bf16x8 bp0 = *(bf16x8*)&Ps[myrow][kq];
      bf16x8 bp1 = *(bf16x8*)&Ps[myrow][32 + kq];
      f32x4 accP[4];
#pragma unroll
      for (int df = 0; df < 4; ++df) {
        bf16x8 av0 = *(bf16x8*)&Vt[df * 16 + r15][kq];
        bf16x8 av1 = *(bf16x8*)&Vt[df * 16 + r15][32 + kq];
        f32x4 t = MFMA16(av0, bp0, fzero);
        accP[df] = MFMA16(av1, bp1, t);
      }
      if (sp_act) {
#pragma unroll
        for (int df = 0; df < 4; ++df)
#pragma unroll
          for (int reg = 0; reg < 4; ++reg)
            accO[0][df][reg] = accO[0][df][reg] * aS + accP[df][reg] * fS;
      }
      if (wn_act) {
#pragma unroll
        for (int df = 0; df < 4; ++df)
#pragma unroll
          for (int reg = 0; reg < 4; ++reg)
            accO[1][df][reg] = accO[1][df][reg] * aW + accP[df][reg] * fW;
      }
    } else {
      // ---- boundary kb == qb-8: two passes (different masks) ----
      if (sp_act) {
        float rm = -1e30f;
#pragma unroll
        for (int f = 0; f < 4; ++f)
#pragma unroll
          for (int reg = 0; reg < 4; ++reg) rm = fmaxf(rm, st[f][reg]);
        rm = fmaxf(rm, __shfl_xor(rm, 16));
        rm = fmaxf(rm, __shfl_xor(rm, 32));
        float rsum = 0.f;
        float pw[4][4];
#pragma unroll
        for (int f = 0; f < 4; ++f)
#pragma unroll
          for (int reg = 0; reg < 4; ++reg) {
            float p = __expf(st[f][reg] - rm);
            pw[f][reg] = p;
            rsum += p;
          }
        rsum += __shfl_xor(rsum, 16);
        rsum += __shfl_xor(rsum, 32);
        float aS = 1.f, fS = 0.f;
        if ((selrow >> kb) & 1u) {
          float mnew = fmaxf(mrun0, rm);
          aS = __expf(mrun0 - mnew);
          fS = __expf(rm - mnew);
          mrun0 = mnew;
          lrun0 = lrun0 * aS + rsum * fS;
        }
#pragma unroll
        for (int f = 0; f < 4; ++f)
#pragma unroll
          for (int c = 0; c < 2; ++c) {
            bf16x2 pk = {(__bf16)pw[f][2 * c], (__bf16)pw[f][2 * c + 1]};
            *(bf16x2*)&Ps[myrow][f * 16 + rbase + 2 * c] = pk;
          }
        bf16x8 bp0 = *(bf16x8*)&Ps[myrow][kq];
        bf16x8 bp1 = *(bf16x8*)&Ps[myrow][32 + kq];
#pragma unroll
        for (int df = 0; df < 4; ++df) {
          bf16x8 av0 = *(bf16x8*)&Vt[df * 16 + r15][kq];
          bf16x8 av1 = *(bf16x8*)&Vt[df * 16 + r15][32 + kq];
          f32x4 t = MFMA16(av0, bp0, fzero);
          f32x4 pv = MFMA16(av1, bp1, t);
#pragma unroll
          for (int reg = 0; reg < 4; ++reg)
            accO[0][df][reg] = accO[0][df][reg] * aS + pv[reg] * fS;
        }
      }
      // window pass: keep t >= myrow
#pragma unroll
      for (int f = 0; f < 4; ++f)
#pragma unroll
        for (int reg = 0; reg < 4; ++reg)
          if (f * 16 + rbase + reg < myrow) st[f][reg] = -1e30f;
      float rm = -1e30f;
#pragma unroll
      for (int f = 0; f < 4; ++f)
#pragma unroll
        for (int reg = 0; reg < 4; ++reg) rm = fmaxf(rm, st[f][reg]);
      rm = fmaxf(rm, __shfl_xor(rm, 16));
      rm = fmaxf(rm, __shfl_xor(rm, 32));
      float rsum = 0.f;
#pragma unroll
      for (int f = 0; f < 4; ++f)
#pragma unroll
        for (int reg = 0; reg < 4; ++reg) {
          float p = __expf(st[f][reg] - rm);
          st[f][reg] = p;
          rsum += p;
        }
      rsum += __shfl_xor(rsum, 16);
      rsum += __shfl_xor(rsum, 32);
      float mnew = fmaxf(mrun1, rm);
      float aW = __expf(mrun1 - mnew);
      float fW = __expf(rm - mnew);
      mrun1 = mnew;
      lrun1 = lrun1 * aW + rsum * fW;
#pragma unroll
      for (int f = 0; f < 4; ++f)
#pragma unroll
        for (int c = 0; c < 2; ++c) {
          bf16x2 pk = {(__bf16)st[f][2 * c], (__bf16)st[f][2 * c + 1]};
          *(bf16x2*)&Ps[myrow][f * 16 + rbase + 2 * c] = pk;
        }
      bf16x8 bp0 = *(bf16x8*)&Ps[myrow][kq];
      bf16x8 bp1 = *(bf16x8*)&Ps[myrow][32 + kq];
#pragma unroll
      for (int df = 0; df < 4; ++df) {
        bf16x8 av0 = *(bf16x8*)&Vt[df * 16 + r15][kq];
        bf16x8 av1 = *(bf16x8*)&Vt[df * 16 + r15][32 + kq];
        f32x4 t = MFMA16(av0, bp0, fzero);
        f32x4 pv = MFMA16(av1, bp1, t);
#pragma unroll
        for (int reg = 0; reg < 4; ++reg)
          accO[1][df][reg] = accO[1][df][reg] * aW + pv[reg] * fW;
      }
    }
  }

  __syncthreads();  // all waves done with Ks/Vt before aliasing as Otw
  float* Otw = (float*)(smem + 9216) + w * (16 * 68);
  const int r2 = lane >> 2;
  const int dq = (lane & 3) * 16;
  const int i_out = qb * 64 + w * 16 + r2;
  const float* gp = gate + (size_t)i_out * GATE_LD + hg * 3;
  const float g0 = gp[0], g1 = gp[1], g2 = gp[2];
  float fv[16];
  {
    const bf16x8* cp = (const bf16x8*)(comp + (size_t)i_out * HQD_ + hg * 64 + dq);
    bf16x8 c0 = cp[0], c1 = cp[1];
#pragma unroll
    for (int e = 0; e < 8; ++e) {
      fv[e] = g0 * (float)c0[e];
      fv[8 + e] = g0 * (float)c1[e];
    }
  }
  const float linv0 = 1.f / lrun0;
  const float linv1 = 1.f / lrun1;
#pragma unroll
  for (int br = 0; br < 2; ++br) {
    const float linv = (br == 0) ? linv0 : linv1;
#pragma unroll
    for (int df = 0; df < 4; ++df)
#pragma unroll
      for (int reg = 0; reg < 4; ++reg)
        Otw[r15 * 68 + df * 16 + rbase + reg] = accO[br][df][reg] * linv;
    const float gg = (br == 0) ? g1 : g2;
#pragma unroll
    for (int e = 0; e < 16; ++e) fv[e] += gg * Otw[r2 * 68 + dq + e];
  }
  bf16x8 o0, o1;
#pragma unroll
  for (int e = 0; e < 8; ++e) {
    o0[e] = (__bf16)fv[e];
    o1[e] = (__bf16)fv[8 + e];
  }
  bf16x8* op = (bf16x8*)(fused + (size_t)i_out * HQD_ + hg * 64 + dq);
  op[0] = o0;
  op[1] = o1;
}

// ---------------------------------------------------------------------------
extern "C" void kernel_launch(void* const* d_in, const int* in_sizes, int n_in,
                              void* d_out, int out_size, void* d_ws, size_t ws_size,
                              hipStream_t stream)
{
  (void)in_sizes; (void)n_in; (void)out_size; (void)ws_size;
  const float* x = (const float*)d_in[0];
  const float* Wq = (const float*)d_in[2];
  const float* Wk = (const float*)d_in[3];
  const float* Wv = (const float*)d_in[4];
  const float* Wo = (const float*)d_in[5];
  const float* Wg = (const float*)d_in[6];
  const float* wck = (const float*)d_in[7];
  const float* wcv = (const float*)d_in[8];
  const float* pe = (const float*)d_in[9];

  char* ws = (char*)d_ws;
  size_t off = 0;
  auto alloc = [&](size_t b) {
    void* p = ws + off;
    off += (b + 255) & ~(size_t)255;
    return p;
  };
  __bf16* xbf = (__bf16*)alloc((size_t)T_ * H_ * 2);
  __bf16* qbf = (__bf16*)alloc((size_t)T_ * HQD_ * 2);
  __bf16* kbf = (__bf16*)alloc((size_t)T_ * KVD_ * 2);
  __bf16* vbf = (__bf16*)alloc((size_t)T_ * KVD_ * 2);
  __bf16* vTbf = (__bf16*)alloc((size_t)T_ * KVD_ * 2);
  float* gatef = (float*)alloc((size_t)T_ * GATE_LD * 4);
  float* ckf = (float*)alloc((size_t)HKV_ * M_ * D_ * 4);
  float* cvf = (float*)alloc((size_t)HKV_ * M_ * D_ * 4);
  float* sf = (float*)alloc((size_t)HKV_ * T_ * M_ * 4);
  unsigned* selw = (unsigned*)alloc((size_t)HKV_ * T_ * 4);
  __bf16* compb = (__bf16*)alloc((size_t)T_ * HQD_ * 2);
  __bf16* fusedb = (__bf16*)alloc((size_t)T_ * HQD_ * 2);

  cvt_bf16_kernel<<<dim3((T_ * H_ / 8 + 255) / 256), 256, 0, stream>>>(x, xbf, T_ * H_ / 8);
  proj_kernel<<<dim3(19, 16), 256, 0, stream>>>(xbf, Wq, Wk, Wv, Wg,
                                                qbf, kbf, vbf, vTbf, gatef);
  ckcv_kernel<<<dim3(M_, HKV_), 64, 0, stream>>>(kbf, vbf, pe, wck, wcv, ckf, cvf);
  comp_kernel<<<dim3(T_ / 4, HKV_), 256, 0, stream>>>(qbf, ckf, cvf, compb, sf);
  topk_kernel<<<dim3(16), 256, 0, stream>>>(sf, selw);
  flash_kernel<<<dim3(1024), 256, 0, stream>>>(qbf, kbf, vTbf, selw, compb, gatef, fusedb);
  gemm_wo_kernel<<<dim3(16, 16), 256, 0, stream>>>(fusedb, Wo, (float*)d_out);
}

// Round 6
// 327.979 us; speedup vs baseline: 2.8556x; 1.2432x over previous
//
#include <hip/hip_runtime.h>
#include <hip/hip_bf16.h>
#include <math.h>

#define T_ 2048
#define H_ 2048
#define HQ_ 32
#define HKV_ 2
#define D_ 64
#define G_ 16
#define M_ 32
#define TOPK_ 16
#define WINDOW_ 512
#define HQD_ 2048   // HQ*D
#define KVD_ 128    // HKV*D
#define GATE_LD 96  // HQ*3

// q pre-scale: 1/sqrt(D) * log2(e); softmax done in log2 domain (exact).
#define QSCALE 0.1803368801111204f
#define SOFF 16.0f   // fixed softmax offset (log2 units)

typedef __attribute__((ext_vector_type(8))) __bf16 bf16x8;
typedef __attribute__((ext_vector_type(2))) __bf16 bf16x2;
typedef __attribute__((ext_vector_type(4))) float f32x4;

#define MFMA16(a, b, c) __builtin_amdgcn_mfma_f32_16x16x32_bf16((a), (b), (c), 0, 0, 0)

#if defined(__has_builtin)
#if __has_builtin(__builtin_amdgcn_exp2f)
#define EXP2F(x) __builtin_amdgcn_exp2f(x)
#endif
#endif
#ifndef EXP2F
#define EXP2F(x) exp2f(x)
#endif

// ---------------------------------------------------------------------------
// fp32 -> bf16 elementwise convert (8 elems/thread)
// ---------------------------------------------------------------------------
__global__ __launch_bounds__(256) void cvt_bf16_kernel(const float* __restrict__ in,
                                                       __bf16* __restrict__ out, int n8)
{
  int i = blockIdx.x * blockDim.x + threadIdx.x;
  if (i >= n8) return;
  const float4* p = (const float4*)(in + (size_t)i * 8);
  float4 f0 = p[0], f1 = p[1];
  bf16x8 w = {(__bf16)f0.x, (__bf16)f0.y, (__bf16)f0.z, (__bf16)f0.w,
              (__bf16)f1.x, (__bf16)f1.y, (__bf16)f1.z, (__bf16)f1.w};
  *(bf16x8*)(out + (size_t)i * 8) = w;
}

// ---------------------------------------------------------------------------
// Weight transpose+convert: W[K=2048][N] fp32 -> Wt[padN][2048] bf16.
// padN = gridDim.x*64; rows n >= N are zero-filled.
// ---------------------------------------------------------------------------
__global__ __launch_bounds__(256) void twt_kernel(const float* __restrict__ W,
                                                  __bf16* __restrict__ Wt, int N)
{
  __shared__ float tile[64][68];
  const int tid = threadIdx.x;
  const int tn0 = blockIdx.x * 64, tk0 = blockIdx.y * 64;
  const int r = tid >> 2, c0 = (tid & 3) * 16;
  if (tn0 + c0 < N) {
    const float* src = W + (size_t)(tk0 + r) * N + tn0 + c0;
    *(float4*)&tile[r][c0 + 0]  = ((const float4*)src)[0];
    *(float4*)&tile[r][c0 + 4]  = ((const float4*)src)[1];
    *(float4*)&tile[r][c0 + 8]  = ((const float4*)src)[2];
    *(float4*)&tile[r][c0 + 12] = ((const float4*)src)[3];
  } else {
#pragma unroll
    for (int e = 0; e < 16; ++e) tile[r][c0 + e] = 0.f;
  }
  __syncthreads();
  const int nloc = tid >> 2, kc = (tid & 3) * 16;
  bf16x8 w0, w1;
#pragma unroll
  for (int j = 0; j < 8; ++j) w0[j] = (__bf16)tile[kc + j][nloc];
#pragma unroll
  for (int j = 0; j < 8; ++j) w1[j] = (__bf16)tile[kc + 8 + j][nloc];
  __bf16* dst = Wt + (size_t)(tn0 + nloc) * H_ + tk0 + kc;
  *(bf16x8*)dst = w0;
  *(bf16x8*)(dst + 8) = w1;
}

// ---------------------------------------------------------------------------
// Fused projection GEMM (all-bf16, B pre-transposed): col-blocks 0-15 = Wq
// (scaled QSCALE), 16 = Wk, 17 = Wv (+V^T), 18 = Wg (sigmoid).
// BM=BN=128, BK=32, reg double-buffer, identical int4 staging for A and B.
// ---------------------------------------------------------------------------
__global__ __launch_bounds__(256) void proj_kernel(
    const __bf16* __restrict__ xbf,
    const __bf16* __restrict__ Wqt, const __bf16* __restrict__ Wkt,
    const __bf16* __restrict__ Wvt, const __bf16* __restrict__ Wgt,
    __bf16* __restrict__ qout, __bf16* __restrict__ kout,
    __bf16* __restrict__ vout, __bf16* __restrict__ vTout,
    float* __restrict__ gout)
{
  __shared__ __bf16 As[128][40];
  __shared__ __bf16 Bs[128][40];
  const int bx = blockIdx.x;                    // 0..18
  const int sel = (bx < 16) ? 0 : (bx - 15);    // 0=Q,1=K,2=V,3=G
  const __bf16* Bt = (sel == 0) ? Wqt : (sel == 1) ? Wkt : (sel == 2) ? Wvt : Wgt;
  const int n0 = (sel == 0) ? bx * 128 : 0;
  const int tid = threadIdx.x;
  const int lane = tid & 63;
  const int w = tid >> 6;
  const int r15 = lane & 15;
  const int kq = (lane >> 4) * 8;
  const int m0 = blockIdx.y * 128;

  const f32x4 fzero = {0.f, 0.f, 0.f, 0.f};
  f32x4 acc[2][8];
#pragma unroll
  for (int a = 0; a < 2; ++a)
#pragma unroll
    for (int b = 0; b < 8; ++b) acc[a][b] = fzero;

  const int ar = tid >> 1, akc = (tid & 1) * 16;

  int4 a0, a1, b0, b1;
  {
    const __bf16* a = xbf + (size_t)(m0 + ar) * H_ + akc;
    a0 = ((const int4*)a)[0];
    a1 = ((const int4*)a)[1];
    const __bf16* b = Bt + (size_t)(n0 + ar) * H_ + akc;
    b0 = ((const int4*)b)[0];
    b1 = ((const int4*)b)[1];
  }

  for (int k0 = 0; k0 < H_; k0 += 32) {
    __syncthreads();
    *(int4*)&As[ar][akc] = a0;
    *(int4*)&As[ar][akc + 8] = a1;
    *(int4*)&Bs[ar][akc] = b0;
    *(int4*)&Bs[ar][akc + 8] = b1;
    __syncthreads();
    if (k0 + 32 < H_) {   // prefetch next tile; overlaps MFMA below
      const __bf16* a = xbf + (size_t)(m0 + ar) * H_ + (k0 + 32) + akc;
      a0 = ((const int4*)a)[0];
      a1 = ((const int4*)a)[1];
      const __bf16* b = Bt + (size_t)(n0 + ar) * H_ + (k0 + 32) + akc;
      b0 = ((const int4*)b)[0];
      b1 = ((const int4*)b)[1];
    }
    bf16x8 af0 = *(bf16x8*)&As[w * 32 + r15][kq];
    bf16x8 af1 = *(bf16x8*)&As[w * 32 + 16 + r15][kq];
#pragma unroll
    for (int ni = 0; ni < 8; ++ni) {
      bf16x8 bfrag = *(bf16x8*)&Bs[ni * 16 + r15][kq];
      acc[0][ni] = MFMA16(af0, bfrag, acc[0][ni]);
      acc[1][ni] = MFMA16(af1, bfrag, acc[1][ni]);
    }
  }

#pragma unroll
  for (int mi = 0; mi < 2; ++mi)
#pragma unroll
    for (int ni = 0; ni < 8; ++ni)
#pragma unroll
      for (int reg = 0; reg < 4; ++reg) {
        int row = m0 + w * 32 + mi * 16 + (lane >> 4) * 4 + reg;
        int col = ni * 16 + r15;
        float vv = acc[mi][ni][reg];
        if (sel == 0) {
          qout[(size_t)row * HQD_ + n0 + col] = (__bf16)(vv * QSCALE);
        } else if (sel == 1) {
          kout[(size_t)row * KVD_ + col] = (__bf16)vv;
        } else if (sel == 2) {
          vout[(size_t)row * KVD_ + col] = (__bf16)vv;
          vTout[(size_t)col * T_ + row] = (__bf16)vv;
        } else if (col < GATE_LD) {
          gout[(size_t)row * GATE_LD + col] = 1.f / (1.f + __expf(-vv));
        }
      }
}

// ---------------------------------------------------------------------------
// Output GEMM: d_out = fused[2048x2048]bf16 @ Wo^T[2048][2048]bf16 -> fp32.
// ---------------------------------------------------------------------------
__global__ __launch_bounds__(256) void gemm_wo_kernel(
    const __bf16* __restrict__ A, const __bf16* __restrict__ Bt,
    float* __restrict__ C)
{
  __shared__ __bf16 As[128][40];
  __shared__ __bf16 Bs[128][40];
  const int tid = threadIdx.x;
  const int lane = tid & 63;
  const int w = tid >> 6;
  const int r15 = lane & 15;
  const int kq = (lane >> 4) * 8;
  const int m0 = blockIdx.y * 128;
  const int n0 = blockIdx.x * 128;

  const f32x4 fzero = {0.f, 0.f, 0.f, 0.f};
  f32x4 acc[2][8];
#pragma unroll
  for (int a = 0; a < 2; ++a)
#pragma unroll
    for (int b = 0; b < 8; ++b) acc[a][b] = fzero;

  const int ar = tid >> 1, akc = (tid & 1) * 16;

  int4 a0, a1, b0, b1;
  {
    const __bf16* a = A + (size_t)(m0 + ar) * H_ + akc;
    a0 = ((const int4*)a)[0];
    a1 = ((const int4*)a)[1];
    const __bf16* b = Bt + (size_t)(n0 + ar) * H_ + akc;
    b0 = ((const int4*)b)[0];
    b1 = ((const int4*)b)[1];
  }

  for (int k0 = 0; k0 < H_; k0 += 32) {
    __syncthreads();
    *(int4*)&As[ar][akc] = a0;
    *(int4*)&As[ar][akc + 8] = a1;
    *(int4*)&Bs[ar][akc] = b0;
    *(int4*)&Bs[ar][akc + 8] = b1;
    __syncthreads();
    if (k0 + 32 < H_) {
      const __bf16* a = A + (size_t)(m0 + ar) * H_ + (k0 + 32) + akc;
      a0 = ((const int4*)a)[0];
      a1 = ((const int4*)a)[1];
      const __bf16* b = Bt + (size_t)(n0 + ar) * H_ + (k0 + 32) + akc;
      b0 = ((const int4*)b)[0];
      b1 = ((const int4*)b)[1];
    }
    bf16x8 af0 = *(bf16x8*)&As[w * 32 + r15][kq];
    bf16x8 af1 = *(bf16x8*)&As[w * 32 + 16 + r15][kq];
#pragma unroll
    for (int ni = 0; ni < 8; ++ni) {
      bf16x8 bfrag = *(bf16x8*)&Bs[ni * 16 + r15][kq];
      acc[0][ni] = MFMA16(af0, bfrag, acc[0][ni]);
      acc[1][ni] = MFMA16(af1, bfrag, acc[1][ni]);
    }
  }

#pragma unroll
  for (int mi = 0; mi < 2; ++mi)
#pragma unroll
    for (int ni = 0; ni < 8; ++ni)
#pragma unroll
      for (int reg = 0; reg < 4; ++reg) {
        int row = m0 + w * 32 + mi * 16 + (lane >> 4) * 4 + reg;
        int col = n0 + ni * 16 + r15;
        C[(size_t)row * H_ + col] = acc[mi][ni][reg];
      }
}

// ---------------------------------------------------------------------------
// ck/cv pooling
// ---------------------------------------------------------------------------
__global__ void ckcv_kernel(const __bf16* __restrict__ kbf, const __bf16* __restrict__ vbf,
                            const float* __restrict__ pe, const float* __restrict__ wck,
                            const float* __restrict__ wcv, float* __restrict__ ckf,
                            float* __restrict__ cvf)
{
  const int m = blockIdx.x, h = blockIdx.y, d = threadIdx.x;
  float cka = 0.f, cva = 0.f;
  for (int t = 0; t < 64; ++t) {
    float kk = (float)kbf[(size_t)(m * 64 + t) * KVD_ + h * 64 + d];
    float vv = (float)vbf[(size_t)(m * 64 + t) * KVD_ + h * 64 + d];
    float pev = pe[((size_t)h * 64 + t) * 64 + d];
    cka += (kk + pev) * wck[h * 64 + t];
    cva += vv * wcv[h * 64 + t];
  }
  ckf[((size_t)h * M_ + m) * D_ + d] = cka;
  cvf[((size_t)h * M_ + m) * D_ + d] = cva;
}

// ---------------------------------------------------------------------------
// Compressed attention: wave per (i, h_kv); balanced i-swizzle.
// q pre-scaled by QSCALE -> logits in log2 domain, exp2 softmax (identical
// probabilities).
// ---------------------------------------------------------------------------
__global__ __launch_bounds__(256) void comp_kernel(
    const __bf16* __restrict__ q, const float* __restrict__ ckf,
    const float* __restrict__ cvf, __bf16* __restrict__ comp,
    float* __restrict__ sout)
{
  __shared__ float cks[M_][65];
  __shared__ float cvs[M_][65];
  __shared__ float qv[4][64];
  __shared__ float pv_sh[4][32];
  const int h = blockIdx.y;
  const int tid = threadIdx.x, w = tid >> 6, lane = tid & 63;
  {
    int mm = tid >> 3, dc = (tid & 7) * 8;
#pragma unroll
    for (int e = 0; e < 8; ++e) {
      cks[mm][dc + e] = ckf[((size_t)h * M_ + mm) * D_ + dc + e];
      cvs[mm][dc + e] = cvf[((size_t)h * M_ + mm) * D_ + dc + e];
    }
  }
  __syncthreads();
  const int bid = blockIdx.x;
  const int ib = (bid & 1) ? (511 - (bid >> 1)) : (bid >> 1);  // balance
  const int i = ib * 4 + w;
  const int nvis = (i >= 63) ? ((i - 63) >> 6) + 1 : 0;
  float s_acc = 0.f;
  for (int g = 0; g < G_; ++g) {
    const int head = h * G_ + g;
    qv[w][lane] = (float)q[(size_t)i * HQD_ + head * 64 + lane];
    float lg = -1e30f;
    if (lane < nvis) {
      float a0 = 0.f, a1 = 0.f, a2 = 0.f, a3 = 0.f;
#pragma unroll
      for (int d2 = 0; d2 < 64; d2 += 4) {
        a0 += qv[w][d2] * cks[lane][d2];
        a1 += qv[w][d2 + 1] * cks[lane][d2 + 1];
        a2 += qv[w][d2 + 2] * cks[lane][d2 + 2];
        a3 += qv[w][d2 + 3] * cks[lane][d2 + 3];
      }
      lg = a0 + a1 + a2 + a3;
    }
    float mx = lg;
    for (int off = 1; off < 32; off <<= 1) mx = fmaxf(mx, __shfl_xor(mx, off));
    float p = (lane < nvis) ? EXP2F(lg - mx) : 0.f;
    float sum = p;
    for (int off = 1; off < 32; off <<= 1) sum += __shfl_xor(sum, off);
    float pn = (sum > 0.f) ? p / sum : 0.f;
    s_acc += pn;
    if (lane < 32) pv_sh[w][lane] = pn;
    float o = 0.f, o2 = 0.f;
    int m2 = 0;
    for (; m2 + 1 < nvis; m2 += 2) {
      o += pv_sh[w][m2] * cvs[m2][lane];
      o2 += pv_sh[w][m2 + 1] * cvs[m2 + 1][lane];
    }
    if (m2 < nvis) o += pv_sh[w][m2] * cvs[m2][lane];
    o += o2;
    comp[(size_t)i * HQD_ + head * 64 + lane] = (__bf16)o;
  }
  if (lane < 32) sout[((size_t)h * T_ + i) * M_ + lane] = s_acc;
}

// ---------------------------------------------------------------------------
// Top-k selection (stable) -> bitmask.
// ---------------------------------------------------------------------------
__global__ void topk_kernel(const float* __restrict__ sin, unsigned* __restrict__ sel)
{
  int idx = blockIdx.x * blockDim.x + threadIdx.x;
  if (idx >= HKV_ * T_) return;
  int h = idx >> 11, i = idx & (T_ - 1);
  int qblk = i >> 6;
  float sc[M_];
#pragma unroll
  for (int m = 0; m < M_; ++m) {
    if (m > qblk) sc[m] = -__builtin_inff();
    else if (m == 0 || m > qblk - 2) sc[m] = __builtin_inff();
    else sc[m] = sin[((size_t)h * T_ + i) * M_ + m];
  }
  unsigned picked = 0;
  for (int r = 0; r < TOPK_; ++r) {
    float best = -__builtin_inff();
    int bi = -1;
#pragma unroll
    for (int m = 0; m < M_; ++m) {
      if (!((picked >> m) & 1u) && sc[m] > best) { best = sc[m]; bi = m; }
    }
    if (bi < 0) break;
    picked |= 1u << bi;
  }
  sel[(size_t)h * T_ + i] = picked;
}

// ---------------------------------------------------------------------------
// Flash kernel, fixed-offset log2-softmax (no running max): logits are
// bounded, so P = exp2(st - SOFF) is exact after normalization. The -SOFF
// is folded into the QK^T MFMA C-init. Per-lane partial l-sums reduced once
// at the epilogue. K/V register-prefetch over the active-block bitmask.
// Ps aliases Qs (dead after frag hoist). q pre-scaled by QSCALE.
// ---------------------------------------------------------------------------
__global__ __launch_bounds__(256) void flash_kernel(
    const __bf16* __restrict__ q, const __bf16* __restrict__ kg,
    const __bf16* __restrict__ vT, const unsigned* __restrict__ selg,
    const __bf16* __restrict__ comp, const float* __restrict__ gate,
    __bf16* __restrict__ fused)
{
  __shared__ alignas(16) char smem[27904];
  __bf16 (*Qs)[72] = (__bf16(*)[72])(smem);            // 9216, aliased by Ps
  __bf16 (*Ps)[72] = (__bf16(*)[72])(smem);
  __bf16 (*Ks)[72] = (__bf16(*)[72])(smem + 9216);     // 9216 (t rows)
  __bf16 (*Vt)[72] = (__bf16(*)[72])(smem + 18432);    // 9216 (d rows)
  unsigned* sel_sh = (unsigned*)(smem + 27648);        // [64]

  // balance swizzle: co-resident v-groups get qb sets {b, 31-b, b+16, 15-b}
  const int lin = blockIdx.x;
  const int slot = lin & 255;
  const int v = lin >> 8;
  const int base = slot & 31, hseg = slot >> 5;
  const int hg = hseg * 4 + v;
  const int b2 = (base + ((v >> 1) << 4)) & 31;
  const int qb = (v & 1) ? (31 - b2) : b2;
  const int h = hg >> 4;

  const int tid = threadIdx.x;
  const int lane = tid & 63;
  const int w = tid >> 6;
  const int r15 = lane & 15;
  const int kq = (lane >> 4) * 8;
  const int rbase = (lane >> 4) * 4;
  const int myrow = w * 16 + r15;
  const int tld = tid >> 2, dld = (tid & 3) * 16;

  {
    const __bf16* src = q + (size_t)(qb * 64 + tld) * HQD_ + hg * 64 + dld;
    *(int4*)&Qs[tld][dld] = ((const int4*)src)[0];
    *(int4*)&Qs[tld][dld + 8] = ((const int4*)src)[1];
  }
  if (tid < 64) sel_sh[tid] = selg[h * T_ + qb * 64 + tid];
  __syncthreads();
  unsigned ubits = sel_sh[lane];
#pragma unroll
  for (int off = 1; off < 64; off <<= 1) ubits |= __shfl_xor(ubits, off);

  bf16x8 aq0 = *(bf16x8*)&Qs[myrow][kq];
  bf16x8 aq1 = *(bf16x8*)&Qs[myrow][32 + kq];
  const unsigned selrow = sel_sh[myrow];

  const f32x4 fzero = {0.f, 0.f, 0.f, 0.f};
  const f32x4 cinit = {-SOFF, -SOFF, -SOFF, -SOFF};
  f32x4 accO[2][4];
#pragma unroll
  for (int br = 0; br < 2; ++br)
#pragma unroll
    for (int a = 0; a < 4; ++a) accO[br][a] = fzero;
  float lp0 = 0.f, lp1 = 0.f;   // per-lane partial l-sums

  // active-block bitmask: union of selected blocks + window range, <= qb
  const unsigned qmaskbits = (qb >= 31) ? 0xFFFFFFFFu : ((1u << (qb + 1)) - 1);
  const unsigned wbits = (qb >= 9) ? (qmaskbits & ~((1u << (qb - 8)) - 1)) : qmaskbits;
  const unsigned amask = (ubits & qmaskbits) | wbits;

  int4 kp0, kp1, vp0, vp1;
  unsigned rem = amask;
  int kb = (int)__builtin_ctz(rem);
  {
    const __bf16* ksrc = kg + (size_t)(kb * 64 + tld) * KVD_ + h * 64 + dld;
    kp0 = ((const int4*)ksrc)[0];
    kp1 = ((const int4*)ksrc)[1];
    const __bf16* vsrc = vT + (size_t)(h * 64 + tld) * T_ + kb * 64 + dld;
    vp0 = ((const int4*)vsrc)[0];
    vp1 = ((const int4*)vsrc)[1];
  }

  for (;;) {
    rem &= rem - 1;
    const int kbn = rem ? (int)__builtin_ctz(rem) : -1;
    __syncthreads();
    *(int4*)&Ks[tld][dld] = kp0;
    *(int4*)&Ks[tld][dld + 8] = kp1;
    *(int4*)&Vt[tld][dld] = vp0;
    *(int4*)&Vt[tld][dld + 8] = vp1;
    __syncthreads();
    if (kbn >= 0) {   // prefetch next active block under this block's compute
      const __bf16* ksrc = kg + (size_t)(kbn * 64 + tld) * KVD_ + h * 64 + dld;
      kp0 = ((const int4*)ksrc)[0];
      kp1 = ((const int4*)ksrc)[1];
      const __bf16* vsrc = vT + (size_t)(h * 64 + tld) * T_ + kbn * 64 + dld;
      vp0 = ((const int4*)vsrc)[0];
      vp1 = ((const int4*)vsrc)[1];
    }

    const bool sp_act = (ubits >> kb) & 1u;
    const bool wn_act = (kb + 8) >= qb;
    const bool boundary = (kb + 8) == qb;

    // S^T with -SOFF folded into C-init. Lane owns q-row myrow (col r15).
    f32x4 st4[4];
    __builtin_amdgcn_s_setprio(1);
#pragma unroll
    for (int f = 0; f < 4; ++f) {
      bf16x8 kf0 = *(bf16x8*)&Ks[f * 16 + r15][kq];
      bf16x8 kf1 = *(bf16x8*)&Ks[f * 16 + r15][32 + kq];
      f32x4 s = MFMA16(kf0, aq0, cinit);
      st4[f] = MFMA16(kf1, aq1, s);
    }
    __builtin_amdgcn_s_setprio(0);
    if (kb == qb) {  // causal diagonal: t > myrow -> -inf
#pragma unroll
      for (int f = 0; f < 4; ++f)
#pragma unroll
        for (int reg = 0; reg < 4; ++reg)
          if (f * 16 + rbase + reg > myrow) st4[f][reg] = -1e30f;
    }

    if (!boundary) {
      // ---- shared path: one exp tile + one PV for both branches ----
      float rowsum = 0.f;
#pragma unroll
      for (int f = 0; f < 4; ++f)
#pragma unroll
        for (int reg = 0; reg < 4; ++reg) {
          float p = EXP2F(st4[f][reg]);
          st4[f][reg] = p;
          rowsum += p;
        }
#pragma unroll
      for (int f = 0; f < 4; ++f)
#pragma unroll
        for (int c = 0; c < 2; ++c) {
          bf16x2 pk = {(__bf16)st4[f][2 * c], (__bf16)st4[f][2 * c + 1]};
          *(bf16x2*)&Ps[myrow][f * 16 + rbase + 2 * c] = pk;
        }
      bf16x8 bp0 = *(bf16x8*)&Ps[myrow][kq];
      bf16x8 bp1 = *(bf16x8*)&Ps[myrow][32 + kq];
      f32x4 accP[4];
      __builtin_amdgcn_s_setprio(1);
#pragma unroll
      for (int df = 0; df < 4; ++df) {
        bf16x8 av0 = *(bf16x8*)&Vt[df * 16 + r15][kq];
        bf16x8 av1 = *(bf16x8*)&Vt[df * 16 + r15][32 + kq];
        f32x4 t = MFMA16(av0, bp0, fzero);
        accP[df] = MFMA16(av1, bp1, t);
      }
      __builtin_amdgcn_s_setprio(0);
      if (sp_act) {
        const float s01 = ((selrow >> kb) & 1u) ? 1.f : 0.f;
        lp0 += s01 * rowsum;
#pragma unroll
        for (int df = 0; df < 4; ++df)
#pragma unroll
          for (int reg = 0; reg < 4; ++reg)
            accO[0][df][reg] += accP[df][reg] * s01;
      }
      if (wn_act) {
        lp1 += rowsum;
#pragma unroll
        for (int df = 0; df < 4; ++df)
#pragma unroll
          for (int reg = 0; reg < 4; ++reg)
            accO[1][df][reg] += accP[df][reg];
      }
    } else {
      // ---- boundary kb == qb-8: two masked passes ----
      if (sp_act) {
        float rowsum = 0.f;
        float pw[4][4];
#pragma unroll
        for (int f = 0; f < 4; ++f)
#pragma unroll
          for (int reg = 0; reg < 4; ++reg) {
            float p = EXP2F(st4[f][reg]);
            pw[f][reg] = p;
            rowsum += p;
          }
#pragma unroll
        for (int f = 0; f < 4; ++f)
#pragma unroll
          for (int c = 0; c < 2; ++c) {
            bf16x2 pk = {(__bf16)pw[f][2 * c], (__bf16)pw[f][2 * c + 1]};
            *(bf16x2*)&Ps[myrow][f * 16 + rbase + 2 * c] = pk;
          }
        bf16x8 bp0 = *(bf16x8*)&Ps[myrow][kq];
        bf16x8 bp1 = *(bf16x8*)&Ps[myrow][32 + kq];
        const float s01 = ((selrow >> kb) & 1u) ? 1.f : 0.f;
        lp0 += s01 * rowsum;
#pragma unroll
        for (int df = 0; df < 4; ++df) {
          bf16x8 av0 = *(bf16x8*)&Vt[df * 16 + r15][kq];
          bf16x8 av1 = *(bf16x8*)&Vt[df * 16 + r15][32 + kq];
          f32x4 t = MFMA16(av0, bp0, fzero);
          f32x4 pv = MFMA16(av1, bp1, t);
#pragma unroll
          for (int reg = 0; reg < 4; ++reg)
            accO[0][df][reg] += pv[reg] * s01;
        }
      }
      // window pass: keep t >= myrow
#pragma unroll
      for (int f = 0; f < 4; ++f)
#pragma unroll
        for (int reg = 0; reg < 4; ++reg)
          if (f * 16 + rbase + reg < myrow) st4[f][reg] = -1e30f;
      float rowsum = 0.f;
#pragma unroll
      for (int f = 0; f < 4; ++f)
#pragma unroll
        for (int reg = 0; reg < 4; ++reg) {
          float p = EXP2F(st4[f][reg]);
          st4[f][reg] = p;
          rowsum += p;
        }
#pragma unroll
      for (int f = 0; f < 4; ++f)
#pragma unroll
        for (int c = 0; c < 2; ++c) {
          bf16x2 pk = {(__bf16)st4[f][2 * c], (__bf16)st4[f][2 * c + 1]};
          *(bf16x2*)&Ps[myrow][f * 16 + rbase + 2 * c] = pk;
        }
      bf16x8 bp0 = *(bf16x8*)&Ps[myrow][kq];
      bf16x8 bp1 = *(bf16x8*)&Ps[myrow][32 + kq];
      lp1 += rowsum;
#pragma unroll
      for (int df = 0; df < 4; ++df) {
        bf16x8 av0 = *(bf16x8*)&Vt[df * 16 + r15][kq];
        bf16x8 av1 = *(bf16x8*)&Vt[df * 16 + r15][32 + kq];
        f32x4 t = MFMA16(av0, bp0, fzero);
        f32x4 pv = MFMA16(av1, bp1, t);
#pragma unroll
        for (int reg = 0; reg < 4; ++reg)
          accO[1][df][reg] += pv[reg];
      }
    }
    if (kbn < 0) break;
    kb = kbn;
  }

  // one-time l reduction across the 4 hi-groups (same row = same r15)
  float lrun0 = lp0, lrun1 = lp1;
  lrun0 += __shfl_xor(lrun0, 16);
  lrun0 += __shfl_xor(lrun0, 32);
  lrun1 += __shfl_xor(lrun1, 16);
  lrun1 += __shfl_xor(lrun1, 32);

  __syncthreads();  // all waves done with Ks/Vt before aliasing as Otw
  float* Otw = (float*)(smem + 9216) + w * (16 * 68);
  const int r2 = lane >> 2;
  const int dq = (lane & 3) * 16;
  const int i_out = qb * 64 + w * 16 + r2;
  const float* gp = gate + (size_t)i_out * GATE_LD + hg * 3;
  const float g0 = gp[0], g1 = gp[1], g2 = gp[2];
  float fv[16];
  {
    const bf16x8* cp = (const bf16x8*)(comp + (size_t)i_out * HQD_ + hg * 64 + dq);
    bf16x8 c0 = cp[0], c1 = cp[1];
#pragma unroll
    for (int e = 0; e < 8; ++e) {
      fv[e] = g0 * (float)c0[e];
      fv[8 + e] = g0 * (float)c1[e];
    }
  }
  const float linv0 = 1.f / lrun0;
  const float linv1 = 1.f / lrun1;
#pragma unroll
  for (int br = 0; br < 2; ++br) {
    const float linv = (br == 0) ? linv0 : linv1;
#pragma unroll
    for (int df = 0; df < 4; ++df)
#pragma unroll
      for (int reg = 0; reg < 4; ++reg)
        Otw[r15 * 68 + df * 16 + rbase + reg] = accO[br][df][reg] * linv;
    const float gg = (br == 0) ? g1 : g2;
#pragma unroll
    for (int e = 0; e < 16; ++e) fv[e] += gg * Otw[r2 * 68 + dq + e];
  }
  bf16x8 o0, o1;
#pragma unroll
  for (int e = 0; e < 8; ++e) {
    o0[e] = (__bf16)fv[e];
    o1[e] = (__bf16)fv[8 + e];
  }
  bf16x8* op = (bf16x8*)(fused + (size_t)i_out * HQD_ + hg * 64 + dq);
  op[0] = o0;
  op[1] = o1;
}

// ---------------------------------------------------------------------------
extern "C" void kernel_launch(void* const* d_in, const int* in_sizes, int n_in,
                              void* d_out, int out_size, void* d_ws, size_t ws_size,
                              hipStream_t stream)
{
  (void)in_sizes; (void)n_in; (void)out_size; (void)ws_size;
  const float* x = (const float*)d_in[0];
  const float* Wq = (const float*)d_in[2];
  const float* Wk = (const float*)d_in[3];
  const float* Wv = (const float*)d_in[4];
  const float* Wo = (const float*)d_in[5];
  const float* Wg = (const float*)d_in[6];
  const float* wck = (const float*)d_in[7];
  const float* wcv = (const float*)d_in[8];
  const float* pe = (const float*)d_in[9];

  char* ws = (char*)d_ws;
  size_t off = 0;
  auto alloc = [&](size_t b) {
    void* p = ws + off;
    off += (b + 255) & ~(size_t)255;
    return p;
  };
  __bf16* xbf = (__bf16*)alloc((size_t)T_ * H_ * 2);
  __bf16* wqt = (__bf16*)alloc((size_t)HQD_ * H_ * 2);
  __bf16* wkt = (__bf16*)alloc((size_t)KVD_ * H_ * 2);
  __bf16* wvt = (__bf16*)alloc((size_t)KVD_ * H_ * 2);
  __bf16* wgt = (__bf16*)alloc((size_t)128 * H_ * 2);   // padded to 128 rows
  __bf16* wot = (__bf16*)alloc((size_t)H_ * HQD_ * 2);
  __bf16* qbf = (__bf16*)alloc((size_t)T_ * HQD_ * 2);
  __bf16* kbf = (__bf16*)alloc((size_t)T_ * KVD_ * 2);
  __bf16* vbf = (__bf16*)alloc((size_t)T_ * KVD_ * 2);
  __bf16* vTbf = (__bf16*)alloc((size_t)T_ * KVD_ * 2);
  float* gatef = (float*)alloc((size_t)T_ * GATE_LD * 4);
  float* ckf = (float*)alloc((size_t)HKV_ * M_ * D_ * 4);
  float* cvf = (float*)alloc((size_t)HKV_ * M_ * D_ * 4);
  float* sf = (float*)alloc((size_t)HKV_ * T_ * M_ * 4);
  unsigned* selw = (unsigned*)alloc((size_t)HKV_ * T_ * 4);
  __bf16* compb = (__bf16*)alloc((size_t)T_ * HQD_ * 2);
  __bf16* fusedb = (__bf16*)alloc((size_t)T_ * HQD_ * 2);

  cvt_bf16_kernel<<<dim3((T_ * H_ / 8 + 255) / 256), 256, 0, stream>>>(x, xbf, T_ * H_ / 8);
  twt_kernel<<<dim3(32, 32), 256, 0, stream>>>(Wq, wqt, HQD_);
  twt_kernel<<<dim3(2, 32), 256, 0, stream>>>(Wk, wkt, KVD_);
  twt_kernel<<<dim3(2, 32), 256, 0, stream>>>(Wv, wvt, KVD_);
  twt_kernel<<<dim3(2, 32), 256, 0, stream>>>(Wg, wgt, GATE_LD);
  twt_kernel<<<dim3(32, 32), 256, 0, stream>>>(Wo, wot, H_);
  proj_kernel<<<dim3(19, 16), 256, 0, stream>>>(xbf, wqt, wkt, wvt, wgt,
                                                qbf, kbf, vbf, vTbf, gatef);
  ckcv_kernel<<<dim3(M_, HKV_), 64, 0, stream>>>(kbf, vbf, pe, wck, wcv, ckf, cvf);
  comp_kernel<<<dim3(T_ / 4, HKV_), 256, 0, stream>>>(qbf, ckf, cvf, compb, sf);
  topk_kernel<<<dim3(16), 256, 0, stream>>>(sf, selw);
  flash_kernel<<<dim3(1024), 256, 0, stream>>>(qbf, kbf, vTbf, selw, compb, gatef, fusedb);
  gemm_wo_kernel<<<dim3(16, 16), 256, 0, stream>>>(fusedb, wot, (float*)d_out);
}

// Round 8
// 313.223 us; speedup vs baseline: 2.9901x; 1.0471x over previous
//
#include <hip/hip_runtime.h>
#include <hip/hip_bf16.h>
#include <math.h>

#define T_ 2048
#define H_ 2048
#define HQ_ 32
#define HKV_ 2
#define D_ 64
#define G_ 16
#define M_ 32
#define TOPK_ 16
#define WINDOW_ 512
#define HQD_ 2048   // HQ*D
#define KVD_ 128    // HKV*D
#define GATE_LD 96  // HQ*3

// q pre-scale: 1/sqrt(D) * log2(e); softmax done in log2 domain (exact).
#define QSCALE 0.1803368801111204f
#define SOFF 16.0f   // fixed softmax offset (log2 units)

typedef __attribute__((ext_vector_type(8))) __bf16 bf16x8;
typedef __attribute__((ext_vector_type(2))) __bf16 bf16x2;
typedef __attribute__((ext_vector_type(4))) float f32x4;

#define MFMA16(a, b, c) __builtin_amdgcn_mfma_f32_16x16x32_bf16((a), (b), (c), 0, 0, 0)

#if defined(__has_builtin)
#if __has_builtin(__builtin_amdgcn_exp2f)
#define EXP2F(x) __builtin_amdgcn_exp2f(x)
#endif
#endif
#ifndef EXP2F
#define EXP2F(x) exp2f(x)
#endif

// ---------------------------------------------------------------------------
// fp32 -> bf16 elementwise convert (8 elems/thread)
// ---------------------------------------------------------------------------
__global__ __launch_bounds__(256) void cvt_bf16_kernel(const float* __restrict__ in,
                                                       __bf16* __restrict__ out, int n8)
{
  int i = blockIdx.x * blockDim.x + threadIdx.x;
  if (i >= n8) return;
  const float4* p = (const float4*)(in + (size_t)i * 8);
  float4 f0 = p[0], f1 = p[1];
  bf16x8 w = {(__bf16)f0.x, (__bf16)f0.y, (__bf16)f0.z, (__bf16)f0.w,
              (__bf16)f1.x, (__bf16)f1.y, (__bf16)f1.z, (__bf16)f1.w};
  *(bf16x8*)(out + (size_t)i * 8) = w;
}

// ---------------------------------------------------------------------------
// Weight transpose+convert: W[K=2048][N] fp32 -> Wt[padN][2048] bf16.
// padN = gridDim.x*64; rows n >= N are zero-filled.
// ---------------------------------------------------------------------------
__global__ __launch_bounds__(256) void twt_kernel(const float* __restrict__ W,
                                                  __bf16* __restrict__ Wt, int N)
{
  __shared__ float tile[64][68];
  const int tid = threadIdx.x;
  const int tn0 = blockIdx.x * 64, tk0 = blockIdx.y * 64;
  const int r = tid >> 2, c0 = (tid & 3) * 16;
  if (tn0 + c0 < N) {
    const float* src = W + (size_t)(tk0 + r) * N + tn0 + c0;
    *(float4*)&tile[r][c0 + 0]  = ((const float4*)src)[0];
    *(float4*)&tile[r][c0 + 4]  = ((const float4*)src)[1];
    *(float4*)&tile[r][c0 + 8]  = ((const float4*)src)[2];
    *(float4*)&tile[r][c0 + 12] = ((const float4*)src)[3];
  } else {
#pragma unroll
    for (int e = 0; e < 16; ++e) tile[r][c0 + e] = 0.f;
  }
  __syncthreads();
  const int nloc = tid >> 2, kc = (tid & 3) * 16;
  bf16x8 w0, w1;
#pragma unroll
  for (int j = 0; j < 8; ++j) w0[j] = (__bf16)tile[kc + j][nloc];
#pragma unroll
  for (int j = 0; j < 8; ++j) w1[j] = (__bf16)tile[kc + 8 + j][nloc];
  __bf16* dst = Wt + (size_t)(tn0 + nloc) * H_ + tk0 + kc;
  *(bf16x8*)dst = w0;
  *(bf16x8*)(dst + 8) = w1;
}

// ---------------------------------------------------------------------------
// Fused projection GEMM (all-bf16, B pre-transposed): col-blocks 0-15 = Wq
// (scaled QSCALE), 16 = Wk, 17 = Wv (+V^T), 18 = Wg (sigmoid).
// BM=BN=128, BK=64 (half the barriers of BK=32), 256 thr, reg double-buffer.
// Row stride 72 elems -> 2-way LDS aliasing on frag reads (free, m136).
// ---------------------------------------------------------------------------
__global__ __launch_bounds__(256) void proj_kernel(
    const __bf16* __restrict__ xbf,
    const __bf16* __restrict__ Wqt, const __bf16* __restrict__ Wkt,
    const __bf16* __restrict__ Wvt, const __bf16* __restrict__ Wgt,
    __bf16* __restrict__ qout, __bf16* __restrict__ kout,
    __bf16* __restrict__ vout, __bf16* __restrict__ vTout,
    float* __restrict__ gout)
{
  __shared__ __bf16 As[128][72];
  __shared__ __bf16 Bs[128][72];
  const int bx = blockIdx.x;                    // 0..18
  const int sel = (bx < 16) ? 0 : (bx - 15);    // 0=Q,1=K,2=V,3=G
  const __bf16* Bt = (sel == 0) ? Wqt : (sel == 1) ? Wkt : (sel == 2) ? Wvt : Wgt;
  const int n0 = (sel == 0) ? bx * 128 : 0;
  const int tid = threadIdx.x;
  const int lane = tid & 63;
  const int w = tid >> 6;
  const int r15 = lane & 15;
  const int kq = (lane >> 4) * 8;
  const int m0 = blockIdx.y * 128;

  const f32x4 fzero = {0.f, 0.f, 0.f, 0.f};
  f32x4 acc[2][8];
#pragma unroll
  for (int a = 0; a < 2; ++a)
#pragma unroll
    for (int b = 0; b < 8; ++b) acc[a][b] = fzero;

  const int ar = tid >> 1, akc = (tid & 1) * 32;   // 4 int4 per thread/tensor

  int4 a0, a1, a2, a3, b0, b1, b2, b3;
  {
    const __bf16* a = xbf + (size_t)(m0 + ar) * H_ + akc;
    a0 = ((const int4*)a)[0]; a1 = ((const int4*)a)[1];
    a2 = ((const int4*)a)[2]; a3 = ((const int4*)a)[3];
    const __bf16* b = Bt + (size_t)(n0 + ar) * H_ + akc;
    b0 = ((const int4*)b)[0]; b1 = ((const int4*)b)[1];
    b2 = ((const int4*)b)[2]; b3 = ((const int4*)b)[3];
  }

  for (int k0 = 0; k0 < H_; k0 += 64) {
    __syncthreads();
    *(int4*)&As[ar][akc] = a0;      *(int4*)&As[ar][akc + 8] = a1;
    *(int4*)&As[ar][akc + 16] = a2; *(int4*)&As[ar][akc + 24] = a3;
    *(int4*)&Bs[ar][akc] = b0;      *(int4*)&Bs[ar][akc + 8] = b1;
    *(int4*)&Bs[ar][akc + 16] = b2; *(int4*)&Bs[ar][akc + 24] = b3;
    __syncthreads();
    if (k0 + 64 < H_) {   // prefetch next tile; overlaps MFMA below
      const __bf16* a = xbf + (size_t)(m0 + ar) * H_ + (k0 + 64) + akc;
      a0 = ((const int4*)a)[0]; a1 = ((const int4*)a)[1];
      a2 = ((const int4*)a)[2]; a3 = ((const int4*)a)[3];
      const __bf16* b = Bt + (size_t)(n0 + ar) * H_ + (k0 + 64) + akc;
      b0 = ((const int4*)b)[0]; b1 = ((const int4*)b)[1];
      b2 = ((const int4*)b)[2]; b3 = ((const int4*)b)[3];
    }
    bf16x8 af0a = *(bf16x8*)&As[w * 32 + r15][kq];
    bf16x8 af0b = *(bf16x8*)&As[w * 32 + r15][32 + kq];
    bf16x8 af1a = *(bf16x8*)&As[w * 32 + 16 + r15][kq];
    bf16x8 af1b = *(bf16x8*)&As[w * 32 + 16 + r15][32 + kq];
#pragma unroll
    for (int ni = 0; ni < 8; ++ni) {
      bf16x8 bfa = *(bf16x8*)&Bs[ni * 16 + r15][kq];
      bf16x8 bfb = *(bf16x8*)&Bs[ni * 16 + r15][32 + kq];
      acc[0][ni] = MFMA16(af0a, bfa, acc[0][ni]);
      acc[0][ni] = MFMA16(af0b, bfb, acc[0][ni]);
      acc[1][ni] = MFMA16(af1a, bfa, acc[1][ni]);
      acc[1][ni] = MFMA16(af1b, bfb, acc[1][ni]);
    }
  }

#pragma unroll
  for (int mi = 0; mi < 2; ++mi)
#pragma unroll
    for (int ni = 0; ni < 8; ++ni)
#pragma unroll
      for (int reg = 0; reg < 4; ++reg) {
        int row = m0 + w * 32 + mi * 16 + (lane >> 4) * 4 + reg;
        int col = ni * 16 + r15;
        float vv = acc[mi][ni][reg];
        if (sel == 0) {
          qout[(size_t)row * HQD_ + n0 + col] = (__bf16)(vv * QSCALE);
        } else if (sel == 1) {
          kout[(size_t)row * KVD_ + col] = (__bf16)vv;
        } else if (sel == 2) {
          vout[(size_t)row * KVD_ + col] = (__bf16)vv;
          vTout[(size_t)col * T_ + row] = (__bf16)vv;
        } else if (col < GATE_LD) {
          gout[(size_t)row * GATE_LD + col] = 1.f / (1.f + __expf(-vv));
        }
      }
}

// ---------------------------------------------------------------------------
// Output GEMM: d_out = fused[2048x2048]bf16 @ Wo^T[2048][2048]bf16 -> fp32.
// BM=BN=128, BK=64, same structure as proj.
// ---------------------------------------------------------------------------
__global__ __launch_bounds__(256) void gemm_wo_kernel(
    const __bf16* __restrict__ A, const __bf16* __restrict__ Bt,
    float* __restrict__ C)
{
  __shared__ __bf16 As[128][72];
  __shared__ __bf16 Bs[128][72];
  const int tid = threadIdx.x;
  const int lane = tid & 63;
  const int w = tid >> 6;
  const int r15 = lane & 15;
  const int kq = (lane >> 4) * 8;
  const int m0 = blockIdx.y * 128;
  const int n0 = blockIdx.x * 128;

  const f32x4 fzero = {0.f, 0.f, 0.f, 0.f};
  f32x4 acc[2][8];
#pragma unroll
  for (int a = 0; a < 2; ++a)
#pragma unroll
    for (int b = 0; b < 8; ++b) acc[a][b] = fzero;

  const int ar = tid >> 1, akc = (tid & 1) * 32;

  int4 a0, a1, a2, a3, b0, b1, b2, b3;
  {
    const __bf16* a = A + (size_t)(m0 + ar) * H_ + akc;
    a0 = ((const int4*)a)[0]; a1 = ((const int4*)a)[1];
    a2 = ((const int4*)a)[2]; a3 = ((const int4*)a)[3];
    const __bf16* b = Bt + (size_t)(n0 + ar) * H_ + akc;
    b0 = ((const int4*)b)[0]; b1 = ((const int4*)b)[1];
    b2 = ((const int4*)b)[2]; b3 = ((const int4*)b)[3];
  }

  for (int k0 = 0; k0 < H_; k0 += 64) {
    __syncthreads();
    *(int4*)&As[ar][akc] = a0;      *(int4*)&As[ar][akc + 8] = a1;
    *(int4*)&As[ar][akc + 16] = a2; *(int4*)&As[ar][akc + 24] = a3;
    *(int4*)&Bs[ar][akc] = b0;      *(int4*)&Bs[ar][akc + 8] = b1;
    *(int4*)&Bs[ar][akc + 16] = b2; *(int4*)&Bs[ar][akc + 24] = b3;
    __syncthreads();
    if (k0 + 64 < H_) {
      const __bf16* a = A + (size_t)(m0 + ar) * H_ + (k0 + 64) + akc;
      a0 = ((const int4*)a)[0]; a1 = ((const int4*)a)[1];
      a2 = ((const int4*)a)[2]; a3 = ((const int4*)a)[3];
      const __bf16* b = Bt + (size_t)(n0 + ar) * H_ + (k0 + 64) + akc;
      b0 = ((const int4*)b)[0]; b1 = ((const int4*)b)[1];
      b2 = ((const int4*)b)[2]; b3 = ((const int4*)b)[3];
    }
    bf16x8 af0a = *(bf16x8*)&As[w * 32 + r15][kq];
    bf16x8 af0b = *(bf16x8*)&As[w * 32 + r15][32 + kq];
    bf16x8 af1a = *(bf16x8*)&As[w * 32 + 16 + r15][kq];
    bf16x8 af1b = *(bf16x8*)&As[w * 32 + 16 + r15][32 + kq];
#pragma unroll
    for (int ni = 0; ni < 8; ++ni) {
      bf16x8 bfa = *(bf16x8*)&Bs[ni * 16 + r15][kq];
      bf16x8 bfb = *(bf16x8*)&Bs[ni * 16 + r15][32 + kq];
      acc[0][ni] = MFMA16(af0a, bfa, acc[0][ni]);
      acc[0][ni] = MFMA16(af0b, bfb, acc[0][ni]);
      acc[1][ni] = MFMA16(af1a, bfa, acc[1][ni]);
      acc[1][ni] = MFMA16(af1b, bfb, acc[1][ni]);
    }
  }

#pragma unroll
  for (int mi = 0; mi < 2; ++mi)
#pragma unroll
    for (int ni = 0; ni < 8; ++ni)
#pragma unroll
      for (int reg = 0; reg < 4; ++reg) {
        int row = m0 + w * 32 + mi * 16 + (lane >> 4) * 4 + reg;
        int col = n0 + ni * 16 + r15;
        C[(size_t)row * H_ + col] = acc[mi][ni][reg];
      }
}

// ---------------------------------------------------------------------------
// ck/cv pooling
// ---------------------------------------------------------------------------
__global__ void ckcv_kernel(const __bf16* __restrict__ kbf, const __bf16* __restrict__ vbf,
                            const float* __restrict__ pe, const float* __restrict__ wck,
                            const float* __restrict__ wcv, float* __restrict__ ckf,
                            float* __restrict__ cvf)
{
  const int m = blockIdx.x, h = blockIdx.y, d = threadIdx.x;
  float cka = 0.f, cva = 0.f;
  for (int t = 0; t < 64; ++t) {
    float kk = (float)kbf[(size_t)(m * 64 + t) * KVD_ + h * 64 + d];
    float vv = (float)vbf[(size_t)(m * 64 + t) * KVD_ + h * 64 + d];
    float pev = pe[((size_t)h * 64 + t) * 64 + d];
    cka += (kk + pev) * wck[h * 64 + t];
    cva += vv * wcv[h * 64 + t];
  }
  ckf[((size_t)h * M_ + m) * D_ + d] = cka;
  cvf[((size_t)h * M_ + m) * D_ + d] = cva;
}

// ---------------------------------------------------------------------------
// Compressed attention: wave per (i, h_kv); balanced i-swizzle.
// q pre-scaled by QSCALE -> logits in log2 domain, exp2 softmax.
// ---------------------------------------------------------------------------
__global__ __launch_bounds__(256) void comp_kernel(
    const __bf16* __restrict__ q, const float* __restrict__ ckf,
    const float* __restrict__ cvf, __bf16* __restrict__ comp,
    float* __restrict__ sout)
{
  __shared__ float cks[M_][65];
  __shared__ float cvs[M_][65];
  __shared__ float qv[4][64];
  __shared__ float pv_sh[4][32];
  const int h = blockIdx.y;
  const int tid = threadIdx.x, w = tid >> 6, lane = tid & 63;
  {
    int mm = tid >> 3, dc = (tid & 7) * 8;
#pragma unroll
    for (int e = 0; e < 8; ++e) {
      cks[mm][dc + e] = ckf[((size_t)h * M_ + mm) * D_ + dc + e];
      cvs[mm][dc + e] = cvf[((size_t)h * M_ + mm) * D_ + dc + e];
    }
  }
  __syncthreads();
  const int bid = blockIdx.x;
  const int ib = (bid & 1) ? (511 - (bid >> 1)) : (bid >> 1);  // balance
  const int i = ib * 4 + w;
  const int nvis = (i >= 63) ? ((i - 63) >> 6) + 1 : 0;
  float s_acc = 0.f;
  for (int g = 0; g < G_; ++g) {
    const int head = h * G_ + g;
    qv[w][lane] = (float)q[(size_t)i * HQD_ + head * 64 + lane];
    float lg = -1e30f;
    if (lane < nvis) {
      float a0 = 0.f, a1 = 0.f, a2 = 0.f, a3 = 0.f;
#pragma unroll
      for (int d2 = 0; d2 < 64; d2 += 4) {
        a0 += qv[w][d2] * cks[lane][d2];
        a1 += qv[w][d2 + 1] * cks[lane][d2 + 1];
        a2 += qv[w][d2 + 2] * cks[lane][d2 + 2];
        a3 += qv[w][d2 + 3] * cks[lane][d2 + 3];
      }
      lg = a0 + a1 + a2 + a3;
    }
    float mx = lg;
    for (int off = 1; off < 32; off <<= 1) mx = fmaxf(mx, __shfl_xor(mx, off));
    float p = (lane < nvis) ? EXP2F(lg - mx) : 0.f;
    float sum = p;
    for (int off = 1; off < 32; off <<= 1) sum += __shfl_xor(sum, off);
    float pn = (sum > 0.f) ? p / sum : 0.f;
    s_acc += pn;
    if (lane < 32) pv_sh[w][lane] = pn;
    float o = 0.f, o2 = 0.f;
    int m2 = 0;
    for (; m2 + 1 < nvis; m2 += 2) {
      o += pv_sh[w][m2] * cvs[m2][lane];
      o2 += pv_sh[w][m2 + 1] * cvs[m2 + 1][lane];
    }
    if (m2 < nvis) o += pv_sh[w][m2] * cvs[m2][lane];
    o += o2;
    comp[(size_t)i * HQD_ + head * 64 + lane] = (__bf16)o;
  }
  if (lane < 32) sout[((size_t)h * T_ + i) * M_ + lane] = s_acc;
}

// ---------------------------------------------------------------------------
// Top-k selection (stable) -> bitmask.
// ---------------------------------------------------------------------------
__global__ void topk_kernel(const float* __restrict__ sin, unsigned* __restrict__ sel)
{
  int idx = blockIdx.x * blockDim.x + threadIdx.x;
  if (idx >= HKV_ * T_) return;
  int h = idx >> 11, i = idx & (T_ - 1);
  int qblk = i >> 6;
  float sc[M_];
#pragma unroll
  for (int m = 0; m < M_; ++m) {
    if (m > qblk) sc[m] = -__builtin_inff();
    else if (m == 0 || m > qblk - 2) sc[m] = __builtin_inff();
    else sc[m] = sin[((size_t)h * T_ + i) * M_ + m];
  }
  unsigned picked = 0;
  for (int r = 0; r < TOPK_; ++r) {
    float best = -__builtin_inff();
    int bi = -1;
#pragma unroll
    for (int m = 0; m < M_; ++m) {
      if (!((picked >> m) & 1u) && sc[m] > best) { best = sc[m]; bi = m; }
    }
    if (bi < 0) break;
    picked |= 1u << bi;
  }
  sel[(size_t)h * T_ + i] = picked;
}

// ---------------------------------------------------------------------------
// Flash kernel, fixed-offset log2-softmax (no running max): logits are
// bounded, so P = exp2(st - SOFF) is exact after normalization. The -SOFF
// is folded into the QK^T MFMA C-init. Per-lane partial l-sums reduced once
// at the epilogue. K/V register-prefetch over the active-block bitmask.
// Ps aliases Qs (dead after frag hoist). q pre-scaled by QSCALE.
// ---------------------------------------------------------------------------
__global__ __launch_bounds__(256) void flash_kernel(
    const __bf16* __restrict__ q, const __bf16* __restrict__ kg,
    const __bf16* __restrict__ vT, const unsigned* __restrict__ selg,
    const __bf16* __restrict__ comp, const float* __restrict__ gate,
    __bf16* __restrict__ fused)
{
  __shared__ alignas(16) char smem[27904];
  __bf16 (*Qs)[72] = (__bf16(*)[72])(smem);            // 9216, aliased by Ps
  __bf16 (*Ps)[72] = (__bf16(*)[72])(smem);
  __bf16 (*Ks)[72] = (__bf16(*)[72])(smem + 9216);     // 9216 (t rows)
  __bf16 (*Vt)[72] = (__bf16(*)[72])(smem + 18432);    // 9216 (d rows)
  unsigned* sel_sh = (unsigned*)(smem + 27648);        // [64]

  // balance swizzle: co-resident v-groups get qb sets {b, 31-b, b+16, 15-b}
  const int lin = blockIdx.x;
  const int slot = lin & 255;
  const int v = lin >> 8;
  const int base = slot & 31, hseg = slot >> 5;
  const int hg = hseg * 4 + v;
  const int b2 = (base + ((v >> 1) << 4)) & 31;
  const int qb = (v & 1) ? (31 - b2) : b2;
  const int h = hg >> 4;

  const int tid = threadIdx.x;
  const int lane = tid & 63;
  const int w = tid >> 6;
  const int r15 = lane & 15;
  const int kq = (lane >> 4) * 8;
  const int rbase = (lane >> 4) * 4;
  const int myrow = w * 16 + r15;
  const int tld = tid >> 2, dld = (tid & 3) * 16;

  {
    const __bf16* src = q + (size_t)(qb * 64 + tld) * HQD_ + hg * 64 + dld;
    *(int4*)&Qs[tld][dld] = ((const int4*)src)[0];
    *(int4*)&Qs[tld][dld + 8] = ((const int4*)src)[1];
  }
  if (tid < 64) sel_sh[tid] = selg[h * T_ + qb * 64 + tid];
  __syncthreads();
  unsigned ubits = sel_sh[lane];
#pragma unroll
  for (int off = 1; off < 64; off <<= 1) ubits |= __shfl_xor(ubits, off);

  bf16x8 aq0 = *(bf16x8*)&Qs[myrow][kq];
  bf16x8 aq1 = *(bf16x8*)&Qs[myrow][32 + kq];
  const unsigned selrow = sel_sh[myrow];

  const f32x4 fzero = {0.f, 0.f, 0.f, 0.f};
  const f32x4 cinit = {-SOFF, -SOFF, -SOFF, -SOFF};
  f32x4 accO[2][4];
#pragma unroll
  for (int br = 0; br < 2; ++br)
#pragma unroll
    for (int a = 0; a < 4; ++a) accO[br][a] = fzero;
  float lp0 = 0.f, lp1 = 0.f;   // per-lane partial l-sums

  // active-block bitmask: union of selected blocks + window range, <= qb
  const unsigned qmaskbits = (qb >= 31) ? 0xFFFFFFFFu : ((1u << (qb + 1)) - 1);
  const unsigned wbits = (qb >= 9) ? (qmaskbits & ~((1u << (qb - 8)) - 1)) : qmaskbits;
  const unsigned amask = (ubits & qmaskbits) | wbits;

  int4 kp0, kp1, vp0, vp1;
  unsigned rem = amask;
  int kb = (int)__builtin_ctz(rem);
  {
    const __bf16* ksrc = kg + (size_t)(kb * 64 + tld) * KVD_ + h * 64 + dld;
    kp0 = ((const int4*)ksrc)[0];
    kp1 = ((const int4*)ksrc)[1];
    const __bf16* vsrc = vT + (size_t)(h * 64 + tld) * T_ + kb * 64 + dld;
    vp0 = ((const int4*)vsrc)[0];
    vp1 = ((const int4*)vsrc)[1];
  }

  for (;;) {
    rem &= rem - 1;
    const int kbn = rem ? (int)__builtin_ctz(rem) : -1;
    __syncthreads();
    *(int4*)&Ks[tld][dld] = kp0;
    *(int4*)&Ks[tld][dld + 8] = kp1;
    *(int4*)&Vt[tld][dld] = vp0;
    *(int4*)&Vt[tld][dld + 8] = vp1;
    __syncthreads();
    if (kbn >= 0) {   // prefetch next active block under this block's compute
      const __bf16* ksrc = kg + (size_t)(kbn * 64 + tld) * KVD_ + h * 64 + dld;
      kp0 = ((const int4*)ksrc)[0];
      kp1 = ((const int4*)ksrc)[1];
      const __bf16* vsrc = vT + (size_t)(h * 64 + tld) * T_ + kbn * 64 + dld;
      vp0 = ((const int4*)vsrc)[0];
      vp1 = ((const int4*)vsrc)[1];
    }

    const bool sp_act = (ubits >> kb) & 1u;
    const bool wn_act = (kb + 8) >= qb;
    const bool boundary = (kb + 8) == qb;

    // S^T with -SOFF folded into C-init. Lane owns q-row myrow (col r15).
    f32x4 st4[4];
    __builtin_amdgcn_s_setprio(1);
#pragma unroll
    for (int f = 0; f < 4; ++f) {
      bf16x8 kf0 = *(bf16x8*)&Ks[f * 16 + r15][kq];
      bf16x8 kf1 = *(bf16x8*)&Ks[f * 16 + r15][32 + kq];
      f32x4 s = MFMA16(kf0, aq0, cinit);
      st4[f] = MFMA16(kf1, aq1, s);
    }
    __builtin_amdgcn_s_setprio(0);
    if (kb == qb) {  // causal diagonal: t > myrow -> -inf
#pragma unroll
      for (int f = 0; f < 4; ++f)
#pragma unroll
        for (int reg = 0; reg < 4; ++reg)
          if (f * 16 + rbase + reg > myrow) st4[f][reg] = -1e30f;
    }

    if (!boundary) {
      // ---- shared path: one exp tile + one PV for both branches ----
      float rowsum = 0.f;
#pragma unroll
      for (int f = 0; f < 4; ++f)
#pragma unroll
        for (int reg = 0; reg < 4; ++reg) {
          float p = EXP2F(st4[f][reg]);
          st4[f][reg] = p;
          rowsum += p;
        }
#pragma unroll
      for (int f = 0; f < 4; ++f)
#pragma unroll
        for (int c = 0; c < 2; ++c) {
          bf16x2 pk = {(__bf16)st4[f][2 * c], (__bf16)st4[f][2 * c + 1]};
          *(bf16x2*)&Ps[myrow][f * 16 + rbase + 2 * c] = pk;
        }
      bf16x8 bp0 = *(bf16x8*)&Ps[myrow][kq];
      bf16x8 bp1 = *(bf16x8*)&Ps[myrow][32 + kq];
      f32x4 accP[4];
      __builtin_amdgcn_s_setprio(1);
#pragma unroll
      for (int df = 0; df < 4; ++df) {
        bf16x8 av0 = *(bf16x8*)&Vt[df * 16 + r15][kq];
        bf16x8 av1 = *(bf16x8*)&Vt[df * 16 + r15][32 + kq];
        f32x4 t = MFMA16(av0, bp0, fzero);
        accP[df] = MFMA16(av1, bp1, t);
      }
      __builtin_amdgcn_s_setprio(0);
      if (sp_act) {
        const float s01 = ((selrow >> kb) & 1u) ? 1.f : 0.f;
        lp0 += s01 * rowsum;
#pragma unroll
        for (int df = 0; df < 4; ++df)
#pragma unroll
          for (int reg = 0; reg < 4; ++reg)
            accO[0][df][reg] += accP[df][reg] * s01;
      }
      if (wn_act) {
        lp1 += rowsum;
#pragma unroll
        for (int df = 0; df < 4; ++df)
#pragma unroll
          for (int reg = 0; reg < 4; ++reg)
            accO[1][df][reg] += accP[df][reg];
      }
    } else {
      // ---- boundary kb == qb-8: two masked passes ----
      if (sp_act) {
        float rowsum = 0.f;
        float pw[4][4];
#pragma unroll
        for (int f = 0; f < 4; ++f)
#pragma unroll
          for (int reg = 0; reg < 4; ++reg) {
            float p = EXP2F(st4[f][reg]);
            pw[f][reg] = p;
            rowsum += p;
          }
#pragma unroll
        for (int f = 0; f < 4; ++f)
#pragma unroll
          for (int c = 0; c < 2; ++c) {
            bf16x2 pk = {(__bf16)pw[f][2 * c], (__bf16)pw[f][2 * c + 1]};
            *(bf16x2*)&Ps[myrow][f * 16 + rbase + 2 * c] = pk;
          }
        bf16x8 bp0 = *(bf16x8*)&Ps[myrow][kq];
        bf16x8 bp1 = *(bf16x8*)&Ps[myrow][32 + kq];
        const float s01 = ((selrow >> kb) & 1u) ? 1.f : 0.f;
        lp0 += s01 * rowsum;
#pragma unroll
        for (int df = 0; df < 4; ++df) {
          bf16x8 av0 = *(bf16x8*)&Vt[df * 16 + r15][kq];
          bf16x8 av1 = *(bf16x8*)&Vt[df * 16 + r15][32 + kq];
          f32x4 t = MFMA16(av0, bp0, fzero);
          f32x4 pv = MFMA16(av1, bp1, t);
#pragma unroll
          for (int reg = 0; reg < 4; ++reg)
            accO[0][df][reg] += pv[reg] * s01;
        }
      }
      // window pass: keep t >= myrow
#pragma unroll
      for (int f = 0; f < 4; ++f)
#pragma unroll
        for (int reg = 0; reg < 4; ++reg)
          if (f * 16 + rbase + reg < myrow) st4[f][reg] = -1e30f;
      float rowsum = 0.f;
#pragma unroll
      for (int f = 0; f < 4; ++f)
#pragma unroll
        for (int reg = 0; reg < 4; ++reg) {
          float p = EXP2F(st4[f][reg]);
          st4[f][reg] = p;
          rowsum += p;
        }
#pragma unroll
      for (int f = 0; f < 4; ++f)
#pragma unroll
        for (int c = 0; c < 2; ++c) {
          bf16x2 pk = {(__bf16)st4[f][2 * c], (__bf16)st4[f][2 * c + 1]};
          *(bf16x2*)&Ps[myrow][f * 16 + rbase + 2 * c] = pk;
        }
      bf16x8 bp0 = *(bf16x8*)&Ps[myrow][kq];
      bf16x8 bp1 = *(bf16x8*)&Ps[myrow][32 + kq];
      lp1 += rowsum;
#pragma unroll
      for (int df = 0; df < 4; ++df) {
        bf16x8 av0 = *(bf16x8*)&Vt[df * 16 + r15][kq];
        bf16x8 av1 = *(bf16x8*)&Vt[df * 16 + r15][32 + kq];
        f32x4 t = MFMA16(av0, bp0, fzero);
        f32x4 pv = MFMA16(av1, bp1, t);
#pragma unroll
        for (int reg = 0; reg < 4; ++reg)
          accO[1][df][reg] += pv[reg];
      }
    }
    if (kbn < 0) break;
    kb = kbn;
  }

  // one-time l reduction across the 4 hi-groups (same row = same r15)
  float lrun0 = lp0, lrun1 = lp1;
  lrun0 += __shfl_xor(lrun0, 16);
  lrun0 += __shfl_xor(lrun0, 32);
  lrun1 += __shfl_xor(lrun1, 16);
  lrun1 += __shfl_xor(lrun1, 32);

  __syncthreads();  // all waves done with Ks/Vt before aliasing as Otw
  float* Otw = (float*)(smem + 9216) + w * (16 * 68);
  const int r2 = lane >> 2;
  const int dq = (lane & 3) * 16;
  const int i_out = qb * 64 + w * 16 + r2;
  const float* gp = gate + (size_t)i_out * GATE_LD + hg * 3;
  const float g0 = gp[0], g1 = gp[1], g2 = gp[2];
  float fv[16];
  {
    const bf16x8* cp = (const bf16x8*)(comp + (size_t)i_out * HQD_ + hg * 64 + dq);
    bf16x8 c0 = cp[0], c1 = cp[1];
#pragma unroll
    for (int e = 0; e < 8; ++e) {
      fv[e] = g0 * (float)c0[e];
      fv[8 + e] = g0 * (float)c1[e];
    }
  }
  const float linv0 = 1.f / lrun0;
  const float linv1 = 1.f / lrun1;
#pragma unroll
  for (int br = 0; br < 2; ++br) {
    const float linv = (br == 0) ? linv0 : linv1;
#pragma unroll
    for (int df = 0; df < 4; ++df)
#pragma unroll
      for (int reg = 0; reg < 4; ++reg)
        Otw[r15 * 68 + df * 16 + rbase + reg] = accO[br][df][reg] * linv;
    const float gg = (br == 0) ? g1 : g2;
#pragma unroll
    for (int e = 0; e < 16; ++e) fv[e] += gg * Otw[r2 * 68 + dq + e];
  }
  bf16x8 o0, o1;
#pragma unroll
  for (int e = 0; e < 8; ++e) {
    o0[e] = (__bf16)fv[e];
    o1[e] = (__bf16)fv[8 + e];
  }
  bf16x8* op = (bf16x8*)(fused + (size_t)i_out * HQD_ + hg * 64 + dq);
  op[0] = o0;
  op[1] = o1;
}

// ---------------------------------------------------------------------------
extern "C" void kernel_launch(void* const* d_in, const int* in_sizes, int n_in,
                              void* d_out, int out_size, void* d_ws, size_t ws_size,
                              hipStream_t stream)
{
  (void)in_sizes; (void)n_in; (void)out_size; (void)ws_size;
  const float* x = (const float*)d_in[0];
  const float* Wq = (const float*)d_in[2];
  const float* Wk = (const float*)d_in[3];
  const float* Wv = (const float*)d_in[4];
  const float* Wo = (const float*)d_in[5];
  const float* Wg = (const float*)d_in[6];
  const float* wck = (const float*)d_in[7];
  const float* wcv = (const float*)d_in[8];
  const float* pe = (const float*)d_in[9];

  char* ws = (char*)d_ws;
  size_t off = 0;
  auto alloc = [&](size_t b) {
    void* p = ws + off;
    off += (b + 255) & ~(size_t)255;
    return p;
  };
  __bf16* xbf = (__bf16*)alloc((size_t)T_ * H_ * 2);
  __bf16* wqt = (__bf16*)alloc((size_t)HQD_ * H_ * 2);
  __bf16* wkt = (__bf16*)alloc((size_t)KVD_ * H_ * 2);
  __bf16* wvt = (__bf16*)alloc((size_t)KVD_ * H_ * 2);
  __bf16* wgt = (__bf16*)alloc((size_t)128 * H_ * 2);   // padded to 128 rows
  __bf16* wot = (__bf16*)alloc((size_t)H_ * HQD_ * 2);
  __bf16* qbf = (__bf16*)alloc((size_t)T_ * HQD_ * 2);
  __bf16* kbf = (__bf16*)alloc((size_t)T_ * KVD_ * 2);
  __bf16* vbf = (__bf16*)alloc((size_t)T_ * KVD_ * 2);
  __bf16* vTbf = (__bf16*)alloc((size_t)T_ * KVD_ * 2);
  float* gatef = (float*)alloc((size_t)T_ * GATE_LD * 4);
  float* ckf = (float*)alloc((size_t)HKV_ * M_ * D_ * 4);
  float* cvf = (float*)alloc((size_t)HKV_ * M_ * D_ * 4);
  float* sf = (float*)alloc((size_t)HKV_ * T_ * M_ * 4);
  unsigned* selw = (unsigned*)alloc((size_t)HKV_ * T_ * 4);
  __bf16* compb = (__bf16*)alloc((size_t)T_ * HQD_ * 2);
  __bf16* fusedb = (__bf16*)alloc((size_t)T_ * HQD_ * 2);

  cvt_bf16_kernel<<<dim3((T_ * H_ / 8 + 255) / 256), 256, 0, stream>>>(x, xbf, T_ * H_ / 8);
  twt_kernel<<<dim3(32, 32), 256, 0, stream>>>(Wq, wqt, HQD_);
  twt_kernel<<<dim3(2, 32), 256, 0, stream>>>(Wk, wkt, KVD_);
  twt_kernel<<<dim3(2, 32), 256, 0, stream>>>(Wv, wvt, KVD_);
  twt_kernel<<<dim3(2, 32), 256, 0, stream>>>(Wg, wgt, GATE_LD);
  twt_kernel<<<dim3(32, 32), 256, 0, stream>>>(Wo, wot, H_);
  proj_kernel<<<dim3(19, 16), 256, 0, stream>>>(xbf, wqt, wkt, wvt, wgt,
                                                qbf, kbf, vbf, vTbf, gatef);
  ckcv_kernel<<<dim3(M_, HKV_), 64, 0, stream>>>(kbf, vbf, pe, wck, wcv, ckf, cvf);
  comp_kernel<<<dim3(T_ / 4, HKV_), 256, 0, stream>>>(qbf, ckf, cvf, compb, sf);
  topk_kernel<<<dim3(16), 256, 0, stream>>>(sf, selw);
  flash_kernel<<<dim3(1024), 256, 0, stream>>>(qbf, kbf, vTbf, selw, compb, gatef, fusedb);
  gemm_wo_kernel<<<dim3(16, 16), 256, 0, stream>>>(fusedb, wot, (float*)d_out);
}